// Round 1
// baseline (1391.331 us; speedup 1.0000x reference)
//
#include <hip/hip_runtime.h>
#include <hip/hip_bf16.h>
#include <cstdint>

#define N_NODES 100000
#define D 300
#define RD 100
#define NREL 1000
#define E2 200000
#define E1 100000
#define NB 8192
#define NEG 0.2f

__device__ __forceinline__ float leaky(float x){ return x >= 0.f ? x : NEG*x; }

// monotone float->uint encoding for atomicMax-based segment max
__device__ __forceinline__ unsigned encf(float f){
  unsigned u = __float_as_uint(f);
  return (u & 0x80000000u) ? ~u : (u | 0x80000000u);
}
__device__ __forceinline__ float decf(unsigned u){
  return (u & 0x80000000u) ? __uint_as_float(u & 0x7FFFFFFFu) : __uint_as_float(~u);
}
__device__ __forceinline__ float wred(float v){
  #pragma unroll
  for (int m = 32; m >= 1; m >>= 1) v += __shfl_xor(v, m, 64);
  return v;
}
__device__ __forceinline__ float rlane(float v, int i){
  return __uint_as_float(__builtin_amdgcn_readlane(__float_as_uint(v), i));
}

// ---- constants: M = W^T W (100x100), W1P = W^T w1 (100) ----
__global__ void k_const(const float* __restrict__ W, const float* __restrict__ watt,
                        float* __restrict__ M, float* __restrict__ W1P){
  int t = blockIdx.x*blockDim.x + threadIdx.x;
  if (t < RD*RD){
    int i = t / RD, j = t % RD;
    float acc = 0.f;
    for (int d = 0; d < D; ++d) acc += W[d*RD+i]*W[d*RD+j];
    M[t] = acc;
  } else if (t < RD*RD + RD){
    int j = t - RD*RD;
    float acc = 0.f;
    for (int d = 0; d < D; ++d) acc += watt[d]*W[d*RD+j];
    W1P[j] = acc;
  }
}

// ---- per-relation: V[r]=normalize(W r), RINV=1/max(||Wr||,1e-12), RVW1=V.w1, RVW2=V.w2 ----
__global__ __launch_bounds__(64) void k_rel(const float* __restrict__ relT, const float* __restrict__ W,
    const float* __restrict__ watt, float* __restrict__ V, float* __restrict__ RINV,
    float* __restrict__ RVW1, float* __restrict__ RVW2){
  __shared__ float rl_[RD];
  __shared__ float ul[D];
  int r = blockIdx.x, lane = threadIdx.x;
  for (int j = lane; j < RD; j += 64) rl_[j] = relT[r*RD+j];
  __syncthreads();
  float nrm2 = 0.f;
  for (int d = 0; d < D; ++d){
    float part = 0.f;
    for (int j = lane; j < RD; j += 64) part += W[d*RD+j]*rl_[j];
    float s = wred(part);
    if (lane == 0) ul[d] = s;
    nrm2 += s*s;
  }
  float invn = 1.f / fmaxf(sqrtf(nrm2), 1e-12f);
  __syncthreads();
  float pw1 = 0.f, pw2 = 0.f;
  for (int d = lane; d < D; d += 64){
    float vd = ul[d]*invn;
    V[r*D+d] = vd;
    pw1 += vd*watt[d];
    pw2 += vd*watt[D+d];
  }
  pw1 = wred(pw1); pw2 = wred(pw2);
  if (lane == 0){ RINV[r] = invn; RVW1[r] = pw1; RVW2[r] = pw2; }
}

// ---- per-node tables: G[n] = W^T e_n (100), P[n] = {e.w1, e.w2, e.w3, 0} ----
#define TM 32
__global__ __launch_bounds__(256) void k_nodetab(const float* __restrict__ Esrc,
    const float* __restrict__ W, const float* __restrict__ watt,
    float* __restrict__ G, float* __restrict__ P){
  __shared__ float Els[TM*D];
  int n0 = blockIdx.x*TM;
  for (int u = threadIdx.x; u < TM*D; u += 256){
    int nl = u / D, d = u % D;
    int n = n0 + nl;
    Els[u] = (n < N_NODES) ? Esrc[(size_t)n*D + d] : 0.f;
  }
  __syncthreads();
  int t = threadIdx.x;
  int g = t % 26, q = t / 26;   // 26 col-groups x 8 node-quads = 208 active threads
  if (q >= 8) return;
  int k0 = g*4;
  float acc[4][4];
  #pragma unroll
  for (int r=0;r<4;++r){
    #pragma unroll
    for (int c2=0;c2<4;++c2) acc[r][c2]=0.f;
  }
  if (g < 25){
    for (int d = 0; d < D; ++d){
      const float4 w4 = *(const float4*)(W + d*RD + k0);
      #pragma unroll
      for (int r=0;r<4;++r){
        float e = Els[(q*4+r)*D + d];
        acc[r][0] += e*w4.x; acc[r][1] += e*w4.y; acc[r][2] += e*w4.z; acc[r][3] += e*w4.w;
      }
    }
  } else {
    for (int d = 0; d < D; ++d){
      float w0 = watt[d], w1v = watt[D+d], w2v = watt[2*D+d];
      #pragma unroll
      for (int r=0;r<4;++r){
        float e = Els[(q*4+r)*D + d];
        acc[r][0] += e*w0; acc[r][1] += e*w1v; acc[r][2] += e*w2v;
      }
    }
  }
  #pragma unroll
  for (int r=0;r<4;++r){
    int n = n0 + q*4 + r;
    if (n >= N_NODES) continue;
    if (g < 25){
      *(float4*)(G + (size_t)n*RD + k0) = make_float4(acc[r][0],acc[r][1],acc[r][2],acc[r][3]);
    } else {
      *(float4*)(P + (size_t)n*4) = make_float4(acc[r][0],acc[r][1],acc[r][2],0.f);
    }
  }
}

// ---- level-2 pass 1: logits b, 4 edges per wave, M in LDS ----
__global__ __launch_bounds__(256) void k_pass1_l2(
    const float* __restrict__ relT, const int* __restrict__ rel2i, const int* __restrict__ relrp2,
    const int* __restrict__ par, const int* __restrict__ chi, const int* __restrict__ roo,
    const float* __restrict__ G, const float* __restrict__ P,
    const float* __restrict__ Mg, const float* __restrict__ W1Pg,
    const float* __restrict__ RINV, const float* __restrict__ RVW2,
    float* __restrict__ BBUF, unsigned* __restrict__ BMAXU){
  __shared__ float Ml[RD*RD];
  __shared__ float w1pl[RD];
  for (int u = threadIdx.x; u < RD*RD; u += 256) Ml[u] = Mg[u];
  if (threadIdx.x < RD) w1pl[threadIdx.x] = W1Pg[threadIdx.x];
  __syncthreads();
  int lane = threadIdx.x & 63, wid = threadIdx.x >> 6;
  int gw = blockIdx.x*4 + wid;
  int nw = gridDim.x*4;
  for (int base = gw*4; base < E2; base += nw*4){
    float c0[4], c1[4];
    int ra[4], rp[4], rc[4], rr[4];
    #pragma unroll
    for (int k=0;k<4;++k){
      int e = base+k;
      if (e < E2){
        int a = rel2i[e], b = relrp2[e];
        ra[k]=a; rp[k]=par[e]; rc[k]=chi[e]; rr[k]=roo[e];
        c0[k] = relT[a*RD+lane]*relT[b*RD+lane];
        c1[k] = (lane<36) ? relT[a*RD+lane+64]*relT[b*RD+lane+64] : 0.f;
      } else { ra[k]=0; rp[k]=0; rc[k]=0; rr[k]=0; c0[k]=0.f; c1[k]=0.f; }
    }
    // t_j = sum_i c_i M[i][j], lane owns j=lane and j=lane+64
    float tj0[4]={0.f,0.f,0.f,0.f}, tj1[4]={0.f,0.f,0.f,0.f};
    for (int i=0;i<64;++i){
      float m0 = Ml[i*RD+lane];
      float m1 = (lane<36) ? Ml[i*RD+lane+64] : 0.f;
      #pragma unroll
      for (int k=0;k<4;++k){
        float ci = rlane(c0[k], i);
        tj0[k] += ci*m0; tj1[k] += ci*m1;
      }
    }
    for (int i=0;i<36;++i){
      float m0 = Ml[(i+64)*RD+lane];
      float m1 = (lane<36) ? Ml[(i+64)*RD+lane+64] : 0.f;
      #pragma unroll
      for (int k=0;k<4;++k){
        float ci = rlane(c1[k], i);
        tj0[k] += ci*m0; tj1[k] += ci*m1;
      }
    }
    #pragma unroll
    for (int k=0;k<4;++k){
      int e = base+k;
      float accn = c0[k]*tj0[k] + c1[k]*tj1[k];
      float accgi=0.f, accw1=0.f, accgx=0.f;
      if (e < E2){
        const float* gI = G + (size_t)rr[k]*RD;
        const float* gX = G + (size_t)rp[k]*RD;
        accgi = c0[k]*gI[lane];
        accw1 = c0[k]*w1pl[lane];
        accgx = relT[ra[k]*RD+lane]*gX[lane];
        if (lane < 36){
          accgi += c1[k]*gI[lane+64];
          accw1 += c1[k]*w1pl[lane+64];
          accgx += relT[ra[k]*RD+lane+64]*gX[lane+64];
        }
      }
      float nr  = wred(accn);
      float dgi = wred(accgi);
      float dw1 = wred(accw1);
      float dgx = wred(accgx);
      if (lane == 0 && e < E2){
        float invp = 1.f / fmaxf(sqrtf(nr), 1e-12f);
        float t1 = (dgi*invp) * (dw1*invp);
        float t2 = (dgx*RINV[ra[k]]) * RVW2[ra[k]];
        float b = P[(size_t)rr[k]*4+0] - 2.f*t1 + P[(size_t)rp[k]*4+1] - 2.f*t2 + P[(size_t)rc[k]*4+2];
        b = leaky(b);
        BBUF[e] = b;
        atomicMax(&BMAXU[rp[k]], encf(b));
      }
    }
  }
}

// ---- level-1 pass 1: v_p = v_k = V[rel], all per-rel scalars precomputed ----
__global__ __launch_bounds__(256) void k_pass1_l1(
    const float* __restrict__ relT, const int* __restrict__ rel1i,
    const int* __restrict__ par, const int* __restrict__ chi, const int* __restrict__ roo,
    const float* __restrict__ G, const float* __restrict__ P,
    const float* __restrict__ RINV, const float* __restrict__ RVW1, const float* __restrict__ RVW2,
    float* __restrict__ BBUF, unsigned* __restrict__ BMAXU){
  int lane = threadIdx.x & 63;
  int e = (blockIdx.x*256 + threadIdx.x) >> 6;
  if (e >= E1) return;
  int r = rel1i[e], pp = par[e], cc = chi[e], ii = roo[e];
  const float* rrow = relT + r*RD;
  const float* gI = G + (size_t)ii*RD;
  const float* gX = G + (size_t)pp*RD;
  float ai = rrow[lane]*gI[lane];
  float ax = rrow[lane]*gX[lane];
  if (lane < 36){
    ai += rrow[lane+64]*gI[lane+64];
    ax += rrow[lane+64]*gX[lane+64];
  }
  float dgi = wred(ai), dgx = wred(ax);
  if (lane == 0){
    float invn = RINV[r];
    float b = P[(size_t)ii*4+0] - 2.f*(dgi*invn)*RVW1[r]
            + P[(size_t)pp*4+1] - 2.f*(dgx*invn)*RVW2[r]
            + P[(size_t)cc*4+2];
    b = leaky(b);
    BBUF[e] = b;
    atomicMax(&BMAXU[pp], encf(b));
  }
}

// ---- pass 2: exp(b - max) and segment sum ----
__global__ void k_pass2(const int* __restrict__ par, const float* __restrict__ BBUF,
    const unsigned* __restrict__ BMAXU, float* __restrict__ BEXP, float* __restrict__ BSUM, int E){
  int e = blockIdx.x*blockDim.x + threadIdx.x;
  if (e >= E) return;
  int p = par[e];
  float m = decf(BMAXU[p]);
  float ex = expf(BBUF[e]-m);
  BEXP[e] = ex;
  atomicAdd(&BSUM[p], ex);
}

// ---- pass 3: upd = (e_y - 2 v_k (v_k.e_y)) * a, atomicAdd into AGG[parent] ----
__global__ __launch_bounds__(256) void k_pass3(const int* __restrict__ relI,
    const int* __restrict__ par, const int* __restrict__ chi,
    const float* __restrict__ V, const float* __restrict__ Esrc,
    const float* __restrict__ BEXP, const float* __restrict__ BSUM,
    float* __restrict__ AGG, int E){
  int lane = threadIdx.x & 63;
  int e = (blockIdx.x*256 + threadIdx.x) >> 6;
  if (e >= E) return;
  int p = par[e], y = chi[e], r = relI[e];
  float a = BEXP[e] / fmaxf(BSUM[p], 1e-10f);
  const float* vr = V + (size_t)r*D;
  const float* ey = Esrc + (size_t)y*D;
  float vv[5], ee[5];
  #pragma unroll
  for (int qq=0;qq<5;++qq){
    int d = lane + 64*qq;
    if (d < D){ vv[qq]=vr[d]; ee[qq]=ey[d]; } else { vv[qq]=0.f; ee[qq]=0.f; }
  }
  float part = 0.f;
  #pragma unroll
  for (int qq=0;qq<5;++qq) part += vv[qq]*ee[qq];
  float dk = wred(part);
  float s2 = 2.f*dk;
  float* ap = AGG + (size_t)p*D;
  #pragma unroll
  for (int qq=0;qq<5;++qq){
    int d = lane + 64*qq;
    if (d < D) atomicAdd(&ap[d], (ee[qq] - s2*vv[qq])*a);
  }
}

// ---- apply: EA = leaky(In + AGG) ----
__global__ void k_apply(const float* __restrict__ In, const float* __restrict__ AGG, float* __restrict__ EA){
  size_t i = (size_t)blockIdx.x*blockDim.x + threadIdx.x;
  size_t stride = (size_t)gridDim.x*blockDim.x;
  size_t total = (size_t)N_NODES*D/4;
  const float4* a4 = (const float4*)In; const float4* g4 = (const float4*)AGG; float4* o4 = (float4*)EA;
  for (; i < total; i += stride){
    float4 x = a4[i], y = g4[i];
    float4 o;
    o.x = leaky(x.x+y.x); o.y = leaky(x.y+y.y); o.z = leaky(x.z+y.z); o.w = leaky(x.w+y.w);
    o4[i] = o;
  }
}

// ---- output gather: out[o] = leaky(EA[root] + AGG[root]) ----
__global__ __launch_bounds__(256) void k_out(const int* __restrict__ ro, const float* __restrict__ EA,
    const float* __restrict__ AGG, float* __restrict__ out){
  int lane = threadIdx.x & 63;
  int o = (blockIdx.x*256 + threadIdx.x) >> 6;
  if (o >= NB) return;
  int n = ro[o];
  const float* ea = EA + (size_t)n*D;
  const float* ag = AGG + (size_t)n*D;
  float* op = out + (size_t)o*D;
  #pragma unroll
  for (int qq=0;qq<5;++qq){
    int d = lane + 64*qq;
    if (d < D) op[d] = leaky(ea[d]+ag[d]);
  }
}

extern "C" void kernel_launch(void* const* d_in, const int* in_sizes, int n_in,
                              void* d_out, int out_size, void* d_ws, size_t ws_size,
                              hipStream_t stream){
  const float* node = (const float*)d_in[0];
  const float* relT = (const float*)d_in[1];
  const float* W    = (const float*)d_in[2];
  const float* watt = (const float*)d_in[3];
  const int* par2 = (const int*)d_in[4];
  const int* chi2 = (const int*)d_in[5];
  const int* roo2 = (const int*)d_in[6];
  const int* rel2i = (const int*)d_in[7];
  const int* relrp2 = (const int*)d_in[8];
  const int* par1 = (const int*)d_in[9];
  const int* chi1 = (const int*)d_in[10];
  const int* roo1 = (const int*)d_in[11];
  const int* rel1i = (const int*)d_in[12];
  const int* roout = (const int*)d_in[13];

  char* w = (char*)d_ws;
  size_t off = 0;
  auto alloc = [&](size_t bytes)->void*{ void* p = w + off; off += (bytes + 255) & ~(size_t)255; return p; };
  float* EA   = (float*)alloc((size_t)N_NODES*D*4);
  float* AGG  = (float*)alloc((size_t)N_NODES*D*4);
  float* G    = (float*)alloc((size_t)N_NODES*RD*4);
  float* P    = (float*)alloc((size_t)N_NODES*4*4);
  float* V    = (float*)alloc((size_t)NREL*D*4);
  float* RINV = (float*)alloc(NREL*4);
  float* RVW1 = (float*)alloc(NREL*4);
  float* RVW2 = (float*)alloc(NREL*4);
  float* M    = (float*)alloc(RD*RD*4);
  float* W1P  = (float*)alloc(RD*4);
  float* BBUF = (float*)alloc((size_t)E2*4);
  float* BEXP = (float*)alloc((size_t)E2*4);
  unsigned* BMAXU = (unsigned*)alloc((size_t)N_NODES*4);
  float* BSUM = (float*)alloc((size_t)N_NODES*4);

  // constants (rel_table / W_proj / w_att are static inputs)
  k_const<<<dim3(40), dim3(256), 0, stream>>>(W, watt, M, W1P);
  k_rel<<<dim3(NREL), dim3(64), 0, stream>>>(relT, W, watt, V, RINV, RVW1, RVW2);

  // ---------- level 2 ----------
  hipMemsetAsync(BMAXU, 0, (size_t)N_NODES*4, stream);
  hipMemsetAsync(BSUM, 0, (size_t)N_NODES*4, stream);
  hipMemsetAsync(AGG, 0, (size_t)N_NODES*D*4, stream);
  k_nodetab<<<dim3((N_NODES+TM-1)/TM), dim3(256), 0, stream>>>(node, W, watt, G, P);
  k_pass1_l2<<<dim3(768), dim3(256), 0, stream>>>(relT, rel2i, relrp2, par2, chi2, roo2,
                                                  G, P, M, W1P, RINV, RVW2, BBUF, BMAXU);
  k_pass2<<<dim3((E2+255)/256), dim3(256), 0, stream>>>(par2, BBUF, BMAXU, BEXP, BSUM, E2);
  k_pass3<<<dim3((E2+3)/4), dim3(256), 0, stream>>>(rel2i, par2, chi2, V, node, BEXP, BSUM, AGG, E2);
  k_apply<<<dim3(2048), dim3(256), 0, stream>>>(node, AGG, EA);

  // ---------- level 1 ----------
  hipMemsetAsync(BMAXU, 0, (size_t)N_NODES*4, stream);
  hipMemsetAsync(BSUM, 0, (size_t)N_NODES*4, stream);
  hipMemsetAsync(AGG, 0, (size_t)N_NODES*D*4, stream);
  k_nodetab<<<dim3((N_NODES+TM-1)/TM), dim3(256), 0, stream>>>(EA, W, watt, G, P);
  k_pass1_l1<<<dim3((E1+3)/4), dim3(256), 0, stream>>>(relT, rel1i, par1, chi1, roo1,
                                                       G, P, RINV, RVW1, RVW2, BBUF, BMAXU);
  k_pass2<<<dim3((E1+255)/256), dim3(256), 0, stream>>>(par1, BBUF, BMAXU, BEXP, BSUM, E1);
  k_pass3<<<dim3((E1+3)/4), dim3(256), 0, stream>>>(rel1i, par1, chi1, V, EA, BEXP, BSUM, AGG, E1);
  k_out<<<dim3((NB+3)/4), dim3(256), 0, stream>>>(roout, EA, AGG, (float*)d_out);
}

// Round 2
// 1063.898 us; speedup vs baseline: 1.3078x; 1.3078x over previous
//
#include <hip/hip_runtime.h>
#include <hip/hip_bf16.h>
#include <cstdint>

#define N_NODES 100000
#define NPAD 100096
#define D 300
#define RD 100
#define NREL 1000
#define E2 200000
#define E1 100000
#define NB 8192
#define NEG 0.2f

typedef __bf16 bf16x8 __attribute__((ext_vector_type(8)));
typedef float f32x4 __attribute__((ext_vector_type(4)));
typedef unsigned short us4 __attribute__((ext_vector_type(4)));
typedef unsigned short us8 __attribute__((ext_vector_type(8)));

__device__ __forceinline__ float leaky(float x){ return x >= 0.f ? x : NEG*x; }

__device__ __forceinline__ unsigned short f2b(float v){
  unsigned u = __float_as_uint(v);
  unsigned r = u + 0x7FFF + ((u>>16)&1u);
  return (unsigned short)(r>>16);
}

// monotone float->uint encoding for atomicMax-based segment max
__device__ __forceinline__ unsigned encf(float f){
  unsigned u = __float_as_uint(f);
  return (u & 0x80000000u) ? ~u : (u | 0x80000000u);
}
__device__ __forceinline__ float decf(unsigned u){
  return (u & 0x80000000u) ? __uint_as_float(u & 0x7FFFFFFFu) : __uint_as_float(~u);
}
__device__ __forceinline__ float wred(float v){
  #pragma unroll
  for (int m = 32; m >= 1; m >>= 1) v += __shfl_xor(v, m, 64);
  return v;
}
__device__ __forceinline__ float rlane(float v, int i){
  return __uint_as_float(__builtin_amdgcn_readlane(__float_as_uint(v), i));
}

// ---- constants: M = W^T W (100x100), W1P = W^T w1 (100) ----
__global__ void k_const(const float* __restrict__ W, const float* __restrict__ watt,
                        float* __restrict__ M, float* __restrict__ W1P){
  int t = blockIdx.x*blockDim.x + threadIdx.x;
  if (t < RD*RD){
    int i = t / RD, j = t % RD;
    float acc = 0.f;
    for (int d = 0; d < D; ++d) acc += W[d*RD+i]*W[d*RD+j];
    M[t] = acc;
  } else if (t < RD*RD + RD){
    int j = t - RD*RD;
    float acc = 0.f;
    for (int d = 0; d < D; ++d) acc += watt[d]*W[d*RD+j];
    W1P[j] = acc;
  }
}

// ---- Bt[112][320] bf16 = [W | w1 w2 w3 | 0]^T, K padded to 320 ----
__global__ void k_prep(const float* __restrict__ W, const float* __restrict__ watt,
                       unsigned short* __restrict__ Bt){
  int u = blockIdx.x*blockDim.x + threadIdx.x;
  if (u >= 112*320) return;
  int c = u / 320, k = u % 320;
  float v = 0.f;
  if (k < D){
    if (c < RD) v = W[k*RD + c];
    else if (c < RD+3) v = watt[(c-RD)*D + k];
  }
  Bt[u] = f2b(v);
}

// ---- cast node embeddings to padded bf16 table Xb[NPAD][320] ----
__global__ void k_cast(const float* __restrict__ src, unsigned short* __restrict__ dst){
  int total = NPAD*40;
  for (int u = blockIdx.x*blockDim.x + threadIdx.x; u < total; u += gridDim.x*blockDim.x){
    int row = u/40, c8 = (u%40)*8;
    us8 o;
    if (row < N_NODES && c8 <= 292){
      float4 x = *(const float4*)(src + (size_t)row*D + c8);
      float4 y = *(const float4*)(src + (size_t)row*D + c8 + 4);
      o[0]=f2b(x.x); o[1]=f2b(x.y); o[2]=f2b(x.z); o[3]=f2b(x.w);
      o[4]=f2b(y.x); o[5]=f2b(y.y); o[6]=f2b(y.z); o[7]=f2b(y.w);
    } else {
      #pragma unroll
      for (int j=0;j<8;++j){
        int c = c8+j;
        float v = (row < N_NODES && c < D) ? src[(size_t)row*D + c] : 0.f;
        o[j] = f2b(v);
      }
    }
    *(us8*)(dst + (size_t)row*320 + c8) = o;
  }
}

// ---- per-relation: V[r]=normalize(W r), RINV=1/max(||Wr||,1e-12), RVW1=V.w1, RVW2=V.w2 ----
__global__ __launch_bounds__(64) void k_rel(const float* __restrict__ relT, const float* __restrict__ W,
    const float* __restrict__ watt, float* __restrict__ V, float* __restrict__ RINV,
    float* __restrict__ RVW1, float* __restrict__ RVW2){
  __shared__ float rl_[RD];
  __shared__ float ul[D];
  int r = blockIdx.x, lane = threadIdx.x;
  for (int j = lane; j < RD; j += 64) rl_[j] = relT[r*RD+j];
  __syncthreads();
  float nrm2 = 0.f;
  for (int d = 0; d < D; ++d){
    float part = 0.f;
    for (int j = lane; j < RD; j += 64) part += W[d*RD+j]*rl_[j];
    float s = wred(part);
    if (lane == 0) ul[d] = s;
    nrm2 += s*s;
  }
  float invn = 1.f / fmaxf(sqrtf(nrm2), 1e-12f);
  __syncthreads();
  float pw1 = 0.f, pw2 = 0.f;
  for (int d = lane; d < D; d += 64){
    float vd = ul[d]*invn;
    V[r*D+d] = vd;
    pw1 += vd*watt[d];
    pw2 += vd*watt[D+d];
  }
  pw1 = wred(pw1); pw2 = wred(pw2);
  if (lane == 0){ RINV[r] = invn; RVW1[r] = pw1; RVW2[r] = pw2; }
}

// ---- MFMA node tables: G[n] = W^T e_n (100), P[n] = {e.w1, e.w2, e.w3, 0} ----
__global__ __launch_bounds__(256) void k_nodetab2(const unsigned short* __restrict__ Eb,
    const unsigned short* __restrict__ Bt, float* __restrict__ G, float* __restrict__ P){
  int lane = threadIdx.x & 63, wid = threadIdx.x >> 6;
  int n0 = blockIdx.x*128;
  size_t a0 = (size_t)(n0 + wid*32 + (lane&15))*320 + ((lane>>4)*8);
  size_t b0 = (size_t)(lane&15)*320 + ((lane>>4)*8);
  f32x4 acc[2][7];
  #pragma unroll
  for (int s=0;s<2;++s)
    #pragma unroll
    for (int c=0;c<7;++c) acc[s][c] = (f32x4){0.f,0.f,0.f,0.f};
  for (int ks = 0; ks < 10; ++ks){
    bf16x8 a0f = *(const bf16x8*)(Eb + a0 + ks*32);
    bf16x8 a1f = *(const bf16x8*)(Eb + a0 + 16*320 + ks*32);
    #pragma unroll
    for (int cf=0; cf<7; ++cf){
      bf16x8 bf = *(const bf16x8*)(Bt + b0 + (size_t)cf*16*320 + ks*32);
      acc[0][cf] = __builtin_amdgcn_mfma_f32_16x16x32_bf16(a0f, bf, acc[0][cf], 0, 0, 0);
      acc[1][cf] = __builtin_amdgcn_mfma_f32_16x16x32_bf16(a1f, bf, acc[1][cf], 0, 0, 0);
    }
  }
  int rbase = n0 + wid*32 + ((lane>>4)<<2);
  int cbase = lane & 15;
  #pragma unroll
  for (int sub=0; sub<2; ++sub){
    #pragma unroll
    for (int cf=0; cf<7; ++cf){
      int col = cf*16 + cbase;
      #pragma unroll
      for (int r=0; r<4; ++r){
        int row = rbase + sub*16 + r;
        if (row < N_NODES){
          float v = acc[sub][cf][r];
          if (col < RD) G[(size_t)row*RD + col] = v;
          else if (col < RD+3) P[(size_t)row*4 + (col-RD)] = v;
        }
      }
    }
  }
}

// ---- level-2 pass 1: logits b, 4 edges per wave, M in LDS ----
__global__ __launch_bounds__(256) void k_pass1_l2(
    const float* __restrict__ relT, const int* __restrict__ rel2i, const int* __restrict__ relrp2,
    const int* __restrict__ par, const int* __restrict__ chi, const int* __restrict__ roo,
    const float* __restrict__ G, const float* __restrict__ P,
    const float* __restrict__ Mg, const float* __restrict__ W1Pg,
    const float* __restrict__ RINV, const float* __restrict__ RVW2,
    float* __restrict__ BBUF, unsigned* __restrict__ BMAXU){
  __shared__ float Ml[RD*RD];
  __shared__ float w1pl[RD];
  for (int u = threadIdx.x; u < RD*RD; u += 256) Ml[u] = Mg[u];
  if (threadIdx.x < RD) w1pl[threadIdx.x] = W1Pg[threadIdx.x];
  __syncthreads();
  int lane = threadIdx.x & 63, wid = threadIdx.x >> 6;
  int gw = blockIdx.x*4 + wid;
  int nw = gridDim.x*4;
  for (int base = gw*4; base < E2; base += nw*4){
    float c0[4], c1[4];
    int ra[4], rp[4], rc[4], rr[4];
    #pragma unroll
    for (int k=0;k<4;++k){
      int e = base+k;
      if (e < E2){
        int a = rel2i[e], b = relrp2[e];
        ra[k]=a; rp[k]=par[e]; rc[k]=chi[e]; rr[k]=roo[e];
        c0[k] = relT[a*RD+lane]*relT[b*RD+lane];
        c1[k] = (lane<36) ? relT[a*RD+lane+64]*relT[b*RD+lane+64] : 0.f;
      } else { ra[k]=0; rp[k]=0; rc[k]=0; rr[k]=0; c0[k]=0.f; c1[k]=0.f; }
    }
    float tj0[4]={0.f,0.f,0.f,0.f}, tj1[4]={0.f,0.f,0.f,0.f};
    for (int i=0;i<64;++i){
      float m0 = Ml[i*RD+lane];
      float m1 = (lane<36) ? Ml[i*RD+lane+64] : 0.f;
      #pragma unroll
      for (int k=0;k<4;++k){
        float ci = rlane(c0[k], i);
        tj0[k] += ci*m0; tj1[k] += ci*m1;
      }
    }
    for (int i=0;i<36;++i){
      float m0 = Ml[(i+64)*RD+lane];
      float m1 = (lane<36) ? Ml[(i+64)*RD+lane+64] : 0.f;
      #pragma unroll
      for (int k=0;k<4;++k){
        float ci = rlane(c1[k], i);
        tj0[k] += ci*m0; tj1[k] += ci*m1;
      }
    }
    #pragma unroll
    for (int k=0;k<4;++k){
      int e = base+k;
      float accn = c0[k]*tj0[k] + c1[k]*tj1[k];
      float accgi=0.f, accw1=0.f, accgx=0.f;
      if (e < E2){
        const float* gI = G + (size_t)rr[k]*RD;
        const float* gX = G + (size_t)rp[k]*RD;
        accgi = c0[k]*gI[lane];
        accw1 = c0[k]*w1pl[lane];
        accgx = relT[ra[k]*RD+lane]*gX[lane];
        if (lane < 36){
          accgi += c1[k]*gI[lane+64];
          accw1 += c1[k]*w1pl[lane+64];
          accgx += relT[ra[k]*RD+lane+64]*gX[lane+64];
        }
      }
      float nr  = wred(accn);
      float dgi = wred(accgi);
      float dw1 = wred(accw1);
      float dgx = wred(accgx);
      if (lane == 0 && e < E2){
        float invp = 1.f / fmaxf(sqrtf(nr), 1e-12f);
        float t1 = (dgi*invp) * (dw1*invp);
        float t2 = (dgx*RINV[ra[k]]) * RVW2[ra[k]];
        float b = P[(size_t)rr[k]*4+0] - 2.f*t1 + P[(size_t)rp[k]*4+1] - 2.f*t2 + P[(size_t)rc[k]*4+2];
        b = leaky(b);
        BBUF[e] = b;
        atomicMax(&BMAXU[rp[k]], encf(b));
      }
    }
  }
}

// ---- level-1 pass 1 ----
__global__ __launch_bounds__(256) void k_pass1_l1(
    const float* __restrict__ relT, const int* __restrict__ rel1i,
    const int* __restrict__ par, const int* __restrict__ chi, const int* __restrict__ roo,
    const float* __restrict__ G, const float* __restrict__ P,
    const float* __restrict__ RINV, const float* __restrict__ RVW1, const float* __restrict__ RVW2,
    float* __restrict__ BBUF, unsigned* __restrict__ BMAXU){
  int lane = threadIdx.x & 63;
  int e = (blockIdx.x*256 + threadIdx.x) >> 6;
  if (e >= E1) return;
  int r = rel1i[e], pp = par[e], cc = chi[e], ii = roo[e];
  const float* rrow = relT + r*RD;
  const float* gI = G + (size_t)ii*RD;
  const float* gX = G + (size_t)pp*RD;
  float ai = rrow[lane]*gI[lane];
  float ax = rrow[lane]*gX[lane];
  if (lane < 36){
    ai += rrow[lane+64]*gI[lane+64];
    ax += rrow[lane+64]*gX[lane+64];
  }
  float dgi = wred(ai), dgx = wred(ax);
  if (lane == 0){
    float invn = RINV[r];
    float b = P[(size_t)ii*4+0] - 2.f*(dgi*invn)*RVW1[r]
            + P[(size_t)pp*4+1] - 2.f*(dgx*invn)*RVW2[r]
            + P[(size_t)cc*4+2];
    b = leaky(b);
    BBUF[e] = b;
    atomicMax(&BMAXU[pp], encf(b));
  }
}

// ---- pass 2: exp(b - max) and segment sum ----
__global__ void k_pass2(const int* __restrict__ par, const float* __restrict__ BBUF,
    const unsigned* __restrict__ BMAXU, float* __restrict__ BEXP, float* __restrict__ BSUM, int E){
  int e = blockIdx.x*blockDim.x + threadIdx.x;
  if (e >= E) return;
  int p = par[e];
  float m = decf(BMAXU[p]);
  float ex = expf(BBUF[e]-m);
  BEXP[e] = ex;
  atomicAdd(&BSUM[p], ex);
}

// ---- pass 3: upd = (e_y - 2 v_k (v_k.e_y)) * a, atomicAdd into AGG[parent] ----
__global__ __launch_bounds__(256) void k_pass3(const int* __restrict__ relI,
    const int* __restrict__ par, const int* __restrict__ chi,
    const float* __restrict__ V, const float* __restrict__ Esrc,
    const float* __restrict__ BEXP, const float* __restrict__ BSUM,
    float* __restrict__ AGG, int E){
  int lane = threadIdx.x & 63;
  int e = (blockIdx.x*256 + threadIdx.x) >> 6;
  if (e >= E) return;
  int p = par[e], y = chi[e], r = relI[e];
  float a = BEXP[e] / fmaxf(BSUM[p], 1e-10f);
  const float* vr = V + (size_t)r*D;
  const float* ey = Esrc + (size_t)y*D;
  float vv[5], ee[5];
  #pragma unroll
  for (int qq=0;qq<5;++qq){
    int d = lane + 64*qq;
    if (d < D){ vv[qq]=vr[d]; ee[qq]=ey[d]; } else { vv[qq]=0.f; ee[qq]=0.f; }
  }
  float part = 0.f;
  #pragma unroll
  for (int qq=0;qq<5;++qq) part += vv[qq]*ee[qq];
  float dk = wred(part);
  float s2 = 2.f*dk;
  float* ap = AGG + (size_t)p*D;
  #pragma unroll
  for (int qq=0;qq<5;++qq){
    int d = lane + 64*qq;
    if (d < D) atomicAdd(&ap[d], (ee[qq] - s2*vv[qq])*a);
  }
}

// ---- apply: EA = leaky(In + AGG), plus bf16 copy into Xb (padded) ----
__global__ void k_apply(const float* __restrict__ In, const float* __restrict__ AGG,
                        float* __restrict__ EA, unsigned short* __restrict__ Xb){
  int total = N_NODES*75;
  for (int i = blockIdx.x*blockDim.x + threadIdx.x; i < total; i += gridDim.x*blockDim.x){
    float4 x = ((const float4*)In)[i];
    float4 y = ((const float4*)AGG)[i];
    float4 o;
    o.x = leaky(x.x+y.x); o.y = leaky(x.y+y.y); o.z = leaky(x.z+y.z); o.w = leaky(x.w+y.w);
    ((float4*)EA)[i] = o;
    int row = i/75, c4 = (i%75)*4;
    us4 b4; b4[0]=f2b(o.x); b4[1]=f2b(o.y); b4[2]=f2b(o.z); b4[3]=f2b(o.w);
    *(us4*)(Xb + (size_t)row*320 + c4) = b4;
  }
}

// ---- output gather ----
__global__ __launch_bounds__(256) void k_out(const int* __restrict__ ro, const float* __restrict__ EA,
    const float* __restrict__ AGG, float* __restrict__ out){
  int lane = threadIdx.x & 63;
  int o = (blockIdx.x*256 + threadIdx.x) >> 6;
  if (o >= NB) return;
  int n = ro[o];
  const float* ea = EA + (size_t)n*D;
  const float* ag = AGG + (size_t)n*D;
  float* op = out + (size_t)o*D;
  #pragma unroll
  for (int qq=0;qq<5;++qq){
    int d = lane + 64*qq;
    if (d < D) op[d] = leaky(ea[d]+ag[d]);
  }
}

extern "C" void kernel_launch(void* const* d_in, const int* in_sizes, int n_in,
                              void* d_out, int out_size, void* d_ws, size_t ws_size,
                              hipStream_t stream){
  const float* node = (const float*)d_in[0];
  const float* relT = (const float*)d_in[1];
  const float* W    = (const float*)d_in[2];
  const float* watt = (const float*)d_in[3];
  const int* par2 = (const int*)d_in[4];
  const int* chi2 = (const int*)d_in[5];
  const int* roo2 = (const int*)d_in[6];
  const int* rel2i = (const int*)d_in[7];
  const int* relrp2 = (const int*)d_in[8];
  const int* par1 = (const int*)d_in[9];
  const int* chi1 = (const int*)d_in[10];
  const int* roo1 = (const int*)d_in[11];
  const int* rel1i = (const int*)d_in[12];
  const int* roout = (const int*)d_in[13];

  char* w = (char*)d_ws;
  size_t off = 0;
  auto alloc = [&](size_t bytes)->void*{ void* p = w + off; off += (bytes + 255) & ~(size_t)255; return p; };
  float* EA   = (float*)alloc((size_t)N_NODES*D*4);
  float* AGG  = (float*)alloc((size_t)N_NODES*D*4);
  float* G    = (float*)alloc((size_t)N_NODES*RD*4);
  float* P    = (float*)alloc((size_t)N_NODES*4*4);
  float* V    = (float*)alloc((size_t)NREL*D*4);
  float* RINV = (float*)alloc(NREL*4);
  float* RVW1 = (float*)alloc(NREL*4);
  float* RVW2 = (float*)alloc(NREL*4);
  float* M    = (float*)alloc(RD*RD*4);
  float* W1P  = (float*)alloc(RD*4);
  float* BBUF = (float*)alloc((size_t)E2*4);
  float* BEXP = (float*)alloc((size_t)E2*4);
  unsigned* BMAXU = (unsigned*)alloc((size_t)N_NODES*4);
  float* BSUM = (float*)alloc((size_t)N_NODES*4);
  unsigned short* Xb = (unsigned short*)alloc((size_t)NPAD*320*2);
  unsigned short* Bt = (unsigned short*)alloc((size_t)112*320*2);

  // constants (rel_table / W_proj / w_att are static inputs)
  k_const<<<dim3(40), dim3(256), 0, stream>>>(W, watt, M, W1P);
  k_prep<<<dim3(140), dim3(256), 0, stream>>>(W, watt, Bt);
  k_rel<<<dim3(NREL), dim3(64), 0, stream>>>(relT, W, watt, V, RINV, RVW1, RVW2);

  // ---------- level 2 ----------
  hipMemsetAsync(BMAXU, 0, (size_t)N_NODES*4, stream);
  hipMemsetAsync(BSUM, 0, (size_t)N_NODES*4, stream);
  hipMemsetAsync(AGG, 0, (size_t)N_NODES*D*4, stream);
  k_cast<<<dim3(2048), dim3(256), 0, stream>>>(node, Xb);
  k_nodetab2<<<dim3((N_NODES+127)/128), dim3(256), 0, stream>>>(Xb, Bt, G, P);
  k_pass1_l2<<<dim3(768), dim3(256), 0, stream>>>(relT, rel2i, relrp2, par2, chi2, roo2,
                                                  G, P, M, W1P, RINV, RVW2, BBUF, BMAXU);
  k_pass2<<<dim3((E2+255)/256), dim3(256), 0, stream>>>(par2, BBUF, BMAXU, BEXP, BSUM, E2);
  k_pass3<<<dim3((E2+3)/4), dim3(256), 0, stream>>>(rel2i, par2, chi2, V, node, BEXP, BSUM, AGG, E2);
  k_apply<<<dim3(2048), dim3(256), 0, stream>>>(node, AGG, EA, Xb);

  // ---------- level 1 ----------
  hipMemsetAsync(BMAXU, 0, (size_t)N_NODES*4, stream);
  hipMemsetAsync(BSUM, 0, (size_t)N_NODES*4, stream);
  hipMemsetAsync(AGG, 0, (size_t)N_NODES*D*4, stream);
  k_nodetab2<<<dim3((N_NODES+127)/128), dim3(256), 0, stream>>>(Xb, Bt, G, P);
  k_pass1_l1<<<dim3((E1+3)/4), dim3(256), 0, stream>>>(relT, rel1i, par1, chi1, roo1,
                                                       G, P, RINV, RVW1, RVW2, BBUF, BMAXU);
  k_pass2<<<dim3((E1+255)/256), dim3(256), 0, stream>>>(par1, BBUF, BMAXU, BEXP, BSUM, E1);
  k_pass3<<<dim3((E1+3)/4), dim3(256), 0, stream>>>(rel1i, par1, chi1, V, EA, BEXP, BSUM, AGG, E1);
  k_out<<<dim3((NB+3)/4), dim3(256), 0, stream>>>(roout, EA, AGG, (float*)d_out);
}

// Round 3
// 907.233 us; speedup vs baseline: 1.5336x; 1.1727x over previous
//
#include <hip/hip_runtime.h>
#include <hip/hip_bf16.h>
#include <cstdint>

#define N_NODES 100000
#define NPAD 100096
#define D 300
#define RD 100
#define NREL 1000
#define E2 200000
#define E1 100000
#define NB 8192
#define NEG 0.2f

typedef __bf16 bf16x8 __attribute__((ext_vector_type(8)));
typedef float f32x4 __attribute__((ext_vector_type(4)));
typedef unsigned short us4 __attribute__((ext_vector_type(4)));
typedef unsigned short us8 __attribute__((ext_vector_type(8)));

__device__ __forceinline__ float leaky(float x){ return x >= 0.f ? x : NEG*x; }

__device__ __forceinline__ unsigned short f2b(float v){
  unsigned u = __float_as_uint(v);
  unsigned r = u + 0x7FFF + ((u>>16)&1u);
  return (unsigned short)(r>>16);
}
__device__ __forceinline__ float b2f(unsigned short b){
  return __uint_as_float(((unsigned)b) << 16);
}

// monotone float->uint encoding for atomicMax-based segment max
__device__ __forceinline__ unsigned encf(float f){
  unsigned u = __float_as_uint(f);
  return (u & 0x80000000u) ? ~u : (u | 0x80000000u);
}
__device__ __forceinline__ float decf(unsigned u){
  return (u & 0x80000000u) ? __uint_as_float(u & 0x7FFFFFFFu) : __uint_as_float(~u);
}
__device__ __forceinline__ float wred(float v){
  #pragma unroll
  for (int m = 32; m >= 1; m >>= 1) v += __shfl_xor(v, m, 64);
  return v;
}

// ---- constants: M = W^T W (100x100), W1P = W^T w1 (100) ----
__global__ void k_const(const float* __restrict__ W, const float* __restrict__ watt,
                        float* __restrict__ M, float* __restrict__ W1P){
  int t = blockIdx.x*blockDim.x + threadIdx.x;
  if (t < RD*RD){
    int i = t / RD, j = t % RD;
    float acc = 0.f;
    for (int d = 0; d < D; ++d) acc += W[d*RD+i]*W[d*RD+j];
    M[t] = acc;
  } else if (t < RD*RD + RD){
    int j = t - RD*RD;
    float acc = 0.f;
    for (int d = 0; d < D; ++d) acc += watt[d]*W[d*RD+j];
    W1P[j] = acc;
  }
}

// ---- Bt[112][320] bf16 = [W | w1 w2 w3 | 0]^T, K padded to 320 ----
__global__ void k_prep(const float* __restrict__ W, const float* __restrict__ watt,
                       unsigned short* __restrict__ Bt){
  int u = blockIdx.x*blockDim.x + threadIdx.x;
  if (u >= 112*320) return;
  int c = u / 320, k = u % 320;
  float v = 0.f;
  if (k < D){
    if (c < RD) v = W[k*RD + c];
    else if (c < RD+3) v = watt[(c-RD)*D + k];
  }
  Bt[u] = f2b(v);
}

// ---- MbT[112][128] bf16: rows j=0..99 -> M[j][i] (symmetric), row 100 -> W1P, rest 0 ----
__global__ void k_prep2(const float* __restrict__ M, const float* __restrict__ W1P,
                        unsigned short* __restrict__ MbT){
  int u = blockIdx.x*blockDim.x + threadIdx.x;
  if (u >= 112*128) return;
  int j = u >> 7, i = u & 127;
  float v = 0.f;
  if (i < RD){
    if (j < RD) v = M[j*RD + i];
    else if (j == RD) v = W1P[i];
  }
  MbT[u] = f2b(v);
}

// ---- cast node embeddings to padded bf16 table Xb[NPAD][320] ----
__global__ void k_cast(const float* __restrict__ src, unsigned short* __restrict__ dst){
  int total = NPAD*40;
  for (int u = blockIdx.x*blockDim.x + threadIdx.x; u < total; u += gridDim.x*blockDim.x){
    int row = u/40, c8 = (u%40)*8;
    us8 o;
    if (row < N_NODES && c8 <= 292){
      float4 x = *(const float4*)(src + (size_t)row*D + c8);
      float4 y = *(const float4*)(src + (size_t)row*D + c8 + 4);
      o[0]=f2b(x.x); o[1]=f2b(x.y); o[2]=f2b(x.z); o[3]=f2b(x.w);
      o[4]=f2b(y.x); o[5]=f2b(y.y); o[6]=f2b(y.z); o[7]=f2b(y.w);
    } else {
      #pragma unroll
      for (int j=0;j<8;++j){
        int c = c8+j;
        float v = (row < N_NODES && c < D) ? src[(size_t)row*D + c] : 0.f;
        o[j] = f2b(v);
      }
    }
    *(us8*)(dst + (size_t)row*320 + c8) = o;
  }
}

// ---- per-relation: V[r]=normalize(W r), RINV=1/max(||Wr||,1e-12), RVW1=V.w1, RVW2=V.w2 ----
__global__ __launch_bounds__(64) void k_rel(const float* __restrict__ relT, const float* __restrict__ W,
    const float* __restrict__ watt, float* __restrict__ V, float* __restrict__ RINV,
    float* __restrict__ RVW1, float* __restrict__ RVW2){
  __shared__ float rl_[RD];
  __shared__ float ul[D];
  int r = blockIdx.x, lane = threadIdx.x;
  for (int j = lane; j < RD; j += 64) rl_[j] = relT[r*RD+j];
  __syncthreads();
  float nrm2 = 0.f;
  for (int d = 0; d < D; ++d){
    float part = 0.f;
    for (int j = lane; j < RD; j += 64) part += W[d*RD+j]*rl_[j];
    float s = wred(part);
    if (lane == 0) ul[d] = s;
    nrm2 += s*s;
  }
  float invn = 1.f / fmaxf(sqrtf(nrm2), 1e-12f);
  __syncthreads();
  float pw1 = 0.f, pw2 = 0.f;
  for (int d = lane; d < D; d += 64){
    float vd = ul[d]*invn;
    V[r*D+d] = vd;
    pw1 += vd*watt[d];
    pw2 += vd*watt[D+d];
  }
  pw1 = wred(pw1); pw2 = wred(pw2);
  if (lane == 0){ RINV[r] = invn; RVW1[r] = pw1; RVW2[r] = pw2; }
}

// ---- MFMA node tables: G[n] = W^T e_n (100), P[n] = {e.w1, e.w2, e.w3, 0} ----
__global__ __launch_bounds__(256) void k_nodetab2(const unsigned short* __restrict__ Eb,
    const unsigned short* __restrict__ Bt, float* __restrict__ G, float* __restrict__ P){
  int lane = threadIdx.x & 63, wid = threadIdx.x >> 6;
  int n0 = blockIdx.x*128;
  size_t a0 = (size_t)(n0 + wid*32 + (lane&15))*320 + ((lane>>4)*8);
  size_t b0 = (size_t)(lane&15)*320 + ((lane>>4)*8);
  f32x4 acc[2][7];
  #pragma unroll
  for (int s=0;s<2;++s)
    #pragma unroll
    for (int c=0;c<7;++c) acc[s][c] = (f32x4){0.f,0.f,0.f,0.f};
  for (int ks = 0; ks < 10; ++ks){
    bf16x8 a0f = *(const bf16x8*)(Eb + a0 + ks*32);
    bf16x8 a1f = *(const bf16x8*)(Eb + a0 + 16*320 + ks*32);
    #pragma unroll
    for (int cf=0; cf<7; ++cf){
      bf16x8 bf = *(const bf16x8*)(Bt + b0 + (size_t)cf*16*320 + ks*32);
      acc[0][cf] = __builtin_amdgcn_mfma_f32_16x16x32_bf16(a0f, bf, acc[0][cf], 0, 0, 0);
      acc[1][cf] = __builtin_amdgcn_mfma_f32_16x16x32_bf16(a1f, bf, acc[1][cf], 0, 0, 0);
    }
  }
  int rbase = n0 + wid*32 + ((lane>>4)<<2);
  int cbase = lane & 15;
  #pragma unroll
  for (int sub=0; sub<2; ++sub){
    #pragma unroll
    for (int cf=0; cf<7; ++cf){
      int col = cf*16 + cbase;
      #pragma unroll
      for (int r=0; r<4; ++r){
        int row = rbase + sub*16 + r;
        if (row < N_NODES){
          float v = acc[sub][cf][r];
          if (col < RD) G[(size_t)row*RD + col] = v;
          else if (col < RD+3) P[(size_t)row*4 + (col-RD)] = v;
        }
      }
    }
  }
}

// ---- level-2 pass 1 (MFMA): per wave 16 edges; nr = c^T M c via mfma, dw1 via col 100 ----
__global__ __launch_bounds__(256) void k_pass1_l2(
    const float* __restrict__ relT, const int* __restrict__ rel2i, const int* __restrict__ relrp2,
    const int* __restrict__ par, const int* __restrict__ chi, const int* __restrict__ roo,
    const float* __restrict__ G, const float* __restrict__ P,
    const unsigned short* __restrict__ MbT,
    const float* __restrict__ RINV, const float* __restrict__ RVW2,
    float* __restrict__ BBUF, unsigned* __restrict__ BMAXU){
  // per-wave C tile: 16 rows x 136 bf16 elems (272B stride -> 2-way banks max)
  __shared__ unsigned short Cl[4*16*136];
  int lane = threadIdx.x & 63, wid = threadIdx.x >> 6;
  int ep = lane & 15, g = lane >> 4;
  unsigned short* cw = Cl + wid*16*136;
  int e = blockIdx.x*64 + wid*16 + ep;
  int ra = rel2i[e], rb = relrp2[e], rp = par[e], rc = chi[e], rr = roo[e];
  const float* rA = relT + (size_t)ra*RD;
  const float* rB = relT + (size_t)rb*RD;
  const float* gR = G + (size_t)rr*RD;
  const float* gX = G + (size_t)rp*RD;
  float dgi = 0.f, dgx = 0.f;
  bf16x8 af[4];
  #pragma unroll
  for (int ks=0; ks<4; ++ks){
    us8 cpack;
    #pragma unroll
    for (int h=0; h<2; ++h){
      int k0 = g*8 + ks*32 + h*4;
      float4 a4 = make_float4(0.f,0.f,0.f,0.f), b4 = a4, grr = a4, grp = a4;
      if (k0 <= 96){
        a4  = *(const float4*)(rA + k0);
        b4  = *(const float4*)(rB + k0);
        grr = *(const float4*)(gR + k0);
        grp = *(const float4*)(gX + k0);
      }
      float4 c4;
      c4.x = a4.x*b4.x; c4.y = a4.y*b4.y; c4.z = a4.z*b4.z; c4.w = a4.w*b4.w;
      dgi += c4.x*grr.x + c4.y*grr.y + c4.z*grr.z + c4.w*grr.w;
      dgx += a4.x*grp.x + a4.y*grp.y + a4.z*grp.z + a4.w*grp.w;
      cpack[h*4+0]=f2b(c4.x); cpack[h*4+1]=f2b(c4.y); cpack[h*4+2]=f2b(c4.z); cpack[h*4+3]=f2b(c4.w);
    }
    *(us8*)((char*)cw + ep*272 + g*16 + ks*64) = cpack;
    af[ks] = *(bf16x8*)&cpack;
  }
  f32x4 acc[7];
  #pragma unroll
  for (int cf=0; cf<7; ++cf) acc[cf] = (f32x4){0.f,0.f,0.f,0.f};
  #pragma unroll
  for (int cf=0; cf<7; ++cf){
    #pragma unroll
    for (int ks=0; ks<4; ++ks){
      bf16x8 bfr = *(const bf16x8*)(MbT + (size_t)(cf*16+ep)*128 + g*8 + ks*32);
      acc[cf] = __builtin_amdgcn_mfma_f32_16x16x32_bf16(af[ks], bfr, acc[cf], 0, 0, 0);
    }
  }
  // reduce gather dots across g-groups (edge key = ep)
  dgi += __shfl_xor(dgi, 16); dgi += __shfl_xor(dgi, 32);
  dgx += __shfl_xor(dgx, 16); dgx += __shfl_xor(dgx, 32);
  __syncthreads();
  #pragma unroll
  for (int r=0; r<4; ++r){
    int row = g*4 + r;
    // nr partial: sum_j c[row][j]*t[row][j], lane holds col j = cf*16+ep
    float pr = 0.f;
    #pragma unroll
    for (int cf=0; cf<7; ++cf)
      pr += b2f(cw[row*136 + cf*16 + ep]) * acc[cf][r];
    pr += __shfl_xor(pr, 1); pr += __shfl_xor(pr, 2);
    pr += __shfl_xor(pr, 4); pr += __shfl_xor(pr, 8);
    float dw1r = __shfl(acc[6][r], (lane & 48) | 4);   // t[row][100]
    int src = (lane & 48) | row;                       // lane with e-key == row
    float dgir = __shfl(dgi, src);
    float dgxr = __shfl(dgx, src);
    int rar = __shfl(ra, src), rpr = __shfl(rp, src);
    int rcr = __shfl(rc, src), rrr = __shfl(rr, src);
    float invp = 1.f / fmaxf(sqrtf(pr), 1e-12f);
    float t1 = (dgir*invp)*(dw1r*invp);
    float t2 = (dgxr*RINV[rar])*RVW2[rar];
    float bb = P[(size_t)rrr*4+0] - 2.f*t1 + P[(size_t)rpr*4+1] - 2.f*t2 + P[(size_t)rcr*4+2];
    bb = leaky(bb);
    if (ep == 0){
      BBUF[blockIdx.x*64 + wid*16 + row] = bb;
      atomicMax(&BMAXU[rpr], encf(bb));
    }
  }
}

// ---- level-1 pass 1 ----
__global__ __launch_bounds__(256) void k_pass1_l1(
    const float* __restrict__ relT, const int* __restrict__ rel1i,
    const int* __restrict__ par, const int* __restrict__ chi, const int* __restrict__ roo,
    const float* __restrict__ G, const float* __restrict__ P,
    const float* __restrict__ RINV, const float* __restrict__ RVW1, const float* __restrict__ RVW2,
    float* __restrict__ BBUF, unsigned* __restrict__ BMAXU){
  int lane = threadIdx.x & 63;
  int e = (blockIdx.x*256 + threadIdx.x) >> 6;
  if (e >= E1) return;
  int r = rel1i[e], pp = par[e], cc = chi[e], ii = roo[e];
  const float* rrow = relT + r*RD;
  const float* gI = G + (size_t)ii*RD;
  const float* gX = G + (size_t)pp*RD;
  float ai = rrow[lane]*gI[lane];
  float ax = rrow[lane]*gX[lane];
  if (lane < 36){
    ai += rrow[lane+64]*gI[lane+64];
    ax += rrow[lane+64]*gX[lane+64];
  }
  float dgi = wred(ai), dgx = wred(ax);
  if (lane == 0){
    float invn = RINV[r];
    float b = P[(size_t)ii*4+0] - 2.f*(dgi*invn)*RVW1[r]
            + P[(size_t)pp*4+1] - 2.f*(dgx*invn)*RVW2[r]
            + P[(size_t)cc*4+2];
    b = leaky(b);
    BBUF[e] = b;
    atomicMax(&BMAXU[pp], encf(b));
  }
}

// ---- pass 2: exp(b - max) and segment sum ----
__global__ void k_pass2(const int* __restrict__ par, const float* __restrict__ BBUF,
    const unsigned* __restrict__ BMAXU, float* __restrict__ BEXP, float* __restrict__ BSUM, int E){
  int e = blockIdx.x*blockDim.x + threadIdx.x;
  if (e >= E) return;
  int p = par[e];
  float m = decf(BMAXU[p]);
  float ex = expf(BBUF[e]-m);
  BEXP[e] = ex;
  atomicAdd(&BSUM[p], ex);
}

// ---- pass 3: upd = (e_y - 2 v_k (v_k.e_y)) * a, atomicAdd into AGG[parent] ----
__global__ __launch_bounds__(256) void k_pass3(const int* __restrict__ relI,
    const int* __restrict__ par, const int* __restrict__ chi,
    const float* __restrict__ V, const float* __restrict__ Esrc,
    const float* __restrict__ BEXP, const float* __restrict__ BSUM,
    float* __restrict__ AGG, int E){
  int lane = threadIdx.x & 63;
  int e = (blockIdx.x*256 + threadIdx.x) >> 6;
  if (e >= E) return;
  int p = par[e], y = chi[e], r = relI[e];
  float a = BEXP[e] / fmaxf(BSUM[p], 1e-10f);
  const float* vr = V + (size_t)r*D;
  const float* ey = Esrc + (size_t)y*D;
  float vv[5], ee[5];
  #pragma unroll
  for (int qq=0;qq<5;++qq){
    int d = lane + 64*qq;
    if (d < D){ vv[qq]=vr[d]; ee[qq]=ey[d]; } else { vv[qq]=0.f; ee[qq]=0.f; }
  }
  float part = 0.f;
  #pragma unroll
  for (int qq=0;qq<5;++qq) part += vv[qq]*ee[qq];
  float dk = wred(part);
  float s2 = 2.f*dk;
  float* ap = AGG + (size_t)p*D;
  #pragma unroll
  for (int qq=0;qq<5;++qq){
    int d = lane + 64*qq;
    if (d < D) atomicAdd(&ap[d], (ee[qq] - s2*vv[qq])*a);
  }
}

// ---- apply: EA = leaky(In + AGG), plus bf16 copy into Xb (padded) ----
__global__ void k_apply(const float* __restrict__ In, const float* __restrict__ AGG,
                        float* __restrict__ EA, unsigned short* __restrict__ Xb){
  int total = N_NODES*75;
  for (int i = blockIdx.x*blockDim.x + threadIdx.x; i < total; i += gridDim.x*blockDim.x){
    float4 x = ((const float4*)In)[i];
    float4 y = ((const float4*)AGG)[i];
    float4 o;
    o.x = leaky(x.x+y.x); o.y = leaky(x.y+y.y); o.z = leaky(x.z+y.z); o.w = leaky(x.w+y.w);
    ((float4*)EA)[i] = o;
    int row = i/75, c4 = (i%75)*4;
    us4 b4; b4[0]=f2b(o.x); b4[1]=f2b(o.y); b4[2]=f2b(o.z); b4[3]=f2b(o.w);
    *(us4*)(Xb + (size_t)row*320 + c4) = b4;
  }
}

// ---- output gather ----
__global__ __launch_bounds__(256) void k_out(const int* __restrict__ ro, const float* __restrict__ EA,
    const float* __restrict__ AGG, float* __restrict__ out){
  int lane = threadIdx.x & 63;
  int o = (blockIdx.x*256 + threadIdx.x) >> 6;
  if (o >= NB) return;
  int n = ro[o];
  const float* ea = EA + (size_t)n*D;
  const float* ag = AGG + (size_t)n*D;
  float* op = out + (size_t)o*D;
  #pragma unroll
  for (int qq=0;qq<5;++qq){
    int d = lane + 64*qq;
    if (d < D) op[d] = leaky(ea[d]+ag[d]);
  }
}

extern "C" void kernel_launch(void* const* d_in, const int* in_sizes, int n_in,
                              void* d_out, int out_size, void* d_ws, size_t ws_size,
                              hipStream_t stream){
  const float* node = (const float*)d_in[0];
  const float* relT = (const float*)d_in[1];
  const float* W    = (const float*)d_in[2];
  const float* watt = (const float*)d_in[3];
  const int* par2 = (const int*)d_in[4];
  const int* chi2 = (const int*)d_in[5];
  const int* roo2 = (const int*)d_in[6];
  const int* rel2i = (const int*)d_in[7];
  const int* relrp2 = (const int*)d_in[8];
  const int* par1 = (const int*)d_in[9];
  const int* chi1 = (const int*)d_in[10];
  const int* roo1 = (const int*)d_in[11];
  const int* rel1i = (const int*)d_in[12];
  const int* roout = (const int*)d_in[13];

  char* w = (char*)d_ws;
  size_t off = 0;
  auto alloc = [&](size_t bytes)->void*{ void* p = w + off; off += (bytes + 255) & ~(size_t)255; return p; };
  float* EA   = (float*)alloc((size_t)N_NODES*D*4);
  float* AGG  = (float*)alloc((size_t)N_NODES*D*4);
  float* G    = (float*)alloc((size_t)N_NODES*RD*4);
  float* P    = (float*)alloc((size_t)N_NODES*4*4);
  float* V    = (float*)alloc((size_t)NREL*D*4);
  float* RINV = (float*)alloc(NREL*4);
  float* RVW1 = (float*)alloc(NREL*4);
  float* RVW2 = (float*)alloc(NREL*4);
  float* M    = (float*)alloc(RD*RD*4);
  float* W1P  = (float*)alloc(RD*4);
  float* BBUF = (float*)alloc((size_t)E2*4);
  float* BEXP = (float*)alloc((size_t)E2*4);
  unsigned* BMAXU = (unsigned*)alloc((size_t)N_NODES*4);
  float* BSUM = (float*)alloc((size_t)N_NODES*4);
  unsigned short* Xb = (unsigned short*)alloc((size_t)NPAD*320*2);
  unsigned short* Bt = (unsigned short*)alloc((size_t)112*320*2);
  unsigned short* MbT = (unsigned short*)alloc((size_t)112*128*2);

  // constants (rel_table / W_proj / w_att are static inputs)
  k_const<<<dim3(40), dim3(256), 0, stream>>>(W, watt, M, W1P);
  k_prep<<<dim3(140), dim3(256), 0, stream>>>(W, watt, Bt);
  k_prep2<<<dim3(56), dim3(256), 0, stream>>>(M, W1P, MbT);
  k_rel<<<dim3(NREL), dim3(64), 0, stream>>>(relT, W, watt, V, RINV, RVW1, RVW2);

  // ---------- level 2 ----------
  hipMemsetAsync(BMAXU, 0, (size_t)N_NODES*4, stream);
  hipMemsetAsync(BSUM, 0, (size_t)N_NODES*4, stream);
  hipMemsetAsync(AGG, 0, (size_t)N_NODES*D*4, stream);
  k_cast<<<dim3(2048), dim3(256), 0, stream>>>(node, Xb);
  k_nodetab2<<<dim3((N_NODES+127)/128), dim3(256), 0, stream>>>(Xb, Bt, G, P);
  k_pass1_l2<<<dim3(E2/64), dim3(256), 0, stream>>>(relT, rel2i, relrp2, par2, chi2, roo2,
                                                    G, P, MbT, RINV, RVW2, BBUF, BMAXU);
  k_pass2<<<dim3((E2+255)/256), dim3(256), 0, stream>>>(par2, BBUF, BMAXU, BEXP, BSUM, E2);
  k_pass3<<<dim3((E2+3)/4), dim3(256), 0, stream>>>(rel2i, par2, chi2, V, node, BEXP, BSUM, AGG, E2);
  k_apply<<<dim3(2048), dim3(256), 0, stream>>>(node, AGG, EA, Xb);

  // ---------- level 1 ----------
  hipMemsetAsync(BMAXU, 0, (size_t)N_NODES*4, stream);
  hipMemsetAsync(BSUM, 0, (size_t)N_NODES*4, stream);
  hipMemsetAsync(AGG, 0, (size_t)N_NODES*D*4, stream);
  k_nodetab2<<<dim3((N_NODES+127)/128), dim3(256), 0, stream>>>(Xb, Bt, G, P);
  k_pass1_l1<<<dim3((E1+3)/4), dim3(256), 0, stream>>>(relT, rel1i, par1, chi1, roo1,
                                                       G, P, RINV, RVW1, RVW2, BBUF, BMAXU);
  k_pass2<<<dim3((E1+255)/256), dim3(256), 0, stream>>>(par1, BBUF, BMAXU, BEXP, BSUM, E1);
  k_pass3<<<dim3((E1+3)/4), dim3(256), 0, stream>>>(rel1i, par1, chi1, V, EA, BEXP, BSUM, AGG, E1);
  k_out<<<dim3((NB+3)/4), dim3(256), 0, stream>>>(roout, EA, AGG, (float*)d_out);
}

// Round 4
// 713.531 us; speedup vs baseline: 1.9499x; 1.2715x over previous
//
#include <hip/hip_runtime.h>
#include <hip/hip_bf16.h>
#include <cstdint>

#define N_NODES 100000
#define NPAD 100096
#define D 300
#define RD 100
#define NREL 1000
#define E2 200000
#define E1 100000
#define NB 8192
#define NEG 0.2f
#define SCAN_BLKS 391   // ceil(100000/256)

typedef __bf16 bf16x8 __attribute__((ext_vector_type(8)));
typedef float f32x4 __attribute__((ext_vector_type(4)));
typedef unsigned short us4 __attribute__((ext_vector_type(4)));
typedef unsigned short us8 __attribute__((ext_vector_type(8)));

__device__ __forceinline__ float leaky(float x){ return x >= 0.f ? x : NEG*x; }

__device__ __forceinline__ unsigned short f2b(float v){
  unsigned u = __float_as_uint(v);
  unsigned r = u + 0x7FFF + ((u>>16)&1u);
  return (unsigned short)(r>>16);
}
__device__ __forceinline__ float b2f(unsigned short b){
  return __uint_as_float(((unsigned)b) << 16);
}
__device__ __forceinline__ float wred(float v){
  #pragma unroll
  for (int m = 32; m >= 1; m >>= 1) v += __shfl_xor(v, m, 64);
  return v;
}

// ---- constants: M = W^T W (100x100), W1P = W^T w1 (100) ----
__global__ void k_const(const float* __restrict__ W, const float* __restrict__ watt,
                        float* __restrict__ M, float* __restrict__ W1P){
  int t = blockIdx.x*blockDim.x + threadIdx.x;
  if (t < RD*RD){
    int i = t / RD, j = t % RD;
    float acc = 0.f;
    for (int d = 0; d < D; ++d) acc += W[d*RD+i]*W[d*RD+j];
    M[t] = acc;
  } else if (t < RD*RD + RD){
    int j = t - RD*RD;
    float acc = 0.f;
    for (int d = 0; d < D; ++d) acc += watt[d]*W[d*RD+j];
    W1P[j] = acc;
  }
}

// ---- Bt[112][320] bf16 = [W | w1 w2 w3 | 0]^T, K padded to 320 ----
__global__ void k_prep(const float* __restrict__ W, const float* __restrict__ watt,
                       unsigned short* __restrict__ Bt){
  int u = blockIdx.x*blockDim.x + threadIdx.x;
  if (u >= 112*320) return;
  int c = u / 320, k = u % 320;
  float v = 0.f;
  if (k < D){
    if (c < RD) v = W[k*RD + c];
    else if (c < RD+3) v = watt[(c-RD)*D + k];
  }
  Bt[u] = f2b(v);
}

// ---- MbT[112][128] bf16: rows j=0..99 -> M[j][i] (symmetric), row 100 -> W1P ----
__global__ void k_prep2(const float* __restrict__ M, const float* __restrict__ W1P,
                        unsigned short* __restrict__ MbT){
  int u = blockIdx.x*blockDim.x + threadIdx.x;
  if (u >= 112*128) return;
  int j = u >> 7, i = u & 127;
  float v = 0.f;
  if (i < RD){
    if (j < RD) v = M[j*RD + i];
    else if (j == RD) v = W1P[i];
  }
  MbT[u] = f2b(v);
}

// ---- cast node embeddings to padded bf16 table Xb[NPAD][320] ----
__global__ void k_cast(const float* __restrict__ src, unsigned short* __restrict__ dst){
  int total = NPAD*40;
  for (int u = blockIdx.x*blockDim.x + threadIdx.x; u < total; u += gridDim.x*blockDim.x){
    int row = u/40, c8 = (u%40)*8;
    us8 o;
    if (row < N_NODES && c8 <= 292){
      float4 x = *(const float4*)(src + (size_t)row*D + c8);
      float4 y = *(const float4*)(src + (size_t)row*D + c8 + 4);
      o[0]=f2b(x.x); o[1]=f2b(x.y); o[2]=f2b(x.z); o[3]=f2b(x.w);
      o[4]=f2b(y.x); o[5]=f2b(y.y); o[6]=f2b(y.z); o[7]=f2b(y.w);
    } else {
      #pragma unroll
      for (int j=0;j<8;++j){
        int c = c8+j;
        float v = (row < N_NODES && c < D) ? src[(size_t)row*D + c] : 0.f;
        o[j] = f2b(v);
      }
    }
    *(us8*)(dst + (size_t)row*320 + c8) = o;
  }
}

// ---- per-relation: V[r]=normalize(W r), RINV, RVW1=V.w1, RVW2=V.w2 ----
__global__ __launch_bounds__(64) void k_rel(const float* __restrict__ relT, const float* __restrict__ W,
    const float* __restrict__ watt, float* __restrict__ V, float* __restrict__ RINV,
    float* __restrict__ RVW1, float* __restrict__ RVW2){
  __shared__ float rl_[RD];
  __shared__ float ul[D];
  int r = blockIdx.x, lane = threadIdx.x;
  for (int j = lane; j < RD; j += 64) rl_[j] = relT[r*RD+j];
  __syncthreads();
  float nrm2 = 0.f;
  for (int d = 0; d < D; ++d){
    float part = 0.f;
    for (int j = lane; j < RD; j += 64) part += W[d*RD+j]*rl_[j];
    float s = wred(part);
    if (lane == 0) ul[d] = s;
    nrm2 += s*s;
  }
  float invn = 1.f / fmaxf(sqrtf(nrm2), 1e-12f);
  __syncthreads();
  float pw1 = 0.f, pw2 = 0.f;
  for (int d = lane; d < D; d += 64){
    float vd = ul[d]*invn;
    V[r*D+d] = vd;
    pw1 += vd*watt[d];
    pw2 += vd*watt[D+d];
  }
  pw1 = wred(pw1); pw2 = wred(pw2);
  if (lane == 0){ RINV[r] = invn; RVW1[r] = pw1; RVW2[r] = pw2; }
}

// ---- MFMA node tables: G[n] = W^T e_n (100), P[n] = {e.w1, e.w2, e.w3, 0} ----
__global__ __launch_bounds__(256) void k_nodetab2(const unsigned short* __restrict__ Eb,
    const unsigned short* __restrict__ Bt, float* __restrict__ G, float* __restrict__ P){
  int lane = threadIdx.x & 63, wid = threadIdx.x >> 6;
  int n0 = blockIdx.x*128;
  size_t a0 = (size_t)(n0 + wid*32 + (lane&15))*320 + ((lane>>4)*8);
  size_t b0 = (size_t)(lane&15)*320 + ((lane>>4)*8);
  f32x4 acc[2][7];
  #pragma unroll
  for (int s=0;s<2;++s)
    #pragma unroll
    for (int c=0;c<7;++c) acc[s][c] = (f32x4){0.f,0.f,0.f,0.f};
  for (int ks = 0; ks < 10; ++ks){
    bf16x8 a0f = *(const bf16x8*)(Eb + a0 + ks*32);
    bf16x8 a1f = *(const bf16x8*)(Eb + a0 + 16*320 + ks*32);
    #pragma unroll
    for (int cf=0; cf<7; ++cf){
      bf16x8 bf = *(const bf16x8*)(Bt + b0 + (size_t)cf*16*320 + ks*32);
      acc[0][cf] = __builtin_amdgcn_mfma_f32_16x16x32_bf16(a0f, bf, acc[0][cf], 0, 0, 0);
      acc[1][cf] = __builtin_amdgcn_mfma_f32_16x16x32_bf16(a1f, bf, acc[1][cf], 0, 0, 0);
    }
  }
  int rbase = n0 + wid*32 + ((lane>>4)<<2);
  int cbase = lane & 15;
  #pragma unroll
  for (int sub=0; sub<2; ++sub){
    #pragma unroll
    for (int cf=0; cf<7; ++cf){
      int col = cf*16 + cbase;
      #pragma unroll
      for (int r=0; r<4; ++r){
        int row = rbase + sub*16 + r;
        if (row < N_NODES){
          float v = acc[sub][cf][r];
          if (col < RD) G[(size_t)row*RD + col] = v;
          else if (col < RD+3) P[(size_t)row*4 + (col-RD)] = v;
        }
      }
    }
  }
}

// ---- level-2 pass 1 (MFMA): logits + parent histogram ----
__global__ __launch_bounds__(256) void k_pass1_l2(
    const float* __restrict__ relT, const int* __restrict__ rel2i, const int* __restrict__ relrp2,
    const int* __restrict__ par, const int* __restrict__ chi, const int* __restrict__ roo,
    const float* __restrict__ G, const float* __restrict__ P,
    const unsigned short* __restrict__ MbT,
    const float* __restrict__ RINV, const float* __restrict__ RVW2,
    float* __restrict__ BBUF, int* __restrict__ CNT){
  __shared__ unsigned short Cl[4*16*136];
  int lane = threadIdx.x & 63, wid = threadIdx.x >> 6;
  int ep = lane & 15, g = lane >> 4;
  unsigned short* cw = Cl + wid*16*136;
  int e = blockIdx.x*64 + wid*16 + ep;
  int ra = rel2i[e], rb = relrp2[e], rp = par[e], rc = chi[e], rr = roo[e];
  const float* rA = relT + (size_t)ra*RD;
  const float* rB = relT + (size_t)rb*RD;
  const float* gR = G + (size_t)rr*RD;
  const float* gX = G + (size_t)rp*RD;
  float dgi = 0.f, dgx = 0.f;
  bf16x8 af[4];
  #pragma unroll
  for (int ks=0; ks<4; ++ks){
    us8 cpack;
    #pragma unroll
    for (int h=0; h<2; ++h){
      int k0 = g*8 + ks*32 + h*4;
      float4 a4 = make_float4(0.f,0.f,0.f,0.f), b4 = a4, grr = a4, grp = a4;
      if (k0 <= 96){
        a4  = *(const float4*)(rA + k0);
        b4  = *(const float4*)(rB + k0);
        grr = *(const float4*)(gR + k0);
        grp = *(const float4*)(gX + k0);
      }
      float4 c4;
      c4.x = a4.x*b4.x; c4.y = a4.y*b4.y; c4.z = a4.z*b4.z; c4.w = a4.w*b4.w;
      dgi += c4.x*grr.x + c4.y*grr.y + c4.z*grr.z + c4.w*grr.w;
      dgx += a4.x*grp.x + a4.y*grp.y + a4.z*grp.z + a4.w*grp.w;
      cpack[h*4+0]=f2b(c4.x); cpack[h*4+1]=f2b(c4.y); cpack[h*4+2]=f2b(c4.z); cpack[h*4+3]=f2b(c4.w);
    }
    *(us8*)((char*)cw + ep*272 + g*16 + ks*64) = cpack;
    af[ks] = *(bf16x8*)&cpack;
  }
  f32x4 acc[7];
  #pragma unroll
  for (int cf=0; cf<7; ++cf) acc[cf] = (f32x4){0.f,0.f,0.f,0.f};
  #pragma unroll
  for (int cf=0; cf<7; ++cf){
    #pragma unroll
    for (int ks=0; ks<4; ++ks){
      bf16x8 bfr = *(const bf16x8*)(MbT + (size_t)(cf*16+ep)*128 + g*8 + ks*32);
      acc[cf] = __builtin_amdgcn_mfma_f32_16x16x32_bf16(af[ks], bfr, acc[cf], 0, 0, 0);
    }
  }
  dgi += __shfl_xor(dgi, 16); dgi += __shfl_xor(dgi, 32);
  dgx += __shfl_xor(dgx, 16); dgx += __shfl_xor(dgx, 32);
  __syncthreads();
  #pragma unroll
  for (int r=0; r<4; ++r){
    int row = g*4 + r;
    float pr = 0.f;
    #pragma unroll
    for (int cf=0; cf<7; ++cf)
      pr += b2f(cw[row*136 + cf*16 + ep]) * acc[cf][r];
    pr += __shfl_xor(pr, 1); pr += __shfl_xor(pr, 2);
    pr += __shfl_xor(pr, 4); pr += __shfl_xor(pr, 8);
    float dw1r = __shfl(acc[6][r], (lane & 48) | 4);   // t[row][100]
    int src = (lane & 48) | row;
    float dgir = __shfl(dgi, src);
    float dgxr = __shfl(dgx, src);
    int rar = __shfl(ra, src), rpr = __shfl(rp, src);
    int rcr = __shfl(rc, src), rrr = __shfl(rr, src);
    float invp = 1.f / fmaxf(sqrtf(pr), 1e-12f);
    float t1 = (dgir*invp)*(dw1r*invp);
    float t2 = (dgxr*RINV[rar])*RVW2[rar];
    float bb = P[(size_t)rrr*4+0] - 2.f*t1 + P[(size_t)rpr*4+1] - 2.f*t2 + P[(size_t)rcr*4+2];
    bb = leaky(bb);
    if (ep == 0){
      BBUF[blockIdx.x*64 + wid*16 + row] = bb;
      atomicAdd(&CNT[rpr], 1);
    }
  }
}

// ---- level-1 pass 1: logits + parent histogram ----
__global__ __launch_bounds__(256) void k_pass1_l1(
    const float* __restrict__ relT, const int* __restrict__ rel1i,
    const int* __restrict__ par, const int* __restrict__ chi, const int* __restrict__ roo,
    const float* __restrict__ G, const float* __restrict__ P,
    const float* __restrict__ RINV, const float* __restrict__ RVW1, const float* __restrict__ RVW2,
    float* __restrict__ BBUF, int* __restrict__ CNT){
  int lane = threadIdx.x & 63;
  int e = (blockIdx.x*256 + threadIdx.x) >> 6;
  if (e >= E1) return;
  int r = rel1i[e], pp = par[e], cc = chi[e], ii = roo[e];
  const float* rrow = relT + r*RD;
  const float* gI = G + (size_t)ii*RD;
  const float* gX = G + (size_t)pp*RD;
  float ai = rrow[lane]*gI[lane];
  float ax = rrow[lane]*gX[lane];
  if (lane < 36){
    ai += rrow[lane+64]*gI[lane+64];
    ax += rrow[lane+64]*gX[lane+64];
  }
  float dgi = wred(ai), dgx = wred(ax);
  if (lane == 0){
    float invn = RINV[r];
    float b = P[(size_t)ii*4+0] - 2.f*(dgi*invn)*RVW1[r]
            + P[(size_t)pp*4+1] - 2.f*(dgx*invn)*RVW2[r]
            + P[(size_t)cc*4+2];
    b = leaky(b);
    BBUF[e] = b;
    atomicAdd(&CNT[pp], 1);
  }
}

// ---- CSR build: exclusive scan over CNT ----
__global__ __launch_bounds__(256) void k_scan_a(const int* __restrict__ CNT,
    int* __restrict__ ROFF, int* __restrict__ PART){
  __shared__ int ls[256];
  int i = blockIdx.x*256 + threadIdx.x;
  int v = (i < N_NODES) ? CNT[i] : 0;
  ls[threadIdx.x] = v;
  __syncthreads();
  for (int off=1; off<256; off<<=1){
    int t = (threadIdx.x >= off) ? ls[threadIdx.x-off] : 0;
    __syncthreads();
    ls[threadIdx.x] += t;
    __syncthreads();
  }
  int incl = ls[threadIdx.x];
  if (i < N_NODES) ROFF[i] = incl - v;
  if (threadIdx.x == 255) PART[blockIdx.x] = incl;
}
__global__ __launch_bounds__(512) void k_scan_b(int* __restrict__ PART){
  __shared__ int ls[512];
  int v = (threadIdx.x < SCAN_BLKS) ? PART[threadIdx.x] : 0;
  ls[threadIdx.x] = v;
  __syncthreads();
  for (int off=1; off<512; off<<=1){
    int t = (threadIdx.x >= off) ? ls[threadIdx.x-off] : 0;
    __syncthreads();
    ls[threadIdx.x] += t;
    __syncthreads();
  }
  if (threadIdx.x < SCAN_BLKS) PART[threadIdx.x] = ls[threadIdx.x] - v;
}
__global__ __launch_bounds__(256) void k_scan_c(int* __restrict__ ROFF, const int* __restrict__ PART){
  int i = blockIdx.x*256 + threadIdx.x;
  if (i < N_NODES) ROFF[i] += PART[blockIdx.x];
}
__global__ void k_scatter(const int* __restrict__ par, const int* __restrict__ ROFF,
                          int* __restrict__ CUR, int* __restrict__ EIDX, int E){
  int e = blockIdx.x*blockDim.x + threadIdx.x;
  if (e >= E) return;
  int p = par[e];
  int pos = ROFF[p] + atomicAdd(&CUR[p], 1);
  EIDX[pos] = e;
}

// ---- fused softmax + aggregate + apply: one wave per parent ----
template<int WXB>
__global__ __launch_bounds__(256) void k_agg(const int* __restrict__ ROFF, const int* __restrict__ CNT,
    const int* __restrict__ EIDX, const float* __restrict__ BBUF,
    const int* __restrict__ chi, const int* __restrict__ relI,
    const float* __restrict__ V, const float* __restrict__ Esrc, const float* __restrict__ In,
    float* __restrict__ Out, unsigned short* __restrict__ Xb){
  int lane = threadIdx.x & 63;
  int p = (blockIdx.x*256 + threadIdx.x) >> 6;
  if (p >= N_NODES) return;
  float acc[5] = {0.f,0.f,0.f,0.f,0.f};
  int cnt = CNT[p];
  if (cnt > 0){
    int base = ROFF[p];
    float m = -1e30f;
    for (int i=0;i<cnt;++i) m = fmaxf(m, BBUF[EIDX[base+i]]);
    float s = 0.f;
    for (int i=0;i<cnt;++i) s += __expf(BBUF[EIDX[base+i]] - m);
    float inv = 1.f / fmaxf(s, 1e-10f);
    for (int i=0;i<cnt;++i){
      int eid = EIDX[base+i];
      float a = __expf(BBUF[eid]-m)*inv;
      int y = chi[eid], r = relI[eid];
      const float* vr = V + (size_t)r*D;
      const float* ey = Esrc + (size_t)y*D;
      float vv[5], ee[5];
      #pragma unroll
      for (int q=0;q<5;++q){
        int d = lane + 64*q;
        vv[q] = (d<D)?vr[d]:0.f; ee[q] = (d<D)?ey[d]:0.f;
      }
      float part = 0.f;
      #pragma unroll
      for (int q=0;q<5;++q) part += vv[q]*ee[q];
      float dk = wred(part);
      float s2 = 2.f*dk*a;
      #pragma unroll
      for (int q=0;q<5;++q) acc[q] += ee[q]*a - s2*vv[q];
    }
  }
  const float* in = In + (size_t)p*D;
  float* op = Out + (size_t)p*D;
  #pragma unroll
  for (int q=0;q<5;++q){
    int d = lane + 64*q;
    if (d < D){
      float o = leaky(in[d] + acc[q]);
      op[d] = o;
      if (WXB) Xb[(size_t)p*320 + d] = f2b(o);
    }
  }
}

// ---- output gather ----
__global__ __launch_bounds__(256) void k_out(const int* __restrict__ ro, const float* __restrict__ FIN,
    float* __restrict__ out){
  int lane = threadIdx.x & 63;
  int o = (blockIdx.x*256 + threadIdx.x) >> 6;
  if (o >= NB) return;
  int n = ro[o];
  const float* f = FIN + (size_t)n*D;
  float* op = out + (size_t)o*D;
  #pragma unroll
  for (int qq=0;qq<5;++qq){
    int d = lane + 64*qq;
    if (d < D) op[d] = f[d];
  }
}

extern "C" void kernel_launch(void* const* d_in, const int* in_sizes, int n_in,
                              void* d_out, int out_size, void* d_ws, size_t ws_size,
                              hipStream_t stream){
  const float* node = (const float*)d_in[0];
  const float* relT = (const float*)d_in[1];
  const float* W    = (const float*)d_in[2];
  const float* watt = (const float*)d_in[3];
  const int* par2 = (const int*)d_in[4];
  const int* chi2 = (const int*)d_in[5];
  const int* roo2 = (const int*)d_in[6];
  const int* rel2i = (const int*)d_in[7];
  const int* relrp2 = (const int*)d_in[8];
  const int* par1 = (const int*)d_in[9];
  const int* chi1 = (const int*)d_in[10];
  const int* roo1 = (const int*)d_in[11];
  const int* rel1i = (const int*)d_in[12];
  const int* roout = (const int*)d_in[13];

  char* w = (char*)d_ws;
  size_t off = 0;
  auto alloc = [&](size_t bytes)->void*{ void* p = w + off; off += (bytes + 255) & ~(size_t)255; return p; };
  float* EA   = (float*)alloc((size_t)N_NODES*D*4);
  float* FIN  = (float*)alloc((size_t)N_NODES*D*4);
  float* G    = (float*)alloc((size_t)N_NODES*RD*4);
  float* P    = (float*)alloc((size_t)N_NODES*4*4);
  float* V    = (float*)alloc((size_t)NREL*D*4);
  float* RINV = (float*)alloc(NREL*4);
  float* RVW1 = (float*)alloc(NREL*4);
  float* RVW2 = (float*)alloc(NREL*4);
  float* M    = (float*)alloc(RD*RD*4);
  float* W1P  = (float*)alloc(RD*4);
  float* BBUF = (float*)alloc((size_t)E2*4);
  unsigned short* Xb = (unsigned short*)alloc((size_t)NPAD*320*2);
  unsigned short* Bt = (unsigned short*)alloc((size_t)112*320*2);
  unsigned short* MbT = (unsigned short*)alloc((size_t)112*128*2);
  int* CNT  = (int*)alloc((size_t)N_NODES*4);
  int* ROFF = (int*)alloc((size_t)N_NODES*4);
  int* CUR  = (int*)alloc((size_t)N_NODES*4);
  int* PART = (int*)alloc(512*4);
  int* EIDX = (int*)alloc((size_t)E2*4);

  // constants
  k_const<<<dim3(40), dim3(256), 0, stream>>>(W, watt, M, W1P);
  k_prep<<<dim3(140), dim3(256), 0, stream>>>(W, watt, Bt);
  k_prep2<<<dim3(56), dim3(256), 0, stream>>>(M, W1P, MbT);
  k_rel<<<dim3(NREL), dim3(64), 0, stream>>>(relT, W, watt, V, RINV, RVW1, RVW2);

  // ---------- level 2 ----------
  hipMemsetAsync(CNT, 0, (size_t)N_NODES*4, stream);
  hipMemsetAsync(CUR, 0, (size_t)N_NODES*4, stream);
  k_cast<<<dim3(2048), dim3(256), 0, stream>>>(node, Xb);
  k_nodetab2<<<dim3((N_NODES+127)/128), dim3(256), 0, stream>>>(Xb, Bt, G, P);
  k_pass1_l2<<<dim3(E2/64), dim3(256), 0, stream>>>(relT, rel2i, relrp2, par2, chi2, roo2,
                                                    G, P, MbT, RINV, RVW2, BBUF, CNT);
  k_scan_a<<<dim3(SCAN_BLKS), dim3(256), 0, stream>>>(CNT, ROFF, PART);
  k_scan_b<<<dim3(1), dim3(512), 0, stream>>>(PART);
  k_scan_c<<<dim3(SCAN_BLKS), dim3(256), 0, stream>>>(ROFF, PART);
  k_scatter<<<dim3((E2+255)/256), dim3(256), 0, stream>>>(par2, ROFF, CUR, EIDX, E2);
  k_agg<1><<<dim3((N_NODES+3)/4), dim3(256), 0, stream>>>(ROFF, CNT, EIDX, BBUF,
                                                          chi2, rel2i, V, node, node, EA, Xb);

  // ---------- level 1 ----------
  hipMemsetAsync(CNT, 0, (size_t)N_NODES*4, stream);
  hipMemsetAsync(CUR, 0, (size_t)N_NODES*4, stream);
  k_nodetab2<<<dim3((N_NODES+127)/128), dim3(256), 0, stream>>>(Xb, Bt, G, P);
  k_pass1_l1<<<dim3((E1+3)/4), dim3(256), 0, stream>>>(relT, rel1i, par1, chi1, roo1,
                                                       G, P, RINV, RVW1, RVW2, BBUF, CNT);
  k_scan_a<<<dim3(SCAN_BLKS), dim3(256), 0, stream>>>(CNT, ROFF, PART);
  k_scan_b<<<dim3(1), dim3(512), 0, stream>>>(PART);
  k_scan_c<<<dim3(SCAN_BLKS), dim3(256), 0, stream>>>(ROFF, PART);
  k_scatter<<<dim3((E1+255)/256), dim3(256), 0, stream>>>(par1, ROFF, CUR, EIDX, E1);
  k_agg<0><<<dim3((N_NODES+3)/4), dim3(256), 0, stream>>>(ROFF, CNT, EIDX, BBUF,
                                                          chi1, rel1i, V, EA, EA, FIN, Xb);
  k_out<<<dim3((NB+3)/4), dim3(256), 0, stream>>>(roout, FIN, (float*)d_out);
}

// Round 5
// 605.146 us; speedup vs baseline: 2.2992x; 1.1791x over previous
//
#include <hip/hip_runtime.h>
#include <hip/hip_bf16.h>
#include <cstdint>

#define N_NODES 100000
#define NPAD 100096
#define D 300
#define RD 100
#define NREL 1000
#define E2 200000
#define E1 100000
#define NB 8192
#define NEG 0.2f
#define SCAN_BLKS 391   // ceil(100000/256)

typedef __bf16 bf16x8 __attribute__((ext_vector_type(8)));
typedef float f32x4 __attribute__((ext_vector_type(4)));
typedef unsigned short us4 __attribute__((ext_vector_type(4)));
typedef unsigned short us8 __attribute__((ext_vector_type(8)));

__device__ __forceinline__ float leaky(float x){ return x >= 0.f ? x : NEG*x; }

__device__ __forceinline__ unsigned short f2b(float v){
  unsigned u = __float_as_uint(v);
  unsigned r = u + 0x7FFF + ((u>>16)&1u);
  return (unsigned short)(r>>16);
}
__device__ __forceinline__ float b2f(unsigned short b){
  return __uint_as_float(((unsigned)b) << 16);
}
__device__ __forceinline__ float wred(float v){
  #pragma unroll
  for (int m = 32; m >= 1; m >>= 1) v += __shfl_xor(v, m, 64);
  return v;
}

// ---- constants: M = W^T W (100x100), W1P = W^T w1 (100) ----
__global__ void k_const(const float* __restrict__ W, const float* __restrict__ watt,
                        float* __restrict__ M, float* __restrict__ W1P){
  int t = blockIdx.x*blockDim.x + threadIdx.x;
  if (t < RD*RD){
    int i = t / RD, j = t % RD;
    float acc = 0.f;
    for (int d = 0; d < D; ++d) acc += W[d*RD+i]*W[d*RD+j];
    M[t] = acc;
  } else if (t < RD*RD + RD){
    int j = t - RD*RD;
    float acc = 0.f;
    for (int d = 0; d < D; ++d) acc += watt[d]*W[d*RD+j];
    W1P[j] = acc;
  }
}

// ---- Bt[112][320] bf16 = [W | w1 w2 w3 | 0]^T, K padded to 320 ----
__global__ void k_prep(const float* __restrict__ W, const float* __restrict__ watt,
                       unsigned short* __restrict__ Bt){
  int u = blockIdx.x*blockDim.x + threadIdx.x;
  if (u >= 112*320) return;
  int c = u / 320, k = u % 320;
  float v = 0.f;
  if (k < D){
    if (c < RD) v = W[k*RD + c];
    else if (c < RD+3) v = watt[(c-RD)*D + k];
  }
  Bt[u] = f2b(v);
}

// ---- MbT[112][128] bf16: rows j=0..99 -> M[j][i] (symmetric), row 100 -> W1P ----
__global__ void k_prep2(const float* __restrict__ M, const float* __restrict__ W1P,
                        unsigned short* __restrict__ MbT){
  int u = blockIdx.x*blockDim.x + threadIdx.x;
  if (u >= 112*128) return;
  int j = u >> 7, i = u & 127;
  float v = 0.f;
  if (i < RD){
    if (j < RD) v = M[j*RD + i];
    else if (j == RD) v = W1P[i];
  }
  MbT[u] = f2b(v);
}

// ---- WtB[304][128] bf16: row d = W[d][0..99], zero-padded ----
__global__ void k_prep3(const float* __restrict__ W, unsigned short* __restrict__ WtB){
  int u = blockIdx.x*blockDim.x + threadIdx.x;
  if (u >= 304*128) return;
  int dd = u >> 7, k = u & 127;
  float v = (dd < D && k < RD) ? W[dd*RD + k] : 0.f;
  WtB[u] = f2b(v);
}

// ---- Rb[1024][128] bf16: relation table rows, zero-padded ----
__global__ void k_castrel(const float* __restrict__ relT, unsigned short* __restrict__ Rb){
  int u = blockIdx.x*blockDim.x + threadIdx.x;   // one us8 per thread
  if (u >= 1024*16) return;
  int row = u >> 4, c8 = (u & 15)*8;
  us8 o;
  #pragma unroll
  for (int j=0;j<8;++j){
    int c = c8+j;
    o[j] = (row < NREL && c < RD) ? f2b(relT[row*RD + c]) : (unsigned short)0;
  }
  *(us8*)(Rb + (size_t)row*128 + c8) = o;
}

// ---- MFMA relation tables: U = Rb @ WtB^T, normalize rows -> V, RINV, RVW1, RVW2 ----
__global__ __launch_bounds__(256) void k_relmm(const unsigned short* __restrict__ Rb,
    const unsigned short* __restrict__ WtB, const float* __restrict__ watt,
    float* __restrict__ V, float* __restrict__ RINV,
    float* __restrict__ RVW1, float* __restrict__ RVW2){
  int lane = threadIdx.x & 63, wid = threadIdx.x >> 6;
  int r0 = blockIdx.x*64 + wid*16;
  int ep = lane & 15, g = lane >> 4;
  size_t a0 = (size_t)(r0 + ep)*128 + g*8;
  size_t b0 = (size_t)ep*128 + g*8;
  f32x4 acc[19];
  #pragma unroll
  for (int cf=0;cf<19;++cf) acc[cf]=(f32x4){0.f,0.f,0.f,0.f};
  #pragma unroll
  for (int ks=0; ks<4; ++ks){
    bf16x8 af = *(const bf16x8*)(Rb + a0 + ks*32);
    #pragma unroll
    for (int cf=0; cf<19; ++cf){
      bf16x8 bf = *(const bf16x8*)(WtB + b0 + (size_t)cf*16*128 + ks*32);
      acc[cf] = __builtin_amdgcn_mfma_f32_16x16x32_bf16(af, bf, acc[cf], 0, 0, 0);
    }
  }
  // per-row norm: row = r0 + g*4 + reg; its 304 cols live in lanes (g*16..g*16+15) as col=cf*16+ep
  float w1v[19], w2v[19];
  #pragma unroll
  for (int cf=0; cf<19; ++cf){
    int col = cf*16+ep;
    bool ok = col < D;
    w1v[cf] = ok ? watt[col] : 0.f;
    w2v[cf] = ok ? watt[D+col] : 0.f;
  }
  #pragma unroll
  for (int reg=0; reg<4; ++reg){
    int row = r0 + g*4 + reg;
    float np = 0.f;
    #pragma unroll
    for (int cf=0; cf<19; ++cf){ float u = acc[cf][reg]; np += u*u; }
    np += __shfl_xor(np,1); np += __shfl_xor(np,2); np += __shfl_xor(np,4); np += __shfl_xor(np,8);
    float iv = 1.f / fmaxf(sqrtf(np), 1e-12f);
    float p1 = 0.f, p2 = 0.f;
    if (row < NREL){
      #pragma unroll
      for (int cf=0; cf<19; ++cf){
        int col = cf*16+ep;
        float v = acc[cf][reg]*iv;
        if (col < D){
          V[(size_t)row*D + col] = v;
          p1 += v*w1v[cf];
          p2 += v*w2v[cf];
        }
      }
    }
    p1 += __shfl_xor(p1,1); p1 += __shfl_xor(p1,2); p1 += __shfl_xor(p1,4); p1 += __shfl_xor(p1,8);
    p2 += __shfl_xor(p2,1); p2 += __shfl_xor(p2,2); p2 += __shfl_xor(p2,4); p2 += __shfl_xor(p2,8);
    if (ep == 0 && row < NREL){
      RINV[row] = iv; RVW1[row] = p1; RVW2[row] = p2;
    }
  }
}

// ---- cast node embeddings to padded bf16 table Xb[NPAD][320] ----
__global__ void k_cast(const float* __restrict__ src, unsigned short* __restrict__ dst){
  int total = NPAD*40;
  for (int u = blockIdx.x*blockDim.x + threadIdx.x; u < total; u += gridDim.x*blockDim.x){
    int row = u/40, c8 = (u%40)*8;
    us8 o;
    if (row < N_NODES && c8 <= 292){
      float4 x = *(const float4*)(src + (size_t)row*D + c8);
      float4 y = *(const float4*)(src + (size_t)row*D + c8 + 4);
      o[0]=f2b(x.x); o[1]=f2b(x.y); o[2]=f2b(x.z); o[3]=f2b(x.w);
      o[4]=f2b(y.x); o[5]=f2b(y.y); o[6]=f2b(y.z); o[7]=f2b(y.w);
    } else {
      #pragma unroll
      for (int j=0;j<8;++j){
        int c = c8+j;
        float v = (row < N_NODES && c < D) ? src[(size_t)row*D + c] : 0.f;
        o[j] = f2b(v);
      }
    }
    *(us8*)(dst + (size_t)row*320 + c8) = o;
  }
}

// ---- MFMA node tables: G[n] = W^T e_n (100), P[n] = {e.w1, e.w2, e.w3, 0} ----
__global__ __launch_bounds__(256) void k_nodetab2(const unsigned short* __restrict__ Eb,
    const unsigned short* __restrict__ Bt, float* __restrict__ G, float* __restrict__ P){
  int lane = threadIdx.x & 63, wid = threadIdx.x >> 6;
  int n0 = blockIdx.x*128;
  size_t a0 = (size_t)(n0 + wid*32 + (lane&15))*320 + ((lane>>4)*8);
  size_t b0 = (size_t)(lane&15)*320 + ((lane>>4)*8);
  f32x4 acc[2][7];
  #pragma unroll
  for (int s=0;s<2;++s)
    #pragma unroll
    for (int c=0;c<7;++c) acc[s][c] = (f32x4){0.f,0.f,0.f,0.f};
  for (int ks = 0; ks < 10; ++ks){
    bf16x8 a0f = *(const bf16x8*)(Eb + a0 + ks*32);
    bf16x8 a1f = *(const bf16x8*)(Eb + a0 + 16*320 + ks*32);
    #pragma unroll
    for (int cf=0; cf<7; ++cf){
      bf16x8 bf = *(const bf16x8*)(Bt + b0 + (size_t)cf*16*320 + ks*32);
      acc[0][cf] = __builtin_amdgcn_mfma_f32_16x16x32_bf16(a0f, bf, acc[0][cf], 0, 0, 0);
      acc[1][cf] = __builtin_amdgcn_mfma_f32_16x16x32_bf16(a1f, bf, acc[1][cf], 0, 0, 0);
    }
  }
  int rbase = n0 + wid*32 + ((lane>>4)<<2);
  int cbase = lane & 15;
  #pragma unroll
  for (int sub=0; sub<2; ++sub){
    #pragma unroll
    for (int cf=0; cf<7; ++cf){
      int col = cf*16 + cbase;
      #pragma unroll
      for (int r=0; r<4; ++r){
        int row = rbase + sub*16 + r;
        if (row < N_NODES){
          float v = acc[sub][cf][r];
          if (col < RD) G[(size_t)row*RD + col] = v;
          else if (col < RD+3) P[(size_t)row*4 + (col-RD)] = v;
        }
      }
    }
  }
}

// ---- level-2 pass 1 (MFMA): logits + parent histogram ----
__global__ __launch_bounds__(256) void k_pass1_l2(
    const float* __restrict__ relT, const int* __restrict__ rel2i, const int* __restrict__ relrp2,
    const int* __restrict__ par, const int* __restrict__ chi, const int* __restrict__ roo,
    const float* __restrict__ G, const float* __restrict__ P,
    const unsigned short* __restrict__ MbT,
    const float* __restrict__ RINV, const float* __restrict__ RVW2,
    float* __restrict__ BBUF, int* __restrict__ CNT){
  __shared__ unsigned short Cl[4*16*136];
  int lane = threadIdx.x & 63, wid = threadIdx.x >> 6;
  int ep = lane & 15, g = lane >> 4;
  unsigned short* cw = Cl + wid*16*136;
  int e = blockIdx.x*64 + wid*16 + ep;
  int ra = rel2i[e], rb = relrp2[e], rp = par[e], rc = chi[e], rr = roo[e];
  const float* rA = relT + (size_t)ra*RD;
  const float* rB = relT + (size_t)rb*RD;
  const float* gR = G + (size_t)rr*RD;
  const float* gX = G + (size_t)rp*RD;
  float dgi = 0.f, dgx = 0.f;
  bf16x8 af[4];
  #pragma unroll
  for (int ks=0; ks<4; ++ks){
    us8 cpack;
    #pragma unroll
    for (int h=0; h<2; ++h){
      int k0 = g*8 + ks*32 + h*4;
      float4 a4 = make_float4(0.f,0.f,0.f,0.f), b4 = a4, grr = a4, grp = a4;
      if (k0 <= 96){
        a4  = *(const float4*)(rA + k0);
        b4  = *(const float4*)(rB + k0);
        grr = *(const float4*)(gR + k0);
        grp = *(const float4*)(gX + k0);
      }
      float4 c4;
      c4.x = a4.x*b4.x; c4.y = a4.y*b4.y; c4.z = a4.z*b4.z; c4.w = a4.w*b4.w;
      dgi += c4.x*grr.x + c4.y*grr.y + c4.z*grr.z + c4.w*grr.w;
      dgx += a4.x*grp.x + a4.y*grp.y + a4.z*grp.z + a4.w*grp.w;
      cpack[h*4+0]=f2b(c4.x); cpack[h*4+1]=f2b(c4.y); cpack[h*4+2]=f2b(c4.z); cpack[h*4+3]=f2b(c4.w);
    }
    *(us8*)((char*)cw + ep*272 + g*16 + ks*64) = cpack;
    af[ks] = *(bf16x8*)&cpack;
  }
  f32x4 acc[7];
  #pragma unroll
  for (int cf=0; cf<7; ++cf) acc[cf] = (f32x4){0.f,0.f,0.f,0.f};
  #pragma unroll
  for (int cf=0; cf<7; ++cf){
    #pragma unroll
    for (int ks=0; ks<4; ++ks){
      bf16x8 bfr = *(const bf16x8*)(MbT + (size_t)(cf*16+ep)*128 + g*8 + ks*32);
      acc[cf] = __builtin_amdgcn_mfma_f32_16x16x32_bf16(af[ks], bfr, acc[cf], 0, 0, 0);
    }
  }
  dgi += __shfl_xor(dgi, 16); dgi += __shfl_xor(dgi, 32);
  dgx += __shfl_xor(dgx, 16); dgx += __shfl_xor(dgx, 32);
  __syncthreads();
  #pragma unroll
  for (int r=0; r<4; ++r){
    int row = g*4 + r;
    float pr = 0.f;
    #pragma unroll
    for (int cf=0; cf<7; ++cf)
      pr += b2f(cw[row*136 + cf*16 + ep]) * acc[cf][r];
    pr += __shfl_xor(pr, 1); pr += __shfl_xor(pr, 2);
    pr += __shfl_xor(pr, 4); pr += __shfl_xor(pr, 8);
    float dw1r = __shfl(acc[6][r], (lane & 48) | 4);   // t[row][100]
    int src = (lane & 48) | row;
    float dgir = __shfl(dgi, src);
    float dgxr = __shfl(dgx, src);
    int rar = __shfl(ra, src), rpr = __shfl(rp, src);
    int rcr = __shfl(rc, src), rrr = __shfl(rr, src);
    float invp = 1.f / fmaxf(sqrtf(pr), 1e-12f);
    float t1 = (dgir*invp)*(dw1r*invp);
    float t2 = (dgxr*RINV[rar])*RVW2[rar];
    float bb = P[(size_t)rrr*4+0] - 2.f*t1 + P[(size_t)rpr*4+1] - 2.f*t2 + P[(size_t)rcr*4+2];
    bb = leaky(bb);
    if (ep == 0){
      BBUF[blockIdx.x*64 + wid*16 + row] = bb;
      atomicAdd(&CNT[rpr], 1);
    }
  }
}

// ---- level-1 pass 1: logits + parent histogram ----
__global__ __launch_bounds__(256) void k_pass1_l1(
    const float* __restrict__ relT, const int* __restrict__ rel1i,
    const int* __restrict__ par, const int* __restrict__ chi, const int* __restrict__ roo,
    const float* __restrict__ G, const float* __restrict__ P,
    const float* __restrict__ RINV, const float* __restrict__ RVW1, const float* __restrict__ RVW2,
    float* __restrict__ BBUF, int* __restrict__ CNT){
  int lane = threadIdx.x & 63;
  int e = (blockIdx.x*256 + threadIdx.x) >> 6;
  if (e >= E1) return;
  int r = rel1i[e], pp = par[e], cc = chi[e], ii = roo[e];
  const float* rrow = relT + r*RD;
  const float* gI = G + (size_t)ii*RD;
  const float* gX = G + (size_t)pp*RD;
  float ai = rrow[lane]*gI[lane];
  float ax = rrow[lane]*gX[lane];
  if (lane < 36){
    ai += rrow[lane+64]*gI[lane+64];
    ax += rrow[lane+64]*gX[lane+64];
  }
  float dgi = wred(ai), dgx = wred(ax);
  if (lane == 0){
    float invn = RINV[r];
    float b = P[(size_t)ii*4+0] - 2.f*(dgi*invn)*RVW1[r]
            + P[(size_t)pp*4+1] - 2.f*(dgx*invn)*RVW2[r]
            + P[(size_t)cc*4+2];
    b = leaky(b);
    BBUF[e] = b;
    atomicAdd(&CNT[pp], 1);
  }
}

// ---- CSR build: exclusive scan over CNT ----
__global__ __launch_bounds__(256) void k_scan_a(const int* __restrict__ CNT,
    int* __restrict__ ROFF, int* __restrict__ PART){
  __shared__ int ls[256];
  int i = blockIdx.x*256 + threadIdx.x;
  int v = (i < N_NODES) ? CNT[i] : 0;
  ls[threadIdx.x] = v;
  __syncthreads();
  for (int off=1; off<256; off<<=1){
    int t = (threadIdx.x >= off) ? ls[threadIdx.x-off] : 0;
    __syncthreads();
    ls[threadIdx.x] += t;
    __syncthreads();
  }
  int incl = ls[threadIdx.x];
  if (i < N_NODES) ROFF[i] = incl - v;
  if (threadIdx.x == 255) PART[blockIdx.x] = incl;
}
__global__ __launch_bounds__(512) void k_scan_b(int* __restrict__ PART){
  __shared__ int ls[512];
  int v = (threadIdx.x < SCAN_BLKS) ? PART[threadIdx.x] : 0;
  ls[threadIdx.x] = v;
  __syncthreads();
  for (int off=1; off<512; off<<=1){
    int t = (threadIdx.x >= off) ? ls[threadIdx.x-off] : 0;
    __syncthreads();
    ls[threadIdx.x] += t;
    __syncthreads();
  }
  if (threadIdx.x < SCAN_BLKS) PART[threadIdx.x] = ls[threadIdx.x] - v;
}
__global__ __launch_bounds__(256) void k_scan_c(int* __restrict__ ROFF, const int* __restrict__ PART){
  int i = blockIdx.x*256 + threadIdx.x;
  if (i < N_NODES) ROFF[i] += PART[blockIdx.x];
}
__global__ void k_scatter(const int* __restrict__ par, const int* __restrict__ ROFF,
                          int* __restrict__ CUR, int* __restrict__ EIDX, int E){
  int e = blockIdx.x*blockDim.x + threadIdx.x;
  if (e >= E) return;
  int p = par[e];
  int pos = ROFF[p] + atomicAdd(&CUR[p], 1);
  EIDX[pos] = e;
}

// ---- fused softmax + aggregate + apply: one wave per parent ----
template<int WXB>
__global__ __launch_bounds__(256) void k_agg(const int* __restrict__ ROFF, const int* __restrict__ CNT,
    const int* __restrict__ EIDX, const float* __restrict__ BBUF,
    const int* __restrict__ chi, const int* __restrict__ relI,
    const float* __restrict__ V, const float* __restrict__ Esrc, const float* __restrict__ In,
    float* __restrict__ Out, unsigned short* __restrict__ Xb){
  int lane = threadIdx.x & 63;
  int p = (blockIdx.x*256 + threadIdx.x) >> 6;
  if (p >= N_NODES) return;
  float acc[5] = {0.f,0.f,0.f,0.f,0.f};
  int cnt = CNT[p];
  if (cnt > 0){
    int base = ROFF[p];
    float m = -1e30f;
    for (int i=0;i<cnt;++i) m = fmaxf(m, BBUF[EIDX[base+i]]);
    float s = 0.f;
    for (int i=0;i<cnt;++i) s += __expf(BBUF[EIDX[base+i]] - m);
    float inv = 1.f / fmaxf(s, 1e-10f);
    for (int i=0;i<cnt;++i){
      int eid = EIDX[base+i];
      float a = __expf(BBUF[eid]-m)*inv;
      int y = chi[eid], r = relI[eid];
      const float* vr = V + (size_t)r*D;
      const float* ey = Esrc + (size_t)y*D;
      float vv[5], ee[5];
      #pragma unroll
      for (int q=0;q<5;++q){
        int d = lane + 64*q;
        vv[q] = (d<D)?vr[d]:0.f; ee[q] = (d<D)?ey[d]:0.f;
      }
      float part = 0.f;
      #pragma unroll
      for (int q=0;q<5;++q) part += vv[q]*ee[q];
      float dk = wred(part);
      float s2 = 2.f*dk*a;
      #pragma unroll
      for (int q=0;q<5;++q) acc[q] += ee[q]*a - s2*vv[q];
    }
  }
  const float* in = In + (size_t)p*D;
  float* op = Out + (size_t)p*D;
  #pragma unroll
  for (int q=0;q<5;++q){
    int d = lane + 64*q;
    if (d < D){
      float o = leaky(in[d] + acc[q]);
      op[d] = o;
      if (WXB) Xb[(size_t)p*320 + d] = f2b(o);
    }
  }
}

// ---- output gather ----
__global__ __launch_bounds__(256) void k_out(const int* __restrict__ ro, const float* __restrict__ FIN,
    float* __restrict__ out){
  int lane = threadIdx.x & 63;
  int o = (blockIdx.x*256 + threadIdx.x) >> 6;
  if (o >= NB) return;
  int n = ro[o];
  const float* f = FIN + (size_t)n*D;
  float* op = out + (size_t)o*D;
  #pragma unroll
  for (int qq=0;qq<5;++qq){
    int d = lane + 64*qq;
    if (d < D) op[d] = f[d];
  }
}

extern "C" void kernel_launch(void* const* d_in, const int* in_sizes, int n_in,
                              void* d_out, int out_size, void* d_ws, size_t ws_size,
                              hipStream_t stream){
  const float* node = (const float*)d_in[0];
  const float* relT = (const float*)d_in[1];
  const float* W    = (const float*)d_in[2];
  const float* watt = (const float*)d_in[3];
  const int* par2 = (const int*)d_in[4];
  const int* chi2 = (const int*)d_in[5];
  const int* roo2 = (const int*)d_in[6];
  const int* rel2i = (const int*)d_in[7];
  const int* relrp2 = (const int*)d_in[8];
  const int* par1 = (const int*)d_in[9];
  const int* chi1 = (const int*)d_in[10];
  const int* roo1 = (const int*)d_in[11];
  const int* rel1i = (const int*)d_in[12];
  const int* roout = (const int*)d_in[13];

  char* w = (char*)d_ws;
  size_t off = 0;
  auto alloc = [&](size_t bytes)->void*{ void* p = w + off; off += (bytes + 255) & ~(size_t)255; return p; };
  float* EA   = (float*)alloc((size_t)N_NODES*D*4);
  float* FIN  = (float*)alloc((size_t)N_NODES*D*4);
  float* G    = (float*)alloc((size_t)N_NODES*RD*4);
  float* P    = (float*)alloc((size_t)N_NODES*4*4);
  float* V    = (float*)alloc((size_t)NREL*D*4);
  float* RINV = (float*)alloc(NREL*4);
  float* RVW1 = (float*)alloc(NREL*4);
  float* RVW2 = (float*)alloc(NREL*4);
  float* M    = (float*)alloc(RD*RD*4);
  float* W1P  = (float*)alloc(RD*4);
  float* BBUF = (float*)alloc((size_t)E2*4);
  unsigned short* Xb = (unsigned short*)alloc((size_t)NPAD*320*2);
  unsigned short* Bt = (unsigned short*)alloc((size_t)112*320*2);
  unsigned short* MbT = (unsigned short*)alloc((size_t)112*128*2);
  unsigned short* WtB = (unsigned short*)alloc((size_t)304*128*2);
  unsigned short* Rb  = (unsigned short*)alloc((size_t)1024*128*2);
  int* CNT  = (int*)alloc((size_t)N_NODES*4);
  int* ROFF = (int*)alloc((size_t)N_NODES*4);
  int* CUR  = (int*)alloc((size_t)N_NODES*4);
  int* PART = (int*)alloc(512*4);
  int* EIDX = (int*)alloc((size_t)E2*4);

  // constants
  k_const<<<dim3(40), dim3(256), 0, stream>>>(W, watt, M, W1P);
  k_prep<<<dim3(140), dim3(256), 0, stream>>>(W, watt, Bt);
  k_prep2<<<dim3(56), dim3(256), 0, stream>>>(M, W1P, MbT);
  k_prep3<<<dim3(152), dim3(256), 0, stream>>>(W, WtB);
  k_castrel<<<dim3(64), dim3(256), 0, stream>>>(relT, Rb);
  k_relmm<<<dim3(16), dim3(256), 0, stream>>>(Rb, WtB, watt, V, RINV, RVW1, RVW2);

  // ---------- level 2 ----------
  hipMemsetAsync(CNT, 0, (size_t)N_NODES*4, stream);
  hipMemsetAsync(CUR, 0, (size_t)N_NODES*4, stream);
  k_cast<<<dim3(2048), dim3(256), 0, stream>>>(node, Xb);
  k_nodetab2<<<dim3((N_NODES+127)/128), dim3(256), 0, stream>>>(Xb, Bt, G, P);
  k_pass1_l2<<<dim3(E2/64), dim3(256), 0, stream>>>(relT, rel2i, relrp2, par2, chi2, roo2,
                                                    G, P, MbT, RINV, RVW2, BBUF, CNT);
  k_scan_a<<<dim3(SCAN_BLKS), dim3(256), 0, stream>>>(CNT, ROFF, PART);
  k_scan_b<<<dim3(1), dim3(512), 0, stream>>>(PART);
  k_scan_c<<<dim3(SCAN_BLKS), dim3(256), 0, stream>>>(ROFF, PART);
  k_scatter<<<dim3((E2+255)/256), dim3(256), 0, stream>>>(par2, ROFF, CUR, EIDX, E2);
  k_agg<1><<<dim3((N_NODES+3)/4), dim3(256), 0, stream>>>(ROFF, CNT, EIDX, BBUF,
                                                          chi2, rel2i, V, node, node, EA, Xb);

  // ---------- level 1 ----------
  hipMemsetAsync(CNT, 0, (size_t)N_NODES*4, stream);
  hipMemsetAsync(CUR, 0, (size_t)N_NODES*4, stream);
  k_nodetab2<<<dim3((N_NODES+127)/128), dim3(256), 0, stream>>>(Xb, Bt, G, P);
  k_pass1_l1<<<dim3((E1+3)/4), dim3(256), 0, stream>>>(relT, rel1i, par1, chi1, roo1,
                                                       G, P, RINV, RVW1, RVW2, BBUF, CNT);
  k_scan_a<<<dim3(SCAN_BLKS), dim3(256), 0, stream>>>(CNT, ROFF, PART);
  k_scan_b<<<dim3(1), dim3(512), 0, stream>>>(PART);
  k_scan_c<<<dim3(SCAN_BLKS), dim3(256), 0, stream>>>(ROFF, PART);
  k_scatter<<<dim3((E1+255)/256), dim3(256), 0, stream>>>(par1, ROFF, CUR, EIDX, E1);
  k_agg<0><<<dim3((N_NODES+3)/4), dim3(256), 0, stream>>>(ROFF, CNT, EIDX, BBUF,
                                                          chi1, rel1i, V, EA, EA, FIN, Xb);
  k_out<<<dim3((NB+3)/4), dim3(256), 0, stream>>>(roout, FIN, (float*)d_out);
}

// Round 6
// 437.465 us; speedup vs baseline: 3.1804x; 1.3833x over previous
//
#include <hip/hip_runtime.h>
#include <hip/hip_bf16.h>
#include <cstdint>

#define N_NODES 100000
#define NPAD 100096
#define D 300
#define RD 100
#define NREL 1000
#define E2 200000
#define E1 100000
#define NB 8192
#define NEG 0.2f
#define SCAN_BLKS 391   // ceil(100000/256)

typedef __bf16 bf16x8 __attribute__((ext_vector_type(8)));
typedef float f32x4 __attribute__((ext_vector_type(4)));
typedef unsigned short us4 __attribute__((ext_vector_type(4)));
typedef unsigned short us8 __attribute__((ext_vector_type(8)));

__device__ __forceinline__ float leaky(float x){ return x >= 0.f ? x : NEG*x; }

__device__ __forceinline__ unsigned short f2b(float v){
  unsigned u = __float_as_uint(v);
  unsigned r = u + 0x7FFF + ((u>>16)&1u);
  return (unsigned short)(r>>16);
}
__device__ __forceinline__ float b2f(unsigned short b){
  return __uint_as_float(((unsigned)b) << 16);
}
__device__ __forceinline__ float wred(float v){
  #pragma unroll
  for (int m = 32; m >= 1; m >>= 1) v += __shfl_xor(v, m, 64);
  return v;
}

// ---- constants: M = W^T W (100x100), W1P = W^T w1 (100) ----
__global__ void k_const(const float* __restrict__ W, const float* __restrict__ watt,
                        float* __restrict__ M, float* __restrict__ W1P){
  int t = blockIdx.x*blockDim.x + threadIdx.x;
  if (t < RD*RD){
    int i = t / RD, j = t % RD;
    float acc = 0.f;
    for (int d = 0; d < D; ++d) acc += W[d*RD+i]*W[d*RD+j];
    M[t] = acc;
  } else if (t < RD*RD + RD){
    int j = t - RD*RD;
    float acc = 0.f;
    for (int d = 0; d < D; ++d) acc += watt[d]*W[d*RD+j];
    W1P[j] = acc;
  }
}

// ---- Bt[112][320] bf16 = [W | w1 w2 w3 | 0]^T, K padded to 320 ----
__global__ void k_prep(const float* __restrict__ W, const float* __restrict__ watt,
                       unsigned short* __restrict__ Bt){
  int u = blockIdx.x*blockDim.x + threadIdx.x;
  if (u >= 112*320) return;
  int c = u / 320, k = u % 320;
  float v = 0.f;
  if (k < D){
    if (c < RD) v = W[k*RD + c];
    else if (c < RD+3) v = watt[(c-RD)*D + k];
  }
  Bt[u] = f2b(v);
}

// ---- MbT[112][128] bf16: rows j=0..99 -> M[j][i] (symmetric), row 100 -> W1P ----
__global__ void k_prep2(const float* __restrict__ M, const float* __restrict__ W1P,
                        unsigned short* __restrict__ MbT){
  int u = blockIdx.x*blockDim.x + threadIdx.x;
  if (u >= 112*128) return;
  int j = u >> 7, i = u & 127;
  float v = 0.f;
  if (i < RD){
    if (j < RD) v = M[j*RD + i];
    else if (j == RD) v = W1P[i];
  }
  MbT[u] = f2b(v);
}

// ---- WtB[304][128] bf16: row d = W[d][0..99], zero-padded ----
__global__ void k_prep3(const float* __restrict__ W, unsigned short* __restrict__ WtB){
  int u = blockIdx.x*blockDim.x + threadIdx.x;
  if (u >= 304*128) return;
  int dd = u >> 7, k = u & 127;
  float v = (dd < D && k < RD) ? W[dd*RD + k] : 0.f;
  WtB[u] = f2b(v);
}

// ---- Rb[1024][128] bf16: relation table rows, zero-padded ----
__global__ void k_castrel(const float* __restrict__ relT, unsigned short* __restrict__ Rb){
  int u = blockIdx.x*blockDim.x + threadIdx.x;   // one us8 per thread
  if (u >= 1024*16) return;
  int row = u >> 4, c8 = (u & 15)*8;
  us8 o;
  #pragma unroll
  for (int j=0;j<8;++j){
    int c = c8+j;
    o[j] = (row < NREL && c < RD) ? f2b(relT[row*RD + c]) : (unsigned short)0;
  }
  *(us8*)(Rb + (size_t)row*128 + c8) = o;
}

// ---- MFMA relation tables: U = Rb @ WtB^T, normalize rows -> V, RINV, RVW1, RVW2 ----
__global__ __launch_bounds__(256) void k_relmm(const unsigned short* __restrict__ Rb,
    const unsigned short* __restrict__ WtB, const float* __restrict__ watt,
    float* __restrict__ V, float* __restrict__ RINV,
    float* __restrict__ RVW1, float* __restrict__ RVW2){
  int lane = threadIdx.x & 63, wid = threadIdx.x >> 6;
  int r0 = blockIdx.x*64 + wid*16;
  int ep = lane & 15, g = lane >> 4;
  size_t a0 = (size_t)(r0 + ep)*128 + g*8;
  size_t b0 = (size_t)ep*128 + g*8;
  f32x4 acc[19];
  #pragma unroll
  for (int cf=0;cf<19;++cf) acc[cf]=(f32x4){0.f,0.f,0.f,0.f};
  #pragma unroll
  for (int ks=0; ks<4; ++ks){
    bf16x8 af = *(const bf16x8*)(Rb + a0 + ks*32);
    #pragma unroll
    for (int cf=0; cf<19; ++cf){
      bf16x8 bf = *(const bf16x8*)(WtB + b0 + (size_t)cf*16*128 + ks*32);
      acc[cf] = __builtin_amdgcn_mfma_f32_16x16x32_bf16(af, bf, acc[cf], 0, 0, 0);
    }
  }
  float w1v[19], w2v[19];
  #pragma unroll
  for (int cf=0; cf<19; ++cf){
    int col = cf*16+ep;
    bool ok = col < D;
    w1v[cf] = ok ? watt[col] : 0.f;
    w2v[cf] = ok ? watt[D+col] : 0.f;
  }
  #pragma unroll
  for (int reg=0; reg<4; ++reg){
    int row = r0 + g*4 + reg;
    float np = 0.f;
    #pragma unroll
    for (int cf=0; cf<19; ++cf){ float u = acc[cf][reg]; np += u*u; }
    np += __shfl_xor(np,1); np += __shfl_xor(np,2); np += __shfl_xor(np,4); np += __shfl_xor(np,8);
    float iv = 1.f / fmaxf(sqrtf(np), 1e-12f);
    float p1 = 0.f, p2 = 0.f;
    if (row < NREL){
      #pragma unroll
      for (int cf=0; cf<19; ++cf){
        int col = cf*16+ep;
        float v = acc[cf][reg]*iv;
        if (col < D){
          V[(size_t)row*D + col] = v;
          p1 += v*w1v[cf];
          p2 += v*w2v[cf];
        }
      }
    }
    p1 += __shfl_xor(p1,1); p1 += __shfl_xor(p1,2); p1 += __shfl_xor(p1,4); p1 += __shfl_xor(p1,8);
    p2 += __shfl_xor(p2,1); p2 += __shfl_xor(p2,2); p2 += __shfl_xor(p2,4); p2 += __shfl_xor(p2,8);
    if (ep == 0 && row < NREL){
      RINV[row] = iv; RVW1[row] = p1; RVW2[row] = p2;
    }
  }
}

// ---- cast node embeddings to padded bf16 table Xb[NPAD][320] ----
__global__ void k_cast(const float* __restrict__ src, unsigned short* __restrict__ dst){
  int total = NPAD*40;
  for (int u = blockIdx.x*blockDim.x + threadIdx.x; u < total; u += gridDim.x*blockDim.x){
    int row = u/40, c8 = (u%40)*8;
    us8 o;
    if (row < N_NODES && c8 <= 292){
      float4 x = *(const float4*)(src + (size_t)row*D + c8);
      float4 y = *(const float4*)(src + (size_t)row*D + c8 + 4);
      o[0]=f2b(x.x); o[1]=f2b(x.y); o[2]=f2b(x.z); o[3]=f2b(x.w);
      o[4]=f2b(y.x); o[5]=f2b(y.y); o[6]=f2b(y.z); o[7]=f2b(y.w);
    } else {
      #pragma unroll
      for (int j=0;j<8;++j){
        int c = c8+j;
        float v = (row < N_NODES && c < D) ? src[(size_t)row*D + c] : 0.f;
        o[j] = f2b(v);
      }
    }
    *(us8*)(dst + (size_t)row*320 + c8) = o;
  }
}

// ---- MFMA node tables: Gh[n] = bf16(W^T e_n) (100), P[n] = {e.w1, e.w2, e.w3, 0} ----
__global__ __launch_bounds__(256) void k_nodetab2(const unsigned short* __restrict__ Eb,
    const unsigned short* __restrict__ Bt, unsigned short* __restrict__ Gh, float* __restrict__ P){
  int lane = threadIdx.x & 63, wid = threadIdx.x >> 6;
  int n0 = blockIdx.x*128;
  size_t a0 = (size_t)(n0 + wid*32 + (lane&15))*320 + ((lane>>4)*8);
  size_t b0 = (size_t)(lane&15)*320 + ((lane>>4)*8);
  f32x4 acc[2][7];
  #pragma unroll
  for (int s=0;s<2;++s)
    #pragma unroll
    for (int c=0;c<7;++c) acc[s][c] = (f32x4){0.f,0.f,0.f,0.f};
  for (int ks = 0; ks < 10; ++ks){
    bf16x8 a0f = *(const bf16x8*)(Eb + a0 + ks*32);
    bf16x8 a1f = *(const bf16x8*)(Eb + a0 + 16*320 + ks*32);
    #pragma unroll
    for (int cf=0; cf<7; ++cf){
      bf16x8 bf = *(const bf16x8*)(Bt + b0 + (size_t)cf*16*320 + ks*32);
      acc[0][cf] = __builtin_amdgcn_mfma_f32_16x16x32_bf16(a0f, bf, acc[0][cf], 0, 0, 0);
      acc[1][cf] = __builtin_amdgcn_mfma_f32_16x16x32_bf16(a1f, bf, acc[1][cf], 0, 0, 0);
    }
  }
  int rbase = n0 + wid*32 + ((lane>>4)<<2);
  int cbase = lane & 15;
  #pragma unroll
  for (int sub=0; sub<2; ++sub){
    #pragma unroll
    for (int cf=0; cf<7; ++cf){
      int col = cf*16 + cbase;
      #pragma unroll
      for (int r=0; r<4; ++r){
        int row = rbase + sub*16 + r;
        if (row < N_NODES){
          float v = acc[sub][cf][r];
          if (col < RD) Gh[(size_t)row*RD + col] = f2b(v);
          else if (col < RD+3) P[(size_t)row*4 + (col-RD)] = v;
        }
      }
    }
  }
}

// ---- level-2 pass 1 (MFMA): logits + parent histogram ----
__global__ __launch_bounds__(256) void k_pass1_l2(
    const float* __restrict__ relT, const int* __restrict__ rel2i, const int* __restrict__ relrp2,
    const int* __restrict__ par, const int* __restrict__ chi, const int* __restrict__ roo,
    const unsigned short* __restrict__ Gh, const float* __restrict__ P,
    const unsigned short* __restrict__ MbT,
    const float* __restrict__ RINV, const float* __restrict__ RVW2,
    float* __restrict__ BBUF, int* __restrict__ CNT){
  __shared__ unsigned short Cl[4*16*136];
  int lane = threadIdx.x & 63, wid = threadIdx.x >> 6;
  int ep = lane & 15, g = lane >> 4;
  unsigned short* cw = Cl + wid*16*136;
  int e = blockIdx.x*64 + wid*16 + ep;
  int ra = rel2i[e], rb = relrp2[e], rp = par[e], rc = chi[e], rr = roo[e];
  const float* rA = relT + (size_t)ra*RD;
  const float* rB = relT + (size_t)rb*RD;
  const unsigned short* gR = Gh + (size_t)rr*RD;
  const unsigned short* gX = Gh + (size_t)rp*RD;
  float dgi = 0.f, dgx = 0.f;
  bf16x8 af[4];
  #pragma unroll
  for (int ks=0; ks<4; ++ks){
    us8 cpack;
    #pragma unroll
    for (int h=0; h<2; ++h){
      int k0 = g*8 + ks*32 + h*4;
      float4 a4 = make_float4(0.f,0.f,0.f,0.f), b4 = a4, grr = a4, grp = a4;
      if (k0 <= 96){
        a4  = *(const float4*)(rA + k0);
        b4  = *(const float4*)(rB + k0);
        us4 r4 = *(const us4*)(gR + k0);
        us4 x4 = *(const us4*)(gX + k0);
        grr = make_float4(b2f(r4[0]),b2f(r4[1]),b2f(r4[2]),b2f(r4[3]));
        grp = make_float4(b2f(x4[0]),b2f(x4[1]),b2f(x4[2]),b2f(x4[3]));
      }
      float4 c4;
      c4.x = a4.x*b4.x; c4.y = a4.y*b4.y; c4.z = a4.z*b4.z; c4.w = a4.w*b4.w;
      dgi += c4.x*grr.x + c4.y*grr.y + c4.z*grr.z + c4.w*grr.w;
      dgx += a4.x*grp.x + a4.y*grp.y + a4.z*grp.z + a4.w*grp.w;
      cpack[h*4+0]=f2b(c4.x); cpack[h*4+1]=f2b(c4.y); cpack[h*4+2]=f2b(c4.z); cpack[h*4+3]=f2b(c4.w);
    }
    *(us8*)((char*)cw + ep*272 + g*16 + ks*64) = cpack;
    af[ks] = *(bf16x8*)&cpack;
  }
  f32x4 acc[7];
  #pragma unroll
  for (int cf=0; cf<7; ++cf) acc[cf] = (f32x4){0.f,0.f,0.f,0.f};
  #pragma unroll
  for (int cf=0; cf<7; ++cf){
    #pragma unroll
    for (int ks=0; ks<4; ++ks){
      bf16x8 bfr = *(const bf16x8*)(MbT + (size_t)(cf*16+ep)*128 + g*8 + ks*32);
      acc[cf] = __builtin_amdgcn_mfma_f32_16x16x32_bf16(af[ks], bfr, acc[cf], 0, 0, 0);
    }
  }
  dgi += __shfl_xor(dgi, 16); dgi += __shfl_xor(dgi, 32);
  dgx += __shfl_xor(dgx, 16); dgx += __shfl_xor(dgx, 32);
  __syncthreads();
  #pragma unroll
  for (int r=0; r<4; ++r){
    int row = g*4 + r;
    float pr = 0.f;
    #pragma unroll
    for (int cf=0; cf<7; ++cf)
      pr += b2f(cw[row*136 + cf*16 + ep]) * acc[cf][r];
    pr += __shfl_xor(pr, 1); pr += __shfl_xor(pr, 2);
    pr += __shfl_xor(pr, 4); pr += __shfl_xor(pr, 8);
    float dw1r = __shfl(acc[6][r], (lane & 48) | 4);   // t[row][100]
    int src = (lane & 48) | row;
    float dgir = __shfl(dgi, src);
    float dgxr = __shfl(dgx, src);
    int rar = __shfl(ra, src), rpr = __shfl(rp, src);
    int rcr = __shfl(rc, src), rrr = __shfl(rr, src);
    float invp = 1.f / fmaxf(sqrtf(pr), 1e-12f);
    float t1 = (dgir*invp)*(dw1r*invp);
    float t2 = (dgxr*RINV[rar])*RVW2[rar];
    float bb = P[(size_t)rrr*4+0] - 2.f*t1 + P[(size_t)rpr*4+1] - 2.f*t2 + P[(size_t)rcr*4+2];
    bb = leaky(bb);
    if (ep == 0){
      BBUF[blockIdx.x*64 + wid*16 + row] = bb;
      atomicAdd(&CNT[rpr], 1);
    }
  }
}

// ---- level-1 pass 1: logits + parent histogram ----
__global__ __launch_bounds__(256) void k_pass1_l1(
    const float* __restrict__ relT, const int* __restrict__ rel1i,
    const int* __restrict__ par, const int* __restrict__ chi, const int* __restrict__ roo,
    const unsigned short* __restrict__ Gh, const float* __restrict__ P,
    const float* __restrict__ RINV, const float* __restrict__ RVW1, const float* __restrict__ RVW2,
    float* __restrict__ BBUF, int* __restrict__ CNT){
  int lane = threadIdx.x & 63;
  int e = (blockIdx.x*256 + threadIdx.x) >> 6;
  if (e >= E1) return;
  int r = rel1i[e], pp = par[e], cc = chi[e], ii = roo[e];
  const float* rrow = relT + r*RD;
  const unsigned short* gI = Gh + (size_t)ii*RD;
  const unsigned short* gX = Gh + (size_t)pp*RD;
  float ai = rrow[lane]*b2f(gI[lane]);
  float ax = rrow[lane]*b2f(gX[lane]);
  if (lane < 36){
    ai += rrow[lane+64]*b2f(gI[lane+64]);
    ax += rrow[lane+64]*b2f(gX[lane+64]);
  }
  float dgi = wred(ai), dgx = wred(ax);
  if (lane == 0){
    float invn = RINV[r];
    float b = P[(size_t)ii*4+0] - 2.f*(dgi*invn)*RVW1[r]
            + P[(size_t)pp*4+1] - 2.f*(dgx*invn)*RVW2[r]
            + P[(size_t)cc*4+2];
    b = leaky(b);
    BBUF[e] = b;
    atomicAdd(&CNT[pp], 1);
  }
}

// ---- CSR build: exclusive scan over CNT ----
__global__ __launch_bounds__(256) void k_scan_a(const int* __restrict__ CNT,
    int* __restrict__ ROFF, int* __restrict__ PART){
  __shared__ int ls[256];
  int i = blockIdx.x*256 + threadIdx.x;
  int v = (i < N_NODES) ? CNT[i] : 0;
  ls[threadIdx.x] = v;
  __syncthreads();
  for (int off=1; off<256; off<<=1){
    int t = (threadIdx.x >= off) ? ls[threadIdx.x-off] : 0;
    __syncthreads();
    ls[threadIdx.x] += t;
    __syncthreads();
  }
  int incl = ls[threadIdx.x];
  if (i < N_NODES) ROFF[i] = incl - v;
  if (threadIdx.x == 255) PART[blockIdx.x] = incl;
}
__global__ __launch_bounds__(512) void k_scan_b(int* __restrict__ PART){
  __shared__ int ls[512];
  int v = (threadIdx.x < SCAN_BLKS) ? PART[threadIdx.x] : 0;
  ls[threadIdx.x] = v;
  __syncthreads();
  for (int off=1; off<512; off<<=1){
    int t = (threadIdx.x >= off) ? ls[threadIdx.x-off] : 0;
    __syncthreads();
    ls[threadIdx.x] += t;
    __syncthreads();
  }
  if (threadIdx.x < SCAN_BLKS) PART[threadIdx.x] = ls[threadIdx.x] - v;
}
__global__ __launch_bounds__(256) void k_scan_c(int* __restrict__ ROFF, const int* __restrict__ PART){
  int i = blockIdx.x*256 + threadIdx.x;
  if (i < N_NODES) ROFF[i] += PART[blockIdx.x];
}
__global__ void k_scatter(const int* __restrict__ par, const int* __restrict__ ROFF,
                          int* __restrict__ CUR, int* __restrict__ EIDX, int E){
  int e = blockIdx.x*blockDim.x + threadIdx.x;
  if (e >= E) return;
  int p = par[e];
  int pos = ROFF[p] + atomicAdd(&CUR[p], 1);
  EIDX[pos] = e;
}

// ---- per-parent softmax + Householder aggregate (bf16 gathers), acc in f32 ----
__device__ __forceinline__ void agg_bucket(int p, int lane,
    const int* __restrict__ ROFF, const int* __restrict__ CNT,
    const int* __restrict__ EIDX, const float* __restrict__ BBUF,
    const int* __restrict__ chi, const int* __restrict__ relI,
    const float* __restrict__ V, const unsigned short* __restrict__ Xe,
    float acc[5]){
  int cnt = CNT[p];
  if (cnt <= 0) return;
  int base = ROFF[p];
  float m = -1e30f;
  for (int i=0;i<cnt;++i) m = fmaxf(m, BBUF[EIDX[base+i]]);
  float s = 0.f;
  for (int i=0;i<cnt;++i) s += __expf(BBUF[EIDX[base+i]] - m);
  float inv = 1.f / fmaxf(s, 1e-10f);
  for (int i=0;i<cnt;++i){
    int eid = EIDX[base+i];
    float a = __expf(BBUF[eid]-m)*inv;
    int y = chi[eid], r = relI[eid];
    const float* vr = V + (size_t)r*D;
    const unsigned short* ey = Xe + (size_t)y*320;
    float vv[5], ee[5];
    #pragma unroll
    for (int q=0;q<5;++q){
      int d = lane + 64*q;
      vv[q] = (d<D)?vr[d]:0.f;
      ee[q] = (d<D)?b2f(ey[d]):0.f;
    }
    float part = 0.f;
    #pragma unroll
    for (int q=0;q<5;++q) part += vv[q]*ee[q];
    float dk = wred(part);
    float s2 = 2.f*dk*a;
    #pragma unroll
    for (int q=0;q<5;++q) acc[q] += ee[q]*a - s2*vv[q];
  }
}

// ---- level-2: one wave per parent; writes bf16 Xb2 row (incl. zero pad) ----
__global__ __launch_bounds__(256) void k_agg2(const int* __restrict__ ROFF, const int* __restrict__ CNT,
    const int* __restrict__ EIDX, const float* __restrict__ BBUF,
    const int* __restrict__ chi, const int* __restrict__ relI,
    const float* __restrict__ V, const unsigned short* __restrict__ Xe,
    unsigned short* __restrict__ Xo){
  int lane = threadIdx.x & 63;
  int p = (blockIdx.x*256 + threadIdx.x) >> 6;
  if (p >= N_NODES) return;
  float acc[5] = {0.f,0.f,0.f,0.f,0.f};
  agg_bucket(p, lane, ROFF, CNT, EIDX, BBUF, chi, relI, V, Xe, acc);
  const unsigned short* in = Xe + (size_t)p*320;
  unsigned short* op = Xo + (size_t)p*320;
  #pragma unroll
  for (int q=0;q<5;++q){
    int d = lane + 64*q;
    unsigned short o = 0;
    if (d < D) o = f2b(leaky(b2f(in[d]) + acc[q]));
    op[d] = o;
  }
}

// ---- level-1: one wave per OUTPUT (8192); writes d_out directly ----
__global__ __launch_bounds__(256) void k_aggout(const int* __restrict__ ro,
    const int* __restrict__ ROFF, const int* __restrict__ CNT,
    const int* __restrict__ EIDX, const float* __restrict__ BBUF,
    const int* __restrict__ chi, const int* __restrict__ relI,
    const float* __restrict__ V, const unsigned short* __restrict__ Xe,
    float* __restrict__ out){
  int lane = threadIdx.x & 63;
  int o = (blockIdx.x*256 + threadIdx.x) >> 6;
  if (o >= NB) return;
  int p = ro[o];
  float acc[5] = {0.f,0.f,0.f,0.f,0.f};
  agg_bucket(p, lane, ROFF, CNT, EIDX, BBUF, chi, relI, V, Xe, acc);
  const unsigned short* in = Xe + (size_t)p*320;
  float* op = out + (size_t)o*D;
  #pragma unroll
  for (int q=0;q<5;++q){
    int d = lane + 64*q;
    if (d < D) op[d] = leaky(b2f(in[d]) + acc[q]);
  }
}

extern "C" void kernel_launch(void* const* d_in, const int* in_sizes, int n_in,
                              void* d_out, int out_size, void* d_ws, size_t ws_size,
                              hipStream_t stream){
  const float* node = (const float*)d_in[0];
  const float* relT = (const float*)d_in[1];
  const float* W    = (const float*)d_in[2];
  const float* watt = (const float*)d_in[3];
  const int* par2 = (const int*)d_in[4];
  const int* chi2 = (const int*)d_in[5];
  const int* roo2 = (const int*)d_in[6];
  const int* rel2i = (const int*)d_in[7];
  const int* relrp2 = (const int*)d_in[8];
  const int* par1 = (const int*)d_in[9];
  const int* chi1 = (const int*)d_in[10];
  const int* roo1 = (const int*)d_in[11];
  const int* rel1i = (const int*)d_in[12];
  const int* roout = (const int*)d_in[13];

  char* w = (char*)d_ws;
  size_t off = 0;
  auto alloc = [&](size_t bytes)->void*{ void* p = w + off; off += (bytes + 255) & ~(size_t)255; return p; };
  unsigned short* Gh = (unsigned short*)alloc((size_t)N_NODES*RD*2);
  float* P    = (float*)alloc((size_t)N_NODES*4*4);
  float* V    = (float*)alloc((size_t)NREL*D*4);
  float* RINV = (float*)alloc(NREL*4);
  float* RVW1 = (float*)alloc(NREL*4);
  float* RVW2 = (float*)alloc(NREL*4);
  float* M    = (float*)alloc(RD*RD*4);
  float* W1P  = (float*)alloc(RD*4);
  float* BBUF = (float*)alloc((size_t)E2*4);
  unsigned short* Xb  = (unsigned short*)alloc((size_t)NPAD*320*2);
  unsigned short* Xb2 = (unsigned short*)alloc((size_t)NPAD*320*2);
  unsigned short* Bt  = (unsigned short*)alloc((size_t)112*320*2);
  unsigned short* MbT = (unsigned short*)alloc((size_t)112*128*2);
  unsigned short* WtB = (unsigned short*)alloc((size_t)304*128*2);
  unsigned short* Rb  = (unsigned short*)alloc((size_t)1024*128*2);
  int* CNT  = (int*)alloc((size_t)N_NODES*4);
  int* ROFF = (int*)alloc((size_t)N_NODES*4);
  int* CUR  = (int*)alloc((size_t)N_NODES*4);
  int* PART = (int*)alloc(512*4);
  int* EIDX = (int*)alloc((size_t)E2*4);

  // constants
  k_const<<<dim3(40), dim3(256), 0, stream>>>(W, watt, M, W1P);
  k_prep<<<dim3(140), dim3(256), 0, stream>>>(W, watt, Bt);
  k_prep2<<<dim3(56), dim3(256), 0, stream>>>(M, W1P, MbT);
  k_prep3<<<dim3(152), dim3(256), 0, stream>>>(W, WtB);
  k_castrel<<<dim3(64), dim3(256), 0, stream>>>(relT, Rb);
  k_relmm<<<dim3(16), dim3(256), 0, stream>>>(Rb, WtB, watt, V, RINV, RVW1, RVW2);

  // ---------- level 2 ----------
  hipMemsetAsync(CNT, 0, (size_t)N_NODES*4, stream);
  hipMemsetAsync(CUR, 0, (size_t)N_NODES*4, stream);
  k_cast<<<dim3(2048), dim3(256), 0, stream>>>(node, Xb);
  k_nodetab2<<<dim3((N_NODES+127)/128), dim3(256), 0, stream>>>(Xb, Bt, Gh, P);
  k_pass1_l2<<<dim3(E2/64), dim3(256), 0, stream>>>(relT, rel2i, relrp2, par2, chi2, roo2,
                                                    Gh, P, MbT, RINV, RVW2, BBUF, CNT);
  k_scan_a<<<dim3(SCAN_BLKS), dim3(256), 0, stream>>>(CNT, ROFF, PART);
  k_scan_b<<<dim3(1), dim3(512), 0, stream>>>(PART);
  k_scan_c<<<dim3(SCAN_BLKS), dim3(256), 0, stream>>>(ROFF, PART);
  k_scatter<<<dim3((E2+255)/256), dim3(256), 0, stream>>>(par2, ROFF, CUR, EIDX, E2);
  k_agg2<<<dim3((N_NODES+3)/4), dim3(256), 0, stream>>>(ROFF, CNT, EIDX, BBUF,
                                                        chi2, rel2i, V, Xb, Xb2);

  // ---------- level 1 ----------
  hipMemsetAsync(CNT, 0, (size_t)N_NODES*4, stream);
  hipMemsetAsync(CUR, 0, (size_t)N_NODES*4, stream);
  k_nodetab2<<<dim3((N_NODES+127)/128), dim3(256), 0, stream>>>(Xb2, Bt, Gh, P);
  k_pass1_l1<<<dim3((E1+3)/4), dim3(256), 0, stream>>>(relT, rel1i, par1, chi1, roo1,
                                                       Gh, P, RINV, RVW1, RVW2, BBUF, CNT);
  k_scan_a<<<dim3(SCAN_BLKS), dim3(256), 0, stream>>>(CNT, ROFF, PART);
  k_scan_b<<<dim3(1), dim3(512), 0, stream>>>(PART);
  k_scan_c<<<dim3(SCAN_BLKS), dim3(256), 0, stream>>>(ROFF, PART);
  k_scatter<<<dim3((E1+255)/256), dim3(256), 0, stream>>>(par1, ROFF, CUR, EIDX, E1);
  k_aggout<<<dim3((NB+3)/4), dim3(256), 0, stream>>>(roout, ROFF, CNT, EIDX, BBUF,
                                                     chi1, rel1i, V, Xb2, (float*)d_out);
}

// Round 7
// 394.801 us; speedup vs baseline: 3.5241x; 1.1081x over previous
//
#include <hip/hip_runtime.h>
#include <hip/hip_bf16.h>
#include <cstdint>

#define N_NODES 100000
#define NPAD 100096
#define D 300
#define RD 100
#define NREL 1000
#define E2 200000
#define E1 100000
#define NB 8192
#define NEG 0.2f
#define SCAN_BLKS 391   // ceil(100000/256)

typedef __bf16 bf16x8 __attribute__((ext_vector_type(8)));
typedef float f32x4 __attribute__((ext_vector_type(4)));
typedef unsigned short us4 __attribute__((ext_vector_type(4)));
typedef unsigned short us8 __attribute__((ext_vector_type(8)));

__device__ __forceinline__ float leaky(float x){ return x >= 0.f ? x : NEG*x; }

__device__ __forceinline__ unsigned short f2b(float v){
  unsigned u = __float_as_uint(v);
  unsigned r = u + 0x7FFF + ((u>>16)&1u);
  return (unsigned short)(r>>16);
}
__device__ __forceinline__ float b2f(unsigned short b){
  return __uint_as_float(((unsigned)b) << 16);
}
__device__ __forceinline__ float wred(float v){
  #pragma unroll
  for (int m = 32; m >= 1; m >>= 1) v += __shfl_xor(v, m, 64);
  return v;
}

// ---- MbT[112][128] bf16: rows j<100 -> M[j][i]=sum_d W[d][i]W[d][j]; row 100 -> W^T w1 ----
__global__ void k_prep2b(const float* __restrict__ W, const float* __restrict__ watt,
                         unsigned short* __restrict__ MbT){
  int u = blockIdx.x*blockDim.x + threadIdx.x;
  if (u >= 112*128) return;
  int j = u >> 7, i = u & 127;
  float v = 0.f;
  if (i < RD){
    if (j < RD){ float a=0.f; for (int d=0;d<D;++d) a += W[d*RD+i]*W[d*RD+j]; v=a; }
    else if (j == RD){ float a=0.f; for (int d=0;d<D;++d) a += watt[d]*W[d*RD+i]; v=a; }
  }
  MbT[u] = f2b(v);
}

// ---- fused prep: Bt[112][320], WtB[304][128], Rb[1024][128] ----
__global__ void k_prepAll(const float* __restrict__ W, const float* __restrict__ watt,
                          const float* __restrict__ relT, unsigned short* __restrict__ Bt,
                          unsigned short* __restrict__ WtB, unsigned short* __restrict__ Rb){
  int b = blockIdx.x;
  if (b < 140){
    int u = b*256 + threadIdx.x;
    if (u < 112*320){
      int c = u / 320, k = u % 320;
      float v = 0.f;
      if (k < D){
        if (c < RD) v = W[k*RD + c];
        else if (c < RD+3) v = watt[(c-RD)*D + k];
      }
      Bt[u] = f2b(v);
    }
  } else if (b < 292){
    int u = (b-140)*256 + threadIdx.x;
    if (u < 304*128){
      int dd = u >> 7, k = u & 127;
      float v = (dd < D && k < RD) ? W[dd*RD + k] : 0.f;
      WtB[u] = f2b(v);
    }
  } else {
    int u = (b-292)*256 + threadIdx.x;
    if (u < 1024*16){
      int row = u >> 4, c8 = (u & 15)*8;
      us8 o;
      #pragma unroll
      for (int j=0;j<8;++j){
        int c = c8+j;
        o[j] = (row < NREL && c < RD) ? f2b(relT[row*RD + c]) : (unsigned short)0;
      }
      *(us8*)(Rb + (size_t)row*128 + c8) = o;
    }
  }
}

// ---- MFMA relation tables: U = Rb @ WtB^T -> Vh (bf16), RINV, RVW1, RVW2 ----
__global__ __launch_bounds__(256) void k_relmm(const unsigned short* __restrict__ Rb,
    const unsigned short* __restrict__ WtB, const float* __restrict__ watt,
    unsigned short* __restrict__ Vh, float* __restrict__ RINV,
    float* __restrict__ RVW1, float* __restrict__ RVW2){
  int lane = threadIdx.x & 63, wid = threadIdx.x >> 6;
  int r0 = blockIdx.x*64 + wid*16;
  int ep = lane & 15, g = lane >> 4;
  size_t a0 = (size_t)(r0 + ep)*128 + g*8;
  size_t b0 = (size_t)ep*128 + g*8;
  f32x4 acc[19];
  #pragma unroll
  for (int cf=0;cf<19;++cf) acc[cf]=(f32x4){0.f,0.f,0.f,0.f};
  #pragma unroll
  for (int ks=0; ks<4; ++ks){
    bf16x8 af = *(const bf16x8*)(Rb + a0 + ks*32);
    #pragma unroll
    for (int cf=0; cf<19; ++cf){
      bf16x8 bf = *(const bf16x8*)(WtB + b0 + (size_t)cf*16*128 + ks*32);
      acc[cf] = __builtin_amdgcn_mfma_f32_16x16x32_bf16(af, bf, acc[cf], 0, 0, 0);
    }
  }
  float w1v[19], w2v[19];
  #pragma unroll
  for (int cf=0; cf<19; ++cf){
    int col = cf*16+ep;
    bool ok = col < D;
    w1v[cf] = ok ? watt[col] : 0.f;
    w2v[cf] = ok ? watt[D+col] : 0.f;
  }
  #pragma unroll
  for (int reg=0; reg<4; ++reg){
    int row = r0 + g*4 + reg;
    float np = 0.f;
    #pragma unroll
    for (int cf=0; cf<19; ++cf){ float u = acc[cf][reg]; np += u*u; }
    np += __shfl_xor(np,1); np += __shfl_xor(np,2); np += __shfl_xor(np,4); np += __shfl_xor(np,8);
    float iv = 1.f / fmaxf(sqrtf(np), 1e-12f);
    float p1 = 0.f, p2 = 0.f;
    if (row < NREL){
      #pragma unroll
      for (int cf=0; cf<19; ++cf){
        int col = cf*16+ep;
        float v = acc[cf][reg]*iv;
        if (col < D){
          Vh[(size_t)row*D + col] = f2b(v);
          p1 += v*w1v[cf];
          p2 += v*w2v[cf];
        }
      }
    }
    p1 += __shfl_xor(p1,1); p1 += __shfl_xor(p1,2); p1 += __shfl_xor(p1,4); p1 += __shfl_xor(p1,8);
    p2 += __shfl_xor(p2,1); p2 += __shfl_xor(p2,2); p2 += __shfl_xor(p2,4); p2 += __shfl_xor(p2,8);
    if (ep == 0 && row < NREL){
      RINV[row] = iv; RVW1[row] = p1; RVW2[row] = p2;
    }
  }
}

// ---- cast node embeddings to padded bf16 table Xb[NPAD][320] ----
__global__ void k_cast(const float* __restrict__ src, unsigned short* __restrict__ dst){
  int total = NPAD*40;
  for (int u = blockIdx.x*blockDim.x + threadIdx.x; u < total; u += gridDim.x*blockDim.x){
    int row = u/40, c8 = (u%40)*8;
    us8 o;
    if (row < N_NODES && c8 <= 292){
      float4 x = *(const float4*)(src + (size_t)row*D + c8);
      float4 y = *(const float4*)(src + (size_t)row*D + c8 + 4);
      o[0]=f2b(x.x); o[1]=f2b(x.y); o[2]=f2b(x.z); o[3]=f2b(x.w);
      o[4]=f2b(y.x); o[5]=f2b(y.y); o[6]=f2b(y.z); o[7]=f2b(y.w);
    } else {
      #pragma unroll
      for (int j=0;j<8;++j){
        int c = c8+j;
        float v = (row < N_NODES && c < D) ? src[(size_t)row*D + c] : 0.f;
        o[j] = f2b(v);
      }
    }
    *(us8*)(dst + (size_t)row*320 + c8) = o;
  }
}

// ---- MFMA node tables: Gh[n] = bf16(W^T e_n), P[n]; also zeroes CNT/CUR ----
__global__ __launch_bounds__(256) void k_nodetab2(const unsigned short* __restrict__ Eb,
    const unsigned short* __restrict__ Bt, unsigned short* __restrict__ Gh, float* __restrict__ P,
    int* __restrict__ CNT, int* __restrict__ CUR){
  int z = blockIdx.x*256 + threadIdx.x;
  if (z < N_NODES){ CNT[z] = 0; CUR[z] = 0; }
  int lane = threadIdx.x & 63, wid = threadIdx.x >> 6;
  int n0 = blockIdx.x*128;
  size_t a0 = (size_t)(n0 + wid*32 + (lane&15))*320 + ((lane>>4)*8);
  size_t b0 = (size_t)(lane&15)*320 + ((lane>>4)*8);
  f32x4 acc[2][7];
  #pragma unroll
  for (int s=0;s<2;++s)
    #pragma unroll
    for (int c=0;c<7;++c) acc[s][c] = (f32x4){0.f,0.f,0.f,0.f};
  for (int ks = 0; ks < 10; ++ks){
    bf16x8 a0f = *(const bf16x8*)(Eb + a0 + ks*32);
    bf16x8 a1f = *(const bf16x8*)(Eb + a0 + 16*320 + ks*32);
    #pragma unroll
    for (int cf=0; cf<7; ++cf){
      bf16x8 bf = *(const bf16x8*)(Bt + b0 + (size_t)cf*16*320 + ks*32);
      acc[0][cf] = __builtin_amdgcn_mfma_f32_16x16x32_bf16(a0f, bf, acc[0][cf], 0, 0, 0);
      acc[1][cf] = __builtin_amdgcn_mfma_f32_16x16x32_bf16(a1f, bf, acc[1][cf], 0, 0, 0);
    }
  }
  int rbase = n0 + wid*32 + ((lane>>4)<<2);
  int cbase = lane & 15;
  #pragma unroll
  for (int sub=0; sub<2; ++sub){
    #pragma unroll
    for (int cf=0; cf<7; ++cf){
      int col = cf*16 + cbase;
      #pragma unroll
      for (int r=0; r<4; ++r){
        int row = rbase + sub*16 + r;
        if (row < N_NODES){
          float v = acc[sub][cf][r];
          if (col < RD) Gh[(size_t)row*RD + col] = f2b(v);
          else if (col < RD+3) P[(size_t)row*4 + (col-RD)] = v;
        }
      }
    }
  }
}

// ---- level-2 pass 1 (MFMA): logits + DK (= v_k . e_y) + parent histogram ----
__global__ __launch_bounds__(256) void k_pass1_l2(
    const float* __restrict__ relT, const int* __restrict__ rel2i, const int* __restrict__ relrp2,
    const int* __restrict__ par, const int* __restrict__ chi, const int* __restrict__ roo,
    const unsigned short* __restrict__ Gh, const float* __restrict__ P,
    const unsigned short* __restrict__ MbT,
    const float* __restrict__ RINV, const float* __restrict__ RVW2,
    float* __restrict__ BBUF, float* __restrict__ DK, int* __restrict__ CNT){
  __shared__ unsigned short Cl[4*16*136];
  int lane = threadIdx.x & 63, wid = threadIdx.x >> 6;
  int ep = lane & 15, g = lane >> 4;
  unsigned short* cw = Cl + wid*16*136;
  int e = blockIdx.x*64 + wid*16 + ep;
  int ra = rel2i[e], rb = relrp2[e], rp = par[e], rc = chi[e], rr = roo[e];
  const float* rA = relT + (size_t)ra*RD;
  const float* rB = relT + (size_t)rb*RD;
  const unsigned short* gR = Gh + (size_t)rr*RD;
  const unsigned short* gX = Gh + (size_t)rp*RD;
  const unsigned short* gY = Gh + (size_t)rc*RD;
  float dgi = 0.f, dgx = 0.f, dgy = 0.f;
  bf16x8 af[4];
  #pragma unroll
  for (int ks=0; ks<4; ++ks){
    us8 cpack;
    #pragma unroll
    for (int h=0; h<2; ++h){
      int k0 = g*8 + ks*32 + h*4;
      float4 a4 = make_float4(0.f,0.f,0.f,0.f), b4 = a4, grr = a4, grp = a4, gry = a4;
      if (k0 <= 96){
        a4  = *(const float4*)(rA + k0);
        b4  = *(const float4*)(rB + k0);
        us4 r4 = *(const us4*)(gR + k0);
        us4 x4 = *(const us4*)(gX + k0);
        us4 y4 = *(const us4*)(gY + k0);
        grr = make_float4(b2f(r4[0]),b2f(r4[1]),b2f(r4[2]),b2f(r4[3]));
        grp = make_float4(b2f(x4[0]),b2f(x4[1]),b2f(x4[2]),b2f(x4[3]));
        gry = make_float4(b2f(y4[0]),b2f(y4[1]),b2f(y4[2]),b2f(y4[3]));
      }
      float4 c4;
      c4.x = a4.x*b4.x; c4.y = a4.y*b4.y; c4.z = a4.z*b4.z; c4.w = a4.w*b4.w;
      dgi += c4.x*grr.x + c4.y*grr.y + c4.z*grr.z + c4.w*grr.w;
      dgx += a4.x*grp.x + a4.y*grp.y + a4.z*grp.z + a4.w*grp.w;
      dgy += a4.x*gry.x + a4.y*gry.y + a4.z*gry.z + a4.w*gry.w;
      cpack[h*4+0]=f2b(c4.x); cpack[h*4+1]=f2b(c4.y); cpack[h*4+2]=f2b(c4.z); cpack[h*4+3]=f2b(c4.w);
    }
    *(us8*)((char*)cw + ep*272 + g*16 + ks*64) = cpack;
    af[ks] = *(bf16x8*)&cpack;
  }
  f32x4 acc[7];
  #pragma unroll
  for (int cf=0; cf<7; ++cf) acc[cf] = (f32x4){0.f,0.f,0.f,0.f};
  #pragma unroll
  for (int cf=0; cf<7; ++cf){
    #pragma unroll
    for (int ks=0; ks<4; ++ks){
      bf16x8 bfr = *(const bf16x8*)(MbT + (size_t)(cf*16+ep)*128 + g*8 + ks*32);
      acc[cf] = __builtin_amdgcn_mfma_f32_16x16x32_bf16(af[ks], bfr, acc[cf], 0, 0, 0);
    }
  }
  dgi += __shfl_xor(dgi, 16); dgi += __shfl_xor(dgi, 32);
  dgx += __shfl_xor(dgx, 16); dgx += __shfl_xor(dgx, 32);
  dgy += __shfl_xor(dgy, 16); dgy += __shfl_xor(dgy, 32);
  __syncthreads();
  #pragma unroll
  for (int r=0; r<4; ++r){
    int row = g*4 + r;
    float pr = 0.f;
    #pragma unroll
    for (int cf=0; cf<7; ++cf)
      pr += b2f(cw[row*136 + cf*16 + ep]) * acc[cf][r];
    pr += __shfl_xor(pr, 1); pr += __shfl_xor(pr, 2);
    pr += __shfl_xor(pr, 4); pr += __shfl_xor(pr, 8);
    float dw1r = __shfl(acc[6][r], (lane & 48) | 4);   // t[row][100]
    int src = (lane & 48) | row;
    float dgir = __shfl(dgi, src);
    float dgxr = __shfl(dgx, src);
    float dgyr = __shfl(dgy, src);
    int rar = __shfl(ra, src), rpr = __shfl(rp, src);
    int rcr = __shfl(rc, src), rrr = __shfl(rr, src);
    float invp = 1.f / fmaxf(sqrtf(pr), 1e-12f);
    float rinv = RINV[rar];
    float t1 = (dgir*invp)*(dw1r*invp);
    float t2 = (dgxr*rinv)*RVW2[rar];
    float bb = P[(size_t)rrr*4+0] - 2.f*t1 + P[(size_t)rpr*4+1] - 2.f*t2 + P[(size_t)rcr*4+2];
    bb = leaky(bb);
    if (ep == 0){
      int eo = blockIdx.x*64 + wid*16 + row;
      BBUF[eo] = bb;
      DK[eo] = dgyr * rinv;
      atomicAdd(&CNT[rpr], 1);
    }
  }
}

// ---- level-1 pass 1: logits + DK + parent histogram ----
__global__ __launch_bounds__(256) void k_pass1_l1(
    const float* __restrict__ relT, const int* __restrict__ rel1i,
    const int* __restrict__ par, const int* __restrict__ chi, const int* __restrict__ roo,
    const unsigned short* __restrict__ Gh, const float* __restrict__ P,
    const float* __restrict__ RINV, const float* __restrict__ RVW1, const float* __restrict__ RVW2,
    float* __restrict__ BBUF, float* __restrict__ DK, int* __restrict__ CNT){
  int lane = threadIdx.x & 63;
  int e = (blockIdx.x*256 + threadIdx.x) >> 6;
  if (e >= E1) return;
  int r = rel1i[e], pp = par[e], cc = chi[e], ii = roo[e];
  const float* rrow = relT + r*RD;
  const unsigned short* gI = Gh + (size_t)ii*RD;
  const unsigned short* gX = Gh + (size_t)pp*RD;
  const unsigned short* gY = Gh + (size_t)cc*RD;
  float ai = rrow[lane]*b2f(gI[lane]);
  float ax = rrow[lane]*b2f(gX[lane]);
  float ay = rrow[lane]*b2f(gY[lane]);
  if (lane < 36){
    ai += rrow[lane+64]*b2f(gI[lane+64]);
    ax += rrow[lane+64]*b2f(gX[lane+64]);
    ay += rrow[lane+64]*b2f(gY[lane+64]);
  }
  float dgi = wred(ai), dgx = wred(ax), dgy = wred(ay);
  if (lane == 0){
    float invn = RINV[r];
    float b = P[(size_t)ii*4+0] - 2.f*(dgi*invn)*RVW1[r]
            + P[(size_t)pp*4+1] - 2.f*(dgx*invn)*RVW2[r]
            + P[(size_t)cc*4+2];
    b = leaky(b);
    BBUF[e] = b;
    DK[e] = dgy * invn;
    atomicAdd(&CNT[pp], 1);
  }
}

// ---- CSR build: exclusive scan over CNT (block-local + block offsets) ----
__global__ __launch_bounds__(256) void k_scan_a(const int* __restrict__ CNT,
    int* __restrict__ ROFF, int* __restrict__ PART){
  __shared__ int ls[256];
  int i = blockIdx.x*256 + threadIdx.x;
  int v = (i < N_NODES) ? CNT[i] : 0;
  ls[threadIdx.x] = v;
  __syncthreads();
  for (int off=1; off<256; off<<=1){
    int t = (threadIdx.x >= off) ? ls[threadIdx.x-off] : 0;
    __syncthreads();
    ls[threadIdx.x] += t;
    __syncthreads();
  }
  int incl = ls[threadIdx.x];
  if (i < N_NODES) ROFF[i] = incl - v;
  if (threadIdx.x == 255) PART[blockIdx.x] = incl;
}
__global__ __launch_bounds__(512) void k_scan_b(int* __restrict__ PART){
  __shared__ int ls[512];
  int v = (threadIdx.x < SCAN_BLKS) ? PART[threadIdx.x] : 0;
  ls[threadIdx.x] = v;
  __syncthreads();
  for (int off=1; off<512; off<<=1){
    int t = (threadIdx.x >= off) ? ls[threadIdx.x-off] : 0;
    __syncthreads();
    ls[threadIdx.x] += t;
    __syncthreads();
  }
  if (threadIdx.x < SCAN_BLKS) PART[threadIdx.x] = ls[threadIdx.x] - v;
}
__global__ void k_scatter(const int* __restrict__ par, const int* __restrict__ ROFF,
                          const int* __restrict__ PART, int* __restrict__ CUR,
                          int* __restrict__ EIDX, int E){
  int e = blockIdx.x*blockDim.x + threadIdx.x;
  if (e >= E) return;
  int p = par[e];
  int pos = ROFF[p] + PART[p>>8] + atomicAdd(&CUR[p], 1);
  EIDX[pos] = e;
}

// ---- per-parent softmax + Householder aggregate; DK precomputed, no cross-lane in loop ----
__device__ __forceinline__ void agg_bucket(int p, int lane,
    const int* __restrict__ ROFF, const int* __restrict__ PART, const int* __restrict__ CNT,
    const int* __restrict__ EIDX, const float* __restrict__ BBUF, const float* __restrict__ DK,
    const int* __restrict__ chi, const int* __restrict__ relI,
    const unsigned short* __restrict__ Vh, const unsigned short* __restrict__ Xe,
    float acc[5]){
  int cnt = CNT[p];
  if (cnt <= 0) return;
  int base = ROFF[p] + PART[p>>8];
  if (cnt <= 64){
    float bl = (lane < cnt) ? BBUF[EIDX[base+lane]] : -1e30f;
    float m = bl;
    #pragma unroll
    for (int msk=32; msk>=1; msk>>=1) m = fmaxf(m, __shfl_xor(m, msk));
    float el = (lane < cnt) ? __expf(bl - m) : 0.f;
    float s = wred(el);
    float inv = 1.f / fmaxf(s, 1e-10f);
    for (int i=0;i<cnt;++i){
      int eid = EIDX[base+i];
      float a = __shfl(el, i) * inv;
      float s2 = 2.f*DK[eid]*a;
      int y = chi[eid], r = relI[eid];
      const unsigned short* vr = Vh + (size_t)r*D;
      const unsigned short* ey = Xe + (size_t)y*320;
      #pragma unroll
      for (int q=0;q<4;++q){
        int d = lane + 64*q;
        acc[q] += b2f(ey[d])*a - s2*b2f(vr[d]);
      }
      if (lane < 44){
        int d = lane + 256;
        acc[4] += b2f(ey[d])*a - s2*b2f(vr[d]);
      }
    }
  } else {
    float m = -1e30f;
    for (int i=0;i<cnt;++i) m = fmaxf(m, BBUF[EIDX[base+i]]);
    float s = 0.f;
    for (int i=0;i<cnt;++i) s += __expf(BBUF[EIDX[base+i]] - m);
    float inv = 1.f / fmaxf(s, 1e-10f);
    for (int i=0;i<cnt;++i){
      int eid = EIDX[base+i];
      float a = __expf(BBUF[eid]-m)*inv;
      float s2 = 2.f*DK[eid]*a;
      int y = chi[eid], r = relI[eid];
      const unsigned short* vr = Vh + (size_t)r*D;
      const unsigned short* ey = Xe + (size_t)y*320;
      #pragma unroll
      for (int q=0;q<4;++q){
        int d = lane + 64*q;
        acc[q] += b2f(ey[d])*a - s2*b2f(vr[d]);
      }
      if (lane < 44){
        int d = lane + 256;
        acc[4] += b2f(ey[d])*a - s2*b2f(vr[d]);
      }
    }
  }
}

// ---- level-2: one wave per parent; writes bf16 Xb2 row (incl. zero pad) ----
__global__ __launch_bounds__(256) void k_agg2(const int* __restrict__ ROFF, const int* __restrict__ PART,
    const int* __restrict__ CNT, const int* __restrict__ EIDX,
    const float* __restrict__ BBUF, const float* __restrict__ DK,
    const int* __restrict__ chi, const int* __restrict__ relI,
    const unsigned short* __restrict__ Vh, const unsigned short* __restrict__ Xe,
    unsigned short* __restrict__ Xo){
  int lane = threadIdx.x & 63;
  int p = (blockIdx.x*256 + threadIdx.x) >> 6;
  if (p >= N_NODES) return;
  float acc[5] = {0.f,0.f,0.f,0.f,0.f};
  agg_bucket(p, lane, ROFF, PART, CNT, EIDX, BBUF, DK, chi, relI, Vh, Xe, acc);
  const unsigned short* in = Xe + (size_t)p*320;
  unsigned short* op = Xo + (size_t)p*320;
  #pragma unroll
  for (int q=0;q<4;++q){
    int d = lane + 64*q;
    op[d] = f2b(leaky(b2f(in[d]) + acc[q]));
  }
  {
    int d = lane + 256;
    unsigned short o = 0;
    if (lane < 44) o = f2b(leaky(b2f(in[d]) + acc[4]));
    op[d] = o;
  }
}

// ---- level-1: one wave per OUTPUT (8192); writes d_out directly ----
__global__ __launch_bounds__(256) void k_aggout(const int* __restrict__ ro,
    const int* __restrict__ ROFF, const int* __restrict__ PART,
    const int* __restrict__ CNT, const int* __restrict__ EIDX,
    const float* __restrict__ BBUF, const float* __restrict__ DK,
    const int* __restrict__ chi, const int* __restrict__ relI,
    const unsigned short* __restrict__ Vh, const unsigned short* __restrict__ Xe,
    float* __restrict__ out){
  int lane = threadIdx.x & 63;
  int o = (blockIdx.x*256 + threadIdx.x) >> 6;
  if (o >= NB) return;
  int p = ro[o];
  float acc[5] = {0.f,0.f,0.f,0.f,0.f};
  agg_bucket(p, lane, ROFF, PART, CNT, EIDX, BBUF, DK, chi, relI, Vh, Xe, acc);
  const unsigned short* in = Xe + (size_t)p*320;
  float* op = out + (size_t)o*D;
  #pragma unroll
  for (int q=0;q<4;++q){
    int d = lane + 64*q;
    op[d] = leaky(b2f(in[d]) + acc[q]);
  }
  if (lane < 44){
    int d = lane + 256;
    op[d] = leaky(b2f(in[d]) + acc[4]);
  }
}

extern "C" void kernel_launch(void* const* d_in, const int* in_sizes, int n_in,
                              void* d_out, int out_size, void* d_ws, size_t ws_size,
                              hipStream_t stream){
  const float* node = (const float*)d_in[0];
  const float* relT = (const float*)d_in[1];
  const float* W    = (const float*)d_in[2];
  const float* watt = (const float*)d_in[3];
  const int* par2 = (const int*)d_in[4];
  const int* chi2 = (const int*)d_in[5];
  const int* roo2 = (const int*)d_in[6];
  const int* rel2i = (const int*)d_in[7];
  const int* relrp2 = (const int*)d_in[8];
  const int* par1 = (const int*)d_in[9];
  const int* chi1 = (const int*)d_in[10];
  const int* roo1 = (const int*)d_in[11];
  const int* rel1i = (const int*)d_in[12];
  const int* roout = (const int*)d_in[13];

  char* w = (char*)d_ws;
  size_t off = 0;
  auto alloc = [&](size_t bytes)->void*{ void* p = w + off; off += (bytes + 255) & ~(size_t)255; return p; };
  unsigned short* Gh = (unsigned short*)alloc((size_t)N_NODES*RD*2);
  float* P    = (float*)alloc((size_t)N_NODES*4*4);
  unsigned short* Vh = (unsigned short*)alloc((size_t)NREL*D*2);
  float* RINV = (float*)alloc(NREL*4);
  float* RVW1 = (float*)alloc(NREL*4);
  float* RVW2 = (float*)alloc(NREL*4);
  float* BBUF = (float*)alloc((size_t)E2*4);
  float* DKb  = (float*)alloc((size_t)E2*4);
  unsigned short* Xb  = (unsigned short*)alloc((size_t)NPAD*320*2);
  unsigned short* Xb2 = (unsigned short*)alloc((size_t)NPAD*320*2);
  unsigned short* Bt  = (unsigned short*)alloc((size_t)112*320*2);
  unsigned short* MbT = (unsigned short*)alloc((size_t)112*128*2);
  unsigned short* WtB = (unsigned short*)alloc((size_t)304*128*2);
  unsigned short* Rb  = (unsigned short*)alloc((size_t)1024*128*2);
  int* CNT  = (int*)alloc((size_t)N_NODES*4);
  int* ROFF = (int*)alloc((size_t)N_NODES*4);
  int* CUR  = (int*)alloc((size_t)N_NODES*4);
  int* PART = (int*)alloc(512*4);
  int* EIDX = (int*)alloc((size_t)E2*4);

  // constants
  k_prep2b<<<dim3(56), dim3(256), 0, stream>>>(W, watt, MbT);
  k_prepAll<<<dim3(356), dim3(256), 0, stream>>>(W, watt, relT, Bt, WtB, Rb);
  k_relmm<<<dim3(16), dim3(256), 0, stream>>>(Rb, WtB, watt, Vh, RINV, RVW1, RVW2);

  // ---------- level 2 ----------
  k_cast<<<dim3(2048), dim3(256), 0, stream>>>(node, Xb);
  k_nodetab2<<<dim3((N_NODES+127)/128), dim3(256), 0, stream>>>(Xb, Bt, Gh, P, CNT, CUR);
  k_pass1_l2<<<dim3(E2/64), dim3(256), 0, stream>>>(relT, rel2i, relrp2, par2, chi2, roo2,
                                                    Gh, P, MbT, RINV, RVW2, BBUF, DKb, CNT);
  k_scan_a<<<dim3(SCAN_BLKS), dim3(256), 0, stream>>>(CNT, ROFF, PART);
  k_scan_b<<<dim3(1), dim3(512), 0, stream>>>(PART);
  k_scatter<<<dim3((E2+255)/256), dim3(256), 0, stream>>>(par2, ROFF, PART, CUR, EIDX, E2);
  k_agg2<<<dim3((N_NODES+3)/4), dim3(256), 0, stream>>>(ROFF, PART, CNT, EIDX, BBUF, DKb,
                                                        chi2, rel2i, Vh, Xb, Xb2);

  // ---------- level 1 ----------
  k_nodetab2<<<dim3((N_NODES+127)/128), dim3(256), 0, stream>>>(Xb2, Bt, Gh, P, CNT, CUR);
  k_pass1_l1<<<dim3((E1+3)/4), dim3(256), 0, stream>>>(relT, rel1i, par1, chi1, roo1,
                                                       Gh, P, RINV, RVW1, RVW2, BBUF, DKb, CNT);
  k_scan_a<<<dim3(SCAN_BLKS), dim3(256), 0, stream>>>(CNT, ROFF, PART);
  k_scan_b<<<dim3(1), dim3(512), 0, stream>>>(PART);
  k_scatter<<<dim3((E1+255)/256), dim3(256), 0, stream>>>(par1, ROFF, PART, CUR, EIDX, E1);
  k_aggout<<<dim3((NB+3)/4), dim3(256), 0, stream>>>(roout, ROFF, PART, CNT, EIDX, BBUF, DKb,
                                                     chi1, rel1i, Vh, Xb2, (float*)d_out);
}

// Round 8
// 327.726 us; speedup vs baseline: 4.2454x; 1.2047x over previous
//
#include <hip/hip_runtime.h>
#include <hip/hip_bf16.h>
#include <cstdint>

#define N_NODES 100000
#define NPAD 100096
#define D 300
#define RD 100
#define NREL 1000
#define E2 200000
#define E1 100000
#define NB 8192
#define NEG 0.2f
#define SCAN_BLKS 391   // ceil(100000/256)

typedef __bf16 bf16x8 __attribute__((ext_vector_type(8)));
typedef float f32x4 __attribute__((ext_vector_type(4)));
typedef unsigned short us4 __attribute__((ext_vector_type(4)));
typedef unsigned short us8 __attribute__((ext_vector_type(8)));

__device__ __forceinline__ float leaky(float x){ return x >= 0.f ? x : NEG*x; }

__device__ __forceinline__ unsigned short f2b(float v){
  unsigned u = __float_as_uint(v);
  unsigned r = u + 0x7FFF + ((u>>16)&1u);
  return (unsigned short)(r>>16);
}
__device__ __forceinline__ float b2f(unsigned short b){
  return __uint_as_float(((unsigned)b) << 16);
}
__device__ __forceinline__ float wred(float v){
  #pragma unroll
  for (int m = 32; m >= 1; m >>= 1) v += __shfl_xor(v, m, 64);
  return v;
}

// ---- backward-slice flags: FRO[n]=1 if n in root_out; ND2 = RO u {roo1,par1,chi1 | par1 in RO}
__global__ void k_flag(const int* __restrict__ ro, int* __restrict__ FRO){
  int o = blockIdx.x*256 + threadIdx.x;
  if (o < NB) FRO[ro[o]] = 1;
}
__global__ void k_need(const int* __restrict__ par1, const int* __restrict__ chi1,
                       const int* __restrict__ roo1, const int* __restrict__ ro,
                       const int* __restrict__ FRO, int* __restrict__ ND2){
  int i = blockIdx.x*256 + threadIdx.x;
  if (i < NB) ND2[ro[i]] = 1;
  if (i < E1){
    int p = par1[i];
    if (FRO[p]){ ND2[p] = 1; ND2[chi1[i]] = 1; ND2[roo1[i]] = 1; }
  }
}

// ---- MbT[112][128] bf16: rows j<100 -> M[j][i]=sum_d W[d][i]W[d][j]; row 100 -> W^T w1 ----
__global__ void k_prep2b(const float* __restrict__ W, const float* __restrict__ watt,
                         unsigned short* __restrict__ MbT){
  int u = blockIdx.x*blockDim.x + threadIdx.x;
  if (u >= 112*128) return;
  int j = u >> 7, i = u & 127;
  float v = 0.f;
  if (i < RD){
    if (j < RD){ float a=0.f; for (int d=0;d<D;++d) a += W[d*RD+i]*W[d*RD+j]; v=a; }
    else if (j == RD){ float a=0.f; for (int d=0;d<D;++d) a += watt[d]*W[d*RD+i]; v=a; }
  }
  MbT[u] = f2b(v);
}

// ---- fused prep: Bt[112][320], WtB[304][128], Rb[1024][128] ----
__global__ void k_prepAll(const float* __restrict__ W, const float* __restrict__ watt,
                          const float* __restrict__ relT, unsigned short* __restrict__ Bt,
                          unsigned short* __restrict__ WtB, unsigned short* __restrict__ Rb){
  int b = blockIdx.x;
  if (b < 140){
    int u = b*256 + threadIdx.x;
    if (u < 112*320){
      int c = u / 320, k = u % 320;
      float v = 0.f;
      if (k < D){
        if (c < RD) v = W[k*RD + c];
        else if (c < RD+3) v = watt[(c-RD)*D + k];
      }
      Bt[u] = f2b(v);
    }
  } else if (b < 292){
    int u = (b-140)*256 + threadIdx.x;
    if (u < 304*128){
      int dd = u >> 7, k = u & 127;
      float v = (dd < D && k < RD) ? W[dd*RD + k] : 0.f;
      WtB[u] = f2b(v);
    }
  } else {
    int u = (b-292)*256 + threadIdx.x;
    if (u < 1024*16){
      int row = u >> 4, c8 = (u & 15)*8;
      us8 o;
      #pragma unroll
      for (int j=0;j<8;++j){
        int c = c8+j;
        o[j] = (row < NREL && c < RD) ? f2b(relT[row*RD + c]) : (unsigned short)0;
      }
      *(us8*)(Rb + (size_t)row*128 + c8) = o;
    }
  }
}

// ---- MFMA relation tables: U = Rb @ WtB^T -> Vh (bf16), RINV, RVW1, RVW2 ----
__global__ __launch_bounds__(256) void k_relmm(const unsigned short* __restrict__ Rb,
    const unsigned short* __restrict__ WtB, const float* __restrict__ watt,
    unsigned short* __restrict__ Vh, float* __restrict__ RINV,
    float* __restrict__ RVW1, float* __restrict__ RVW2){
  int lane = threadIdx.x & 63, wid = threadIdx.x >> 6;
  int r0 = blockIdx.x*64 + wid*16;
  int ep = lane & 15, g = lane >> 4;
  size_t a0 = (size_t)(r0 + ep)*128 + g*8;
  size_t b0 = (size_t)ep*128 + g*8;
  f32x4 acc[19];
  #pragma unroll
  for (int cf=0;cf<19;++cf) acc[cf]=(f32x4){0.f,0.f,0.f,0.f};
  #pragma unroll
  for (int ks=0; ks<4; ++ks){
    bf16x8 af = *(const bf16x8*)(Rb + a0 + ks*32);
    #pragma unroll
    for (int cf=0; cf<19; ++cf){
      bf16x8 bf = *(const bf16x8*)(WtB + b0 + (size_t)cf*16*128 + ks*32);
      acc[cf] = __builtin_amdgcn_mfma_f32_16x16x32_bf16(af, bf, acc[cf], 0, 0, 0);
    }
  }
  float w1v[19], w2v[19];
  #pragma unroll
  for (int cf=0; cf<19; ++cf){
    int col = cf*16+ep;
    bool ok = col < D;
    w1v[cf] = ok ? watt[col] : 0.f;
    w2v[cf] = ok ? watt[D+col] : 0.f;
  }
  #pragma unroll
  for (int reg=0; reg<4; ++reg){
    int row = r0 + g*4 + reg;
    float np = 0.f;
    #pragma unroll
    for (int cf=0; cf<19; ++cf){ float u = acc[cf][reg]; np += u*u; }
    np += __shfl_xor(np,1); np += __shfl_xor(np,2); np += __shfl_xor(np,4); np += __shfl_xor(np,8);
    float iv = 1.f / fmaxf(sqrtf(np), 1e-12f);
    float p1 = 0.f, p2 = 0.f;
    if (row < NREL){
      #pragma unroll
      for (int cf=0; cf<19; ++cf){
        int col = cf*16+ep;
        float v = acc[cf][reg]*iv;
        if (col < D){
          Vh[(size_t)row*D + col] = f2b(v);
          p1 += v*w1v[cf];
          p2 += v*w2v[cf];
        }
      }
    }
    p1 += __shfl_xor(p1,1); p1 += __shfl_xor(p1,2); p1 += __shfl_xor(p1,4); p1 += __shfl_xor(p1,8);
    p2 += __shfl_xor(p2,1); p2 += __shfl_xor(p2,2); p2 += __shfl_xor(p2,4); p2 += __shfl_xor(p2,8);
    if (ep == 0 && row < NREL){
      RINV[row] = iv; RVW1[row] = p1; RVW2[row] = p2;
    }
  }
}

// ---- cast node embeddings to padded bf16 table Xb[NPAD][320] ----
__global__ void k_cast(const float* __restrict__ src, unsigned short* __restrict__ dst){
  int total = NPAD*40;
  for (int u = blockIdx.x*blockDim.x + threadIdx.x; u < total; u += gridDim.x*blockDim.x){
    int row = u/40, c8 = (u%40)*8;
    us8 o;
    if (row < N_NODES && c8 <= 292){
      float4 x = *(const float4*)(src + (size_t)row*D + c8);
      float4 y = *(const float4*)(src + (size_t)row*D + c8 + 4);
      o[0]=f2b(x.x); o[1]=f2b(x.y); o[2]=f2b(x.z); o[3]=f2b(x.w);
      o[4]=f2b(y.x); o[5]=f2b(y.y); o[6]=f2b(y.z); o[7]=f2b(y.w);
    } else {
      #pragma unroll
      for (int j=0;j<8;++j){
        int c = c8+j;
        float v = (row < N_NODES && c < D) ? src[(size_t)row*D + c] : 0.f;
        o[j] = f2b(v);
      }
    }
    *(us8*)(dst + (size_t)row*320 + c8) = o;
  }
}

// ---- MFMA node tables: Gh[n] = bf16(W^T e_n), P[n]; also zeroes CNT/CUR ----
__global__ __launch_bounds__(256) void k_nodetab2(const unsigned short* __restrict__ Eb,
    const unsigned short* __restrict__ Bt, unsigned short* __restrict__ Gh, float* __restrict__ P,
    int* __restrict__ CNT, int* __restrict__ CUR){
  int z = blockIdx.x*256 + threadIdx.x;
  if (z < N_NODES){ CNT[z] = 0; CUR[z] = 0; }
  int lane = threadIdx.x & 63, wid = threadIdx.x >> 6;
  int n0 = blockIdx.x*128;
  size_t a0 = (size_t)(n0 + wid*32 + (lane&15))*320 + ((lane>>4)*8);
  size_t b0 = (size_t)(lane&15)*320 + ((lane>>4)*8);
  f32x4 acc[2][7];
  #pragma unroll
  for (int s=0;s<2;++s)
    #pragma unroll
    for (int c=0;c<7;++c) acc[s][c] = (f32x4){0.f,0.f,0.f,0.f};
  for (int ks = 0; ks < 10; ++ks){
    bf16x8 a0f = *(const bf16x8*)(Eb + a0 + ks*32);
    bf16x8 a1f = *(const bf16x8*)(Eb + a0 + 16*320 + ks*32);
    #pragma unroll
    for (int cf=0; cf<7; ++cf){
      bf16x8 bf = *(const bf16x8*)(Bt + b0 + (size_t)cf*16*320 + ks*32);
      acc[0][cf] = __builtin_amdgcn_mfma_f32_16x16x32_bf16(a0f, bf, acc[0][cf], 0, 0, 0);
      acc[1][cf] = __builtin_amdgcn_mfma_f32_16x16x32_bf16(a1f, bf, acc[1][cf], 0, 0, 0);
    }
  }
  int rbase = n0 + wid*32 + ((lane>>4)<<2);
  int cbase = lane & 15;
  #pragma unroll
  for (int sub=0; sub<2; ++sub){
    #pragma unroll
    for (int cf=0; cf<7; ++cf){
      int col = cf*16 + cbase;
      #pragma unroll
      for (int r=0; r<4; ++r){
        int row = rbase + sub*16 + r;
        if (row < N_NODES){
          float v = acc[sub][cf][r];
          if (col < RD) Gh[(size_t)row*RD + col] = f2b(v);
          else if (col < RD+3) P[(size_t)row*4 + (col-RD)] = v;
        }
      }
    }
  }
}

// ---- level-2 pass 1 (MFMA): logits + DK + parent histogram; masked by ND2[parent] ----
__global__ __launch_bounds__(256) void k_pass1_l2(
    const float* __restrict__ relT, const int* __restrict__ rel2i, const int* __restrict__ relrp2,
    const int* __restrict__ par, const int* __restrict__ chi, const int* __restrict__ roo,
    const unsigned short* __restrict__ Gh, const float* __restrict__ P,
    const unsigned short* __restrict__ MbT,
    const float* __restrict__ RINV, const float* __restrict__ RVW2,
    const int* __restrict__ ND2,
    float* __restrict__ BBUF, float* __restrict__ DK, int* __restrict__ CNT){
  __shared__ unsigned short Cl[4*16*136];
  int lane = threadIdx.x & 63, wid = threadIdx.x >> 6;
  int ep = lane & 15, g = lane >> 4;
  unsigned short* cw = Cl + wid*16*136;
  int e = blockIdx.x*64 + wid*16 + ep;
  int rp = par[e];
  int live = ND2[rp];
  int ra = rel2i[e], rb = relrp2[e], rc = chi[e], rr = roo[e];
  const float* rA = relT + (size_t)ra*RD;
  const float* rB = relT + (size_t)rb*RD;
  const unsigned short* gR = Gh + (size_t)rr*RD;
  const unsigned short* gX = Gh + (size_t)rp*RD;
  const unsigned short* gY = Gh + (size_t)rc*RD;
  float dgi = 0.f, dgx = 0.f, dgy = 0.f;
  bf16x8 af[4];
  #pragma unroll
  for (int ks=0; ks<4; ++ks){
    us8 cpack;
    #pragma unroll
    for (int h=0; h<2; ++h){
      int k0 = g*8 + ks*32 + h*4;
      float4 a4 = make_float4(0.f,0.f,0.f,0.f), b4 = a4, grr = a4, grp = a4, gry = a4;
      if (live && k0 <= 96){
        a4  = *(const float4*)(rA + k0);
        b4  = *(const float4*)(rB + k0);
        us4 r4 = *(const us4*)(gR + k0);
        us4 x4 = *(const us4*)(gX + k0);
        us4 y4 = *(const us4*)(gY + k0);
        grr = make_float4(b2f(r4[0]),b2f(r4[1]),b2f(r4[2]),b2f(r4[3]));
        grp = make_float4(b2f(x4[0]),b2f(x4[1]),b2f(x4[2]),b2f(x4[3]));
        gry = make_float4(b2f(y4[0]),b2f(y4[1]),b2f(y4[2]),b2f(y4[3]));
      }
      float4 c4;
      c4.x = a4.x*b4.x; c4.y = a4.y*b4.y; c4.z = a4.z*b4.z; c4.w = a4.w*b4.w;
      dgi += c4.x*grr.x + c4.y*grr.y + c4.z*grr.z + c4.w*grr.w;
      dgx += a4.x*grp.x + a4.y*grp.y + a4.z*grp.z + a4.w*grp.w;
      dgy += a4.x*gry.x + a4.y*gry.y + a4.z*gry.z + a4.w*gry.w;
      cpack[h*4+0]=f2b(c4.x); cpack[h*4+1]=f2b(c4.y); cpack[h*4+2]=f2b(c4.z); cpack[h*4+3]=f2b(c4.w);
    }
    *(us8*)((char*)cw + ep*272 + g*16 + ks*64) = cpack;
    af[ks] = *(bf16x8*)&cpack;
  }
  f32x4 acc[7];
  #pragma unroll
  for (int cf=0; cf<7; ++cf) acc[cf] = (f32x4){0.f,0.f,0.f,0.f};
  #pragma unroll
  for (int cf=0; cf<7; ++cf){
    #pragma unroll
    for (int ks=0; ks<4; ++ks){
      bf16x8 bfr = *(const bf16x8*)(MbT + (size_t)(cf*16+ep)*128 + g*8 + ks*32);
      acc[cf] = __builtin_amdgcn_mfma_f32_16x16x32_bf16(af[ks], bfr, acc[cf], 0, 0, 0);
    }
  }
  dgi += __shfl_xor(dgi, 16); dgi += __shfl_xor(dgi, 32);
  dgx += __shfl_xor(dgx, 16); dgx += __shfl_xor(dgx, 32);
  dgy += __shfl_xor(dgy, 16); dgy += __shfl_xor(dgy, 32);
  __syncthreads();
  #pragma unroll
  for (int r=0; r<4; ++r){
    int row = g*4 + r;
    int src = (lane & 48) | row;
    int livr = __shfl(live, src);
    if (!livr) continue;
    float pr = 0.f;
    #pragma unroll
    for (int cf=0; cf<7; ++cf)
      pr += b2f(cw[row*136 + cf*16 + ep]) * acc[cf][r];
    pr += __shfl_xor(pr, 1); pr += __shfl_xor(pr, 2);
    pr += __shfl_xor(pr, 4); pr += __shfl_xor(pr, 8);
    float dw1r = __shfl(acc[6][r], (lane & 48) | 4);   // t[row][100]
    float dgir = __shfl(dgi, src);
    float dgxr = __shfl(dgx, src);
    float dgyr = __shfl(dgy, src);
    int rar = __shfl(ra, src), rpr = __shfl(rp, src);
    int rcr = __shfl(rc, src), rrr = __shfl(rr, src);
    float invp = 1.f / fmaxf(sqrtf(pr), 1e-12f);
    float rinv = RINV[rar];
    float t1 = (dgir*invp)*(dw1r*invp);
    float t2 = (dgxr*rinv)*RVW2[rar];
    float bb = P[(size_t)rrr*4+0] - 2.f*t1 + P[(size_t)rpr*4+1] - 2.f*t2 + P[(size_t)rcr*4+2];
    bb = leaky(bb);
    if (ep == 0){
      int eo = blockIdx.x*64 + wid*16 + row;
      BBUF[eo] = bb;
      DK[eo] = dgyr * rinv;
      atomicAdd(&CNT[rpr], 1);
    }
  }
}

// ---- level-1 pass 1: logits + DK + histogram; only edges with par in root_out ----
__global__ __launch_bounds__(256) void k_pass1_l1(
    const float* __restrict__ relT, const int* __restrict__ rel1i,
    const int* __restrict__ par, const int* __restrict__ chi, const int* __restrict__ roo,
    const unsigned short* __restrict__ Gh, const float* __restrict__ P,
    const float* __restrict__ RINV, const float* __restrict__ RVW1, const float* __restrict__ RVW2,
    const int* __restrict__ FRO,
    float* __restrict__ BBUF, float* __restrict__ DK, int* __restrict__ CNT){
  int lane = threadIdx.x & 63;
  int e = (blockIdx.x*256 + threadIdx.x) >> 6;
  if (e >= E1) return;
  int pp = par[e];
  if (!FRO[pp]) return;
  int r = rel1i[e], cc = chi[e], ii = roo[e];
  const float* rrow = relT + r*RD;
  const unsigned short* gI = Gh + (size_t)ii*RD;
  const unsigned short* gX = Gh + (size_t)pp*RD;
  const unsigned short* gY = Gh + (size_t)cc*RD;
  float ai = rrow[lane]*b2f(gI[lane]);
  float ax = rrow[lane]*b2f(gX[lane]);
  float ay = rrow[lane]*b2f(gY[lane]);
  if (lane < 36){
    ai += rrow[lane+64]*b2f(gI[lane+64]);
    ax += rrow[lane+64]*b2f(gX[lane+64]);
    ay += rrow[lane+64]*b2f(gY[lane+64]);
  }
  float dgi = wred(ai), dgx = wred(ax), dgy = wred(ay);
  if (lane == 0){
    float invn = RINV[r];
    float b = P[(size_t)ii*4+0] - 2.f*(dgi*invn)*RVW1[r]
            + P[(size_t)pp*4+1] - 2.f*(dgx*invn)*RVW2[r]
            + P[(size_t)cc*4+2];
    b = leaky(b);
    BBUF[e] = b;
    DK[e] = dgy * invn;
    atomicAdd(&CNT[pp], 1);
  }
}

// ---- CSR build: exclusive scan over CNT (block-local + block offsets) ----
__global__ __launch_bounds__(256) void k_scan_a(const int* __restrict__ CNT,
    int* __restrict__ ROFF, int* __restrict__ PART){
  __shared__ int ls[256];
  int i = blockIdx.x*256 + threadIdx.x;
  int v = (i < N_NODES) ? CNT[i] : 0;
  ls[threadIdx.x] = v;
  __syncthreads();
  for (int off=1; off<256; off<<=1){
    int t = (threadIdx.x >= off) ? ls[threadIdx.x-off] : 0;
    __syncthreads();
    ls[threadIdx.x] += t;
    __syncthreads();
  }
  int incl = ls[threadIdx.x];
  if (i < N_NODES) ROFF[i] = incl - v;
  if (threadIdx.x == 255) PART[blockIdx.x] = incl;
}
__global__ __launch_bounds__(512) void k_scan_b(int* __restrict__ PART){
  __shared__ int ls[512];
  int v = (threadIdx.x < SCAN_BLKS) ? PART[threadIdx.x] : 0;
  ls[threadIdx.x] = v;
  __syncthreads();
  for (int off=1; off<512; off<<=1){
    int t = (threadIdx.x >= off) ? ls[threadIdx.x-off] : 0;
    __syncthreads();
    ls[threadIdx.x] += t;
    __syncthreads();
  }
  if (threadIdx.x < SCAN_BLKS) PART[threadIdx.x] = ls[threadIdx.x] - v;
}
__global__ void k_scatter(const int* __restrict__ par, const int* __restrict__ ROFF,
                          const int* __restrict__ PART, const int* __restrict__ FLG,
                          int* __restrict__ CUR, int* __restrict__ EIDX, int E){
  int e = blockIdx.x*blockDim.x + threadIdx.x;
  if (e >= E) return;
  int p = par[e];
  if (!FLG[p]) return;
  int pos = ROFF[p] + PART[p>>8] + atomicAdd(&CUR[p], 1);
  EIDX[pos] = e;
}

// ---- per-parent softmax + Householder aggregate; DK precomputed ----
__device__ __forceinline__ void agg_bucket(int p, int lane,
    const int* __restrict__ ROFF, const int* __restrict__ PART, const int* __restrict__ CNT,
    const int* __restrict__ EIDX, const float* __restrict__ BBUF, const float* __restrict__ DK,
    const int* __restrict__ chi, const int* __restrict__ relI,
    const unsigned short* __restrict__ Vh, const unsigned short* __restrict__ Xe,
    float acc[5]){
  int cnt = CNT[p];
  if (cnt <= 0) return;
  int base = ROFF[p] + PART[p>>8];
  if (cnt <= 64){
    float bl = (lane < cnt) ? BBUF[EIDX[base+lane]] : -1e30f;
    float m = bl;
    #pragma unroll
    for (int msk=32; msk>=1; msk>>=1) m = fmaxf(m, __shfl_xor(m, msk));
    float el = (lane < cnt) ? __expf(bl - m) : 0.f;
    float s = wred(el);
    float inv = 1.f / fmaxf(s, 1e-10f);
    for (int i=0;i<cnt;++i){
      int eid = EIDX[base+i];
      float a = __shfl(el, i) * inv;
      float s2 = 2.f*DK[eid]*a;
      int y = chi[eid], r = relI[eid];
      const unsigned short* vr = Vh + (size_t)r*D;
      const unsigned short* ey = Xe + (size_t)y*320;
      #pragma unroll
      for (int q=0;q<4;++q){
        int d = lane + 64*q;
        acc[q] += b2f(ey[d])*a - s2*b2f(vr[d]);
      }
      if (lane < 44){
        int d = lane + 256;
        acc[4] += b2f(ey[d])*a - s2*b2f(vr[d]);
      }
    }
  } else {
    float m = -1e30f;
    for (int i=0;i<cnt;++i) m = fmaxf(m, BBUF[EIDX[base+i]]);
    float s = 0.f;
    for (int i=0;i<cnt;++i) s += __expf(BBUF[EIDX[base+i]] - m);
    float inv = 1.f / fmaxf(s, 1e-10f);
    for (int i=0;i<cnt;++i){
      int eid = EIDX[base+i];
      float a = __expf(BBUF[eid]-m)*inv;
      float s2 = 2.f*DK[eid]*a;
      int y = chi[eid], r = relI[eid];
      const unsigned short* vr = Vh + (size_t)r*D;
      const unsigned short* ey = Xe + (size_t)y*320;
      #pragma unroll
      for (int q=0;q<4;++q){
        int d = lane + 64*q;
        acc[q] += b2f(ey[d])*a - s2*b2f(vr[d]);
      }
      if (lane < 44){
        int d = lane + 256;
        acc[4] += b2f(ey[d])*a - s2*b2f(vr[d]);
      }
    }
  }
}

// ---- level-2: one wave per NEEDED parent; writes bf16 Xb2 row ----
__global__ __launch_bounds__(256) void k_agg2(const int* __restrict__ ROFF, const int* __restrict__ PART,
    const int* __restrict__ CNT, const int* __restrict__ EIDX,
    const float* __restrict__ BBUF, const float* __restrict__ DK,
    const int* __restrict__ chi, const int* __restrict__ relI,
    const unsigned short* __restrict__ Vh, const unsigned short* __restrict__ Xe,
    const int* __restrict__ ND2,
    unsigned short* __restrict__ Xo){
  int lane = threadIdx.x & 63;
  int p = (blockIdx.x*256 + threadIdx.x) >> 6;
  if (p >= N_NODES) return;
  if (!ND2[p]) return;
  float acc[5] = {0.f,0.f,0.f,0.f,0.f};
  agg_bucket(p, lane, ROFF, PART, CNT, EIDX, BBUF, DK, chi, relI, Vh, Xe, acc);
  const unsigned short* in = Xe + (size_t)p*320;
  unsigned short* op = Xo + (size_t)p*320;
  #pragma unroll
  for (int q=0;q<4;++q){
    int d = lane + 64*q;
    op[d] = f2b(leaky(b2f(in[d]) + acc[q]));
  }
  {
    int d = lane + 256;
    unsigned short o = 0;
    if (lane < 44) o = f2b(leaky(b2f(in[d]) + acc[4]));
    op[d] = o;
  }
}

// ---- level-1: one wave per OUTPUT (8192); writes d_out directly ----
__global__ __launch_bounds__(256) void k_aggout(const int* __restrict__ ro,
    const int* __restrict__ ROFF, const int* __restrict__ PART,
    const int* __restrict__ CNT, const int* __restrict__ EIDX,
    const float* __restrict__ BBUF, const float* __restrict__ DK,
    const int* __restrict__ chi, const int* __restrict__ relI,
    const unsigned short* __restrict__ Vh, const unsigned short* __restrict__ Xe,
    float* __restrict__ out){
  int lane = threadIdx.x & 63;
  int o = (blockIdx.x*256 + threadIdx.x) >> 6;
  if (o >= NB) return;
  int p = ro[o];
  float acc[5] = {0.f,0.f,0.f,0.f,0.f};
  agg_bucket(p, lane, ROFF, PART, CNT, EIDX, BBUF, DK, chi, relI, Vh, Xe, acc);
  const unsigned short* in = Xe + (size_t)p*320;
  float* op = out + (size_t)o*D;
  #pragma unroll
  for (int q=0;q<4;++q){
    int d = lane + 64*q;
    op[d] = leaky(b2f(in[d]) + acc[q]);
  }
  if (lane < 44){
    int d = lane + 256;
    op[d] = leaky(b2f(in[d]) + acc[4]);
  }
}

extern "C" void kernel_launch(void* const* d_in, const int* in_sizes, int n_in,
                              void* d_out, int out_size, void* d_ws, size_t ws_size,
                              hipStream_t stream){
  const float* node = (const float*)d_in[0];
  const float* relT = (const float*)d_in[1];
  const float* W    = (const float*)d_in[2];
  const float* watt = (const float*)d_in[3];
  const int* par2 = (const int*)d_in[4];
  const int* chi2 = (const int*)d_in[5];
  const int* roo2 = (const int*)d_in[6];
  const int* rel2i = (const int*)d_in[7];
  const int* relrp2 = (const int*)d_in[8];
  const int* par1 = (const int*)d_in[9];
  const int* chi1 = (const int*)d_in[10];
  const int* roo1 = (const int*)d_in[11];
  const int* rel1i = (const int*)d_in[12];
  const int* roout = (const int*)d_in[13];

  char* w = (char*)d_ws;
  size_t off = 0;
  auto alloc = [&](size_t bytes)->void*{ void* p = w + off; off += (bytes + 255) & ~(size_t)255; return p; };
  unsigned short* Gh = (unsigned short*)alloc((size_t)N_NODES*RD*2);
  float* P    = (float*)alloc((size_t)N_NODES*4*4);
  unsigned short* Vh = (unsigned short*)alloc((size_t)NREL*D*2);
  float* RINV = (float*)alloc(NREL*4);
  float* RVW1 = (float*)alloc(NREL*4);
  float* RVW2 = (float*)alloc(NREL*4);
  float* BBUF = (float*)alloc((size_t)E2*4);
  float* DKb  = (float*)alloc((size_t)E2*4);
  unsigned short* Xb  = (unsigned short*)alloc((size_t)NPAD*320*2);
  unsigned short* Xb2 = (unsigned short*)alloc((size_t)NPAD*320*2);
  unsigned short* Bt  = (unsigned short*)alloc((size_t)112*320*2);
  unsigned short* MbT = (unsigned short*)alloc((size_t)112*128*2);
  unsigned short* WtB = (unsigned short*)alloc((size_t)304*128*2);
  unsigned short* Rb  = (unsigned short*)alloc((size_t)1024*128*2);
  int* CNT  = (int*)alloc((size_t)N_NODES*4);
  int* ROFF = (int*)alloc((size_t)N_NODES*4);
  int* CUR  = (int*)alloc((size_t)N_NODES*4);
  int* PART = (int*)alloc(512*4);
  int* EIDX = (int*)alloc((size_t)E2*4);
  int* FRO  = (int*)alloc((size_t)N_NODES*4);
  int* ND2  = (int*)alloc((size_t)N_NODES*4);

  // backward-slice flags (index-only dependency)
  hipMemsetAsync(FRO, 0, (size_t)N_NODES*4, stream);
  hipMemsetAsync(ND2, 0, (size_t)N_NODES*4, stream);
  k_flag<<<dim3((NB+255)/256), dim3(256), 0, stream>>>(roout, FRO);
  k_need<<<dim3((E1+255)/256), dim3(256), 0, stream>>>(par1, chi1, roo1, roout, FRO, ND2);

  // constants
  k_prep2b<<<dim3(56), dim3(256), 0, stream>>>(W, watt, MbT);
  k_prepAll<<<dim3(356), dim3(256), 0, stream>>>(W, watt, relT, Bt, WtB, Rb);
  k_relmm<<<dim3(16), dim3(256), 0, stream>>>(Rb, WtB, watt, Vh, RINV, RVW1, RVW2);

  // ---------- level 2 ----------
  k_cast<<<dim3(2048), dim3(256), 0, stream>>>(node, Xb);
  k_nodetab2<<<dim3((N_NODES+127)/128), dim3(256), 0, stream>>>(Xb, Bt, Gh, P, CNT, CUR);
  k_pass1_l2<<<dim3(E2/64), dim3(256), 0, stream>>>(relT, rel2i, relrp2, par2, chi2, roo2,
                                                    Gh, P, MbT, RINV, RVW2, ND2, BBUF, DKb, CNT);
  k_scan_a<<<dim3(SCAN_BLKS), dim3(256), 0, stream>>>(CNT, ROFF, PART);
  k_scan_b<<<dim3(1), dim3(512), 0, stream>>>(PART);
  k_scatter<<<dim3((E2+255)/256), dim3(256), 0, stream>>>(par2, ROFF, PART, ND2, CUR, EIDX, E2);
  k_agg2<<<dim3((N_NODES+3)/4), dim3(256), 0, stream>>>(ROFF, PART, CNT, EIDX, BBUF, DKb,
                                                        chi2, rel2i, Vh, Xb, ND2, Xb2);

  // ---------- level 1 ----------
  k_nodetab2<<<dim3((N_NODES+127)/128), dim3(256), 0, stream>>>(Xb2, Bt, Gh, P, CNT, CUR);
  k_pass1_l1<<<dim3((E1+3)/4), dim3(256), 0, stream>>>(relT, rel1i, par1, chi1, roo1,
                                                       Gh, P, RINV, RVW1, RVW2, FRO, BBUF, DKb, CNT);
  k_scan_a<<<dim3(SCAN_BLKS), dim3(256), 0, stream>>>(CNT, ROFF, PART);
  k_scan_b<<<dim3(1), dim3(512), 0, stream>>>(PART);
  k_scatter<<<dim3((E1+255)/256), dim3(256), 0, stream>>>(par1, ROFF, PART, FRO, CUR, EIDX, E1);
  k_aggout<<<dim3((NB+3)/4), dim3(256), 0, stream>>>(roout, ROFF, PART, CNT, EIDX, BBUF, DKb,
                                                     chi1, rel1i, Vh, Xb2, (float*)d_out);
}

// Round 9
// 306.001 us; speedup vs baseline: 4.5468x; 1.0710x over previous
//
#include <hip/hip_runtime.h>
#include <hip/hip_bf16.h>
#include <cstdint>

#define N_NODES 100000
#define NPAD 100096
#define D 300
#define RD 100
#define NREL 1000
#define E2 200000
#define E1 100000
#define NB 8192
#define NEG 0.2f
#define SCAN_BLKS 391   // ceil(100000/256)

typedef __bf16 bf16x8 __attribute__((ext_vector_type(8)));
typedef float f32x4 __attribute__((ext_vector_type(4)));
typedef unsigned short us4 __attribute__((ext_vector_type(4)));
typedef unsigned short us8 __attribute__((ext_vector_type(8)));

__device__ __forceinline__ float leaky(float x){ return x >= 0.f ? x : NEG*x; }

__device__ __forceinline__ unsigned short f2b(float v){
  unsigned u = __float_as_uint(v);
  unsigned r = u + 0x7FFF + ((u>>16)&1u);
  return (unsigned short)(r>>16);
}
__device__ __forceinline__ float b2f(unsigned short b){
  return __uint_as_float(((unsigned)b) << 16);
}
__device__ __forceinline__ float wred(float v){
  #pragma unroll
  for (int m = 32; m >= 1; m >>= 1) v += __shfl_xor(v, m, 64);
  return v;
}

// ---- init: zero flags, per-level CNT/CUR, live counters ----
__global__ void k_init(int* __restrict__ FRO, int* __restrict__ ND2,
                       int* __restrict__ CNTa, int* __restrict__ CURa,
                       int* __restrict__ CNTb, int* __restrict__ CURb,
                       int* __restrict__ NLV){
  int i = blockIdx.x*256 + threadIdx.x;
  if (i < N_NODES){ FRO[i]=0; ND2[i]=0; CNTa[i]=0; CURa[i]=0; CNTb[i]=0; CURb[i]=0; }
  if (i < 4) NLV[i] = 0;
}
__global__ void k_flag(const int* __restrict__ ro, int* __restrict__ FRO){
  int o = blockIdx.x*256 + threadIdx.x;
  if (o < NB) FRO[ro[o]] = 1;
}
__global__ void k_need(const int* __restrict__ par1, const int* __restrict__ chi1,
                       const int* __restrict__ roo1, const int* __restrict__ ro,
                       const int* __restrict__ FRO, int* __restrict__ ND2){
  int i = blockIdx.x*256 + threadIdx.x;
  if (i < NB) ND2[ro[i]] = 1;
  if (i < E1){
    int p = par1[i];
    if (FRO[p]){ ND2[p] = 1; ND2[chi1[i]] = 1; ND2[roo1[i]] = 1; }
  }
}
// ---- compact live L2 edges, live L1 edges, needed nodes ----
__global__ void k_compactAll(const int* __restrict__ par2, const int* __restrict__ par1,
                             const int* __restrict__ FRO, const int* __restrict__ ND2,
                             int* __restrict__ L2L, int* __restrict__ L1L, int* __restrict__ NDL,
                             int* __restrict__ NLV){
  int i = blockIdx.x*256 + threadIdx.x;
  if (i < E2 && ND2[par2[i]]) L2L[atomicAdd(&NLV[0],1)] = i;
  if (i < E1 && FRO[par1[i]]) L1L[atomicAdd(&NLV[1],1)] = i;
  if (i < N_NODES && ND2[i])  NDL[atomicAdd(&NLV[2],1)] = i;
}

// ---- MbT[112][128] bf16: rows j<100 -> M[j][i]; row 100 -> W^T w1 ----
__global__ void k_prep2b(const float* __restrict__ W, const float* __restrict__ watt,
                         unsigned short* __restrict__ MbT){
  int u = blockIdx.x*blockDim.x + threadIdx.x;
  if (u >= 112*128) return;
  int j = u >> 7, i = u & 127;
  float v = 0.f;
  if (i < RD){
    if (j < RD){ float a=0.f; for (int d=0;d<D;++d) a += W[d*RD+i]*W[d*RD+j]; v=a; }
    else if (j == RD){ float a=0.f; for (int d=0;d<D;++d) a += watt[d]*W[d*RD+i]; v=a; }
  }
  MbT[u] = f2b(v);
}

// ---- fused prep: Bt[112][320], WtB[304][128], Rb[1024][128] ----
__global__ void k_prepAll(const float* __restrict__ W, const float* __restrict__ watt,
                          const float* __restrict__ relT, unsigned short* __restrict__ Bt,
                          unsigned short* __restrict__ WtB, unsigned short* __restrict__ Rb){
  int b = blockIdx.x;
  if (b < 140){
    int u = b*256 + threadIdx.x;
    if (u < 112*320){
      int c = u / 320, k = u % 320;
      float v = 0.f;
      if (k < D){
        if (c < RD) v = W[k*RD + c];
        else if (c < RD+3) v = watt[(c-RD)*D + k];
      }
      Bt[u] = f2b(v);
    }
  } else if (b < 292){
    int u = (b-140)*256 + threadIdx.x;
    if (u < 304*128){
      int dd = u >> 7, k = u & 127;
      float v = (dd < D && k < RD) ? W[dd*RD + k] : 0.f;
      WtB[u] = f2b(v);
    }
  } else {
    int u = (b-292)*256 + threadIdx.x;
    if (u < 1024*16){
      int row = u >> 4, c8 = (u & 15)*8;
      us8 o;
      #pragma unroll
      for (int j=0;j<8;++j){
        int c = c8+j;
        o[j] = (row < NREL && c < RD) ? f2b(relT[row*RD + c]) : (unsigned short)0;
      }
      *(us8*)(Rb + (size_t)row*128 + c8) = o;
    }
  }
}

// ---- MFMA relation tables: U = Rb @ WtB^T -> Vh (bf16), RINV, RVW1, RVW2 ----
__global__ __launch_bounds__(256) void k_relmm(const unsigned short* __restrict__ Rb,
    const unsigned short* __restrict__ WtB, const float* __restrict__ watt,
    unsigned short* __restrict__ Vh, float* __restrict__ RINV,
    float* __restrict__ RVW1, float* __restrict__ RVW2){
  int lane = threadIdx.x & 63, wid = threadIdx.x >> 6;
  int r0 = blockIdx.x*64 + wid*16;
  int ep = lane & 15, g = lane >> 4;
  size_t a0 = (size_t)(r0 + ep)*128 + g*8;
  size_t b0 = (size_t)ep*128 + g*8;
  f32x4 acc[19];
  #pragma unroll
  for (int cf=0;cf<19;++cf) acc[cf]=(f32x4){0.f,0.f,0.f,0.f};
  #pragma unroll
  for (int ks=0; ks<4; ++ks){
    bf16x8 af = *(const bf16x8*)(Rb + a0 + ks*32);
    #pragma unroll
    for (int cf=0; cf<19; ++cf){
      bf16x8 bf = *(const bf16x8*)(WtB + b0 + (size_t)cf*16*128 + ks*32);
      acc[cf] = __builtin_amdgcn_mfma_f32_16x16x32_bf16(af, bf, acc[cf], 0, 0, 0);
    }
  }
  float w1v[19], w2v[19];
  #pragma unroll
  for (int cf=0; cf<19; ++cf){
    int col = cf*16+ep;
    bool ok = col < D;
    w1v[cf] = ok ? watt[col] : 0.f;
    w2v[cf] = ok ? watt[D+col] : 0.f;
  }
  #pragma unroll
  for (int reg=0; reg<4; ++reg){
    int row = r0 + g*4 + reg;
    float np = 0.f;
    #pragma unroll
    for (int cf=0; cf<19; ++cf){ float u = acc[cf][reg]; np += u*u; }
    np += __shfl_xor(np,1); np += __shfl_xor(np,2); np += __shfl_xor(np,4); np += __shfl_xor(np,8);
    float iv = 1.f / fmaxf(sqrtf(np), 1e-12f);
    float p1 = 0.f, p2 = 0.f;
    if (row < NREL){
      #pragma unroll
      for (int cf=0; cf<19; ++cf){
        int col = cf*16+ep;
        float v = acc[cf][reg]*iv;
        if (col < D){
          Vh[(size_t)row*D + col] = f2b(v);
          p1 += v*w1v[cf];
          p2 += v*w2v[cf];
        }
      }
    }
    p1 += __shfl_xor(p1,1); p1 += __shfl_xor(p1,2); p1 += __shfl_xor(p1,4); p1 += __shfl_xor(p1,8);
    p2 += __shfl_xor(p2,1); p2 += __shfl_xor(p2,2); p2 += __shfl_xor(p2,4); p2 += __shfl_xor(p2,8);
    if (ep == 0 && row < NREL){
      RINV[row] = iv; RVW1[row] = p1; RVW2[row] = p2;
    }
  }
}

// ---- cast node embeddings to padded bf16 table Xb[NPAD][320] ----
__global__ void k_cast(const float* __restrict__ src, unsigned short* __restrict__ dst){
  int total = NPAD*40;
  for (int u = blockIdx.x*blockDim.x + threadIdx.x; u < total; u += gridDim.x*blockDim.x){
    int row = u/40, c8 = (u%40)*8;
    us8 o;
    if (row < N_NODES && c8 <= 292){
      float4 x = *(const float4*)(src + (size_t)row*D + c8);
      float4 y = *(const float4*)(src + (size_t)row*D + c8 + 4);
      o[0]=f2b(x.x); o[1]=f2b(x.y); o[2]=f2b(x.z); o[3]=f2b(x.w);
      o[4]=f2b(y.x); o[5]=f2b(y.y); o[6]=f2b(y.z); o[7]=f2b(y.w);
    } else {
      #pragma unroll
      for (int j=0;j<8;++j){
        int c = c8+j;
        float v = (row < N_NODES && c < D) ? src[(size_t)row*D + c] : 0.f;
        o[j] = f2b(v);
      }
    }
    *(us8*)(dst + (size_t)row*320 + c8) = o;
  }
}

// ---- MFMA node tables (full, level 2): Gh[n] = bf16(W^T e_n), P[n] ----
__global__ __launch_bounds__(256) void k_nodetab2(const unsigned short* __restrict__ Eb,
    const unsigned short* __restrict__ Bt, unsigned short* __restrict__ Gh, float* __restrict__ P){
  int lane = threadIdx.x & 63, wid = threadIdx.x >> 6;
  int n0 = blockIdx.x*128;
  size_t a0 = (size_t)(n0 + wid*32 + (lane&15))*320 + ((lane>>4)*8);
  size_t b0 = (size_t)(lane&15)*320 + ((lane>>4)*8);
  f32x4 acc[2][7];
  #pragma unroll
  for (int s=0;s<2;++s)
    #pragma unroll
    for (int c=0;c<7;++c) acc[s][c] = (f32x4){0.f,0.f,0.f,0.f};
  for (int ks = 0; ks < 10; ++ks){
    bf16x8 a0f = *(const bf16x8*)(Eb + a0 + ks*32);
    bf16x8 a1f = *(const bf16x8*)(Eb + a0 + 16*320 + ks*32);
    #pragma unroll
    for (int cf=0; cf<7; ++cf){
      bf16x8 bf = *(const bf16x8*)(Bt + b0 + (size_t)cf*16*320 + ks*32);
      acc[0][cf] = __builtin_amdgcn_mfma_f32_16x16x32_bf16(a0f, bf, acc[0][cf], 0, 0, 0);
      acc[1][cf] = __builtin_amdgcn_mfma_f32_16x16x32_bf16(a1f, bf, acc[1][cf], 0, 0, 0);
    }
  }
  int rbase = n0 + wid*32 + ((lane>>4)<<2);
  int cbase = lane & 15;
  #pragma unroll
  for (int sub=0; sub<2; ++sub){
    #pragma unroll
    for (int cf=0; cf<7; ++cf){
      int col = cf*16 + cbase;
      #pragma unroll
      for (int r=0; r<4; ++r){
        int row = rbase + sub*16 + r;
        if (row < N_NODES){
          float v = acc[sub][cf][r];
          if (col < RD) Gh[(size_t)row*RD + col] = f2b(v);
          else if (col < RD+3) P[(size_t)row*4 + (col-RD)] = v;
        }
      }
    }
  }
}

// ---- MFMA node tables (indexed, level 1): rows from NDL, count-capped ----
__global__ __launch_bounds__(256) void k_nodetab2i(const unsigned short* __restrict__ Eb,
    const unsigned short* __restrict__ Bt, const int* __restrict__ NDL, const int* __restrict__ NLV,
    unsigned short* __restrict__ Gh, float* __restrict__ P){
  int nlv = NLV[2];
  int base = blockIdx.x*128;
  if (base >= nlv) return;
  int lane = threadIdx.x & 63, wid = threadIdx.x >> 6;
  int li0 = base + wid*32 + (lane&15);
  int li1 = li0 + 16;
  int row0 = (li0 < nlv) ? NDL[li0] : 0;
  int row1 = (li1 < nlv) ? NDL[li1] : 0;
  size_t a0 = (size_t)row0*320 + ((lane>>4)*8);
  size_t a1 = (size_t)row1*320 + ((lane>>4)*8);
  size_t b0 = (size_t)(lane&15)*320 + ((lane>>4)*8);
  f32x4 acc[2][7];
  #pragma unroll
  for (int s=0;s<2;++s)
    #pragma unroll
    for (int c=0;c<7;++c) acc[s][c] = (f32x4){0.f,0.f,0.f,0.f};
  for (int ks = 0; ks < 10; ++ks){
    bf16x8 a0f = *(const bf16x8*)(Eb + a0 + ks*32);
    bf16x8 a1f = *(const bf16x8*)(Eb + a1 + ks*32);
    #pragma unroll
    for (int cf=0; cf<7; ++cf){
      bf16x8 bf = *(const bf16x8*)(Bt + b0 + (size_t)cf*16*320 + ks*32);
      acc[0][cf] = __builtin_amdgcn_mfma_f32_16x16x32_bf16(a0f, bf, acc[0][cf], 0, 0, 0);
      acc[1][cf] = __builtin_amdgcn_mfma_f32_16x16x32_bf16(a1f, bf, acc[1][cf], 0, 0, 0);
    }
  }
  int lbase = base + wid*32 + ((lane>>4)<<2);
  int cbase = lane & 15;
  #pragma unroll
  for (int sub=0; sub<2; ++sub){
    #pragma unroll
    for (int r=0; r<4; ++r){
      int li = lbase + sub*16 + r;
      if (li >= nlv) continue;
      int row = NDL[li];
      #pragma unroll
      for (int cf=0; cf<7; ++cf){
        int col = cf*16 + cbase;
        float v = acc[sub][cf][r];
        if (col < RD) Gh[(size_t)row*RD + col] = f2b(v);
        else if (col < RD+3) P[(size_t)row*4 + (col-RD)] = v;
      }
    }
  }
}

// ---- level-2 pass 1 (MFMA, compacted): logits + DK + parent histogram ----
__global__ __launch_bounds__(256) void k_pass1_l2c(
    const float* __restrict__ relT, const int* __restrict__ rel2i, const int* __restrict__ relrp2,
    const int* __restrict__ par, const int* __restrict__ chi, const int* __restrict__ roo,
    const unsigned short* __restrict__ Gh, const float* __restrict__ P,
    const unsigned short* __restrict__ MbT,
    const float* __restrict__ RINV, const float* __restrict__ RVW2,
    const int* __restrict__ L2L, const int* __restrict__ NLV,
    float* __restrict__ BBUF, float* __restrict__ DK, int* __restrict__ CNT){
  __shared__ unsigned short Cl[4*16*136];
  int nlv = NLV[0];
  if (blockIdx.x*64 >= nlv) return;
  int lane = threadIdx.x & 63, wid = threadIdx.x >> 6;
  int ep = lane & 15, g = lane >> 4;
  unsigned short* cw = Cl + wid*16*136;
  int idx = blockIdx.x*64 + wid*16 + ep;
  int live = idx < nlv;
  int e = live ? L2L[idx] : 0;
  int rp = par[e];
  int ra = rel2i[e], rb = relrp2[e], rc = chi[e], rr = roo[e];
  const float* rA = relT + (size_t)ra*RD;
  const float* rB = relT + (size_t)rb*RD;
  const unsigned short* gR = Gh + (size_t)rr*RD;
  const unsigned short* gX = Gh + (size_t)rp*RD;
  const unsigned short* gY = Gh + (size_t)rc*RD;
  float dgi = 0.f, dgx = 0.f, dgy = 0.f;
  bf16x8 af[4];
  #pragma unroll
  for (int ks=0; ks<4; ++ks){
    us8 cpack;
    #pragma unroll
    for (int h=0; h<2; ++h){
      int k0 = g*8 + ks*32 + h*4;
      float4 a4 = make_float4(0.f,0.f,0.f,0.f), b4 = a4, grr = a4, grp = a4, gry = a4;
      if (live && k0 <= 96){
        a4  = *(const float4*)(rA + k0);
        b4  = *(const float4*)(rB + k0);
        us4 r4 = *(const us4*)(gR + k0);
        us4 x4 = *(const us4*)(gX + k0);
        us4 y4 = *(const us4*)(gY + k0);
        grr = make_float4(b2f(r4[0]),b2f(r4[1]),b2f(r4[2]),b2f(r4[3]));
        grp = make_float4(b2f(x4[0]),b2f(x4[1]),b2f(x4[2]),b2f(x4[3]));
        gry = make_float4(b2f(y4[0]),b2f(y4[1]),b2f(y4[2]),b2f(y4[3]));
      }
      float4 c4;
      c4.x = a4.x*b4.x; c4.y = a4.y*b4.y; c4.z = a4.z*b4.z; c4.w = a4.w*b4.w;
      dgi += c4.x*grr.x + c4.y*grr.y + c4.z*grr.z + c4.w*grr.w;
      dgx += a4.x*grp.x + a4.y*grp.y + a4.z*grp.z + a4.w*grp.w;
      dgy += a4.x*gry.x + a4.y*gry.y + a4.z*gry.z + a4.w*gry.w;
      cpack[h*4+0]=f2b(c4.x); cpack[h*4+1]=f2b(c4.y); cpack[h*4+2]=f2b(c4.z); cpack[h*4+3]=f2b(c4.w);
    }
    *(us8*)((char*)cw + ep*272 + g*16 + ks*64) = cpack;
    af[ks] = *(bf16x8*)&cpack;
  }
  f32x4 acc[7];
  #pragma unroll
  for (int cf=0; cf<7; ++cf) acc[cf] = (f32x4){0.f,0.f,0.f,0.f};
  #pragma unroll
  for (int cf=0; cf<7; ++cf){
    #pragma unroll
    for (int ks=0; ks<4; ++ks){
      bf16x8 bfr = *(const bf16x8*)(MbT + (size_t)(cf*16+ep)*128 + g*8 + ks*32);
      acc[cf] = __builtin_amdgcn_mfma_f32_16x16x32_bf16(af[ks], bfr, acc[cf], 0, 0, 0);
    }
  }
  dgi += __shfl_xor(dgi, 16); dgi += __shfl_xor(dgi, 32);
  dgx += __shfl_xor(dgx, 16); dgx += __shfl_xor(dgx, 32);
  dgy += __shfl_xor(dgy, 16); dgy += __shfl_xor(dgy, 32);
  __syncthreads();
  #pragma unroll
  for (int r=0; r<4; ++r){
    int row = g*4 + r;
    int src = (lane & 48) | row;
    int livr = __shfl(live, src);
    if (!livr) continue;
    float pr = 0.f;
    #pragma unroll
    for (int cf=0; cf<7; ++cf)
      pr += b2f(cw[row*136 + cf*16 + ep]) * acc[cf][r];
    pr += __shfl_xor(pr, 1); pr += __shfl_xor(pr, 2);
    pr += __shfl_xor(pr, 4); pr += __shfl_xor(pr, 8);
    float dw1r = __shfl(acc[6][r], (lane & 48) | 4);   // t[row][100]
    float dgir = __shfl(dgi, src);
    float dgxr = __shfl(dgx, src);
    float dgyr = __shfl(dgy, src);
    int rar = __shfl(ra, src), rpr = __shfl(rp, src);
    int rcr = __shfl(rc, src), rrr = __shfl(rr, src);
    int er  = __shfl(e, src);
    float invp = 1.f / fmaxf(sqrtf(pr), 1e-12f);
    float rinv = RINV[rar];
    float t1 = (dgir*invp)*(dw1r*invp);
    float t2 = (dgxr*rinv)*RVW2[rar];
    float bb = P[(size_t)rrr*4+0] - 2.f*t1 + P[(size_t)rpr*4+1] - 2.f*t2 + P[(size_t)rcr*4+2];
    bb = leaky(bb);
    if (ep == 0){
      BBUF[er] = bb;
      DK[er] = dgyr * rinv;
      atomicAdd(&CNT[rpr], 1);
    }
  }
}

// ---- level-1 pass 1 (compacted): one wave per live edge ----
__global__ __launch_bounds__(256) void k_pass1_l1c(
    const float* __restrict__ relT, const int* __restrict__ rel1i,
    const int* __restrict__ par, const int* __restrict__ chi, const int* __restrict__ roo,
    const unsigned short* __restrict__ Gh, const float* __restrict__ P,
    const float* __restrict__ RINV, const float* __restrict__ RVW1, const float* __restrict__ RVW2,
    const int* __restrict__ L1L, const int* __restrict__ NLV,
    float* __restrict__ BBUF, float* __restrict__ DK, int* __restrict__ CNT){
  int nlv = NLV[1];
  int j = (blockIdx.x*256 + threadIdx.x) >> 6;
  if (j >= nlv) return;
  int lane = threadIdx.x & 63;
  int e = L1L[j];
  int pp = par[e];
  int r = rel1i[e], cc = chi[e], ii = roo[e];
  const float* rrow = relT + r*RD;
  const unsigned short* gI = Gh + (size_t)ii*RD;
  const unsigned short* gX = Gh + (size_t)pp*RD;
  const unsigned short* gY = Gh + (size_t)cc*RD;
  float ai = rrow[lane]*b2f(gI[lane]);
  float ax = rrow[lane]*b2f(gX[lane]);
  float ay = rrow[lane]*b2f(gY[lane]);
  if (lane < 36){
    ai += rrow[lane+64]*b2f(gI[lane+64]);
    ax += rrow[lane+64]*b2f(gX[lane+64]);
    ay += rrow[lane+64]*b2f(gY[lane+64]);
  }
  float dgi = wred(ai), dgx = wred(ax), dgy = wred(ay);
  if (lane == 0){
    float invn = RINV[r];
    float b = P[(size_t)ii*4+0] - 2.f*(dgi*invn)*RVW1[r]
            + P[(size_t)pp*4+1] - 2.f*(dgx*invn)*RVW2[r]
            + P[(size_t)cc*4+2];
    b = leaky(b);
    BBUF[e] = b;
    DK[e] = dgy * invn;
    atomicAdd(&CNT[pp], 1);
  }
}

// ---- CSR build: exclusive scan over CNT ----
__global__ __launch_bounds__(256) void k_scan_a(const int* __restrict__ CNT,
    int* __restrict__ ROFF, int* __restrict__ PART){
  __shared__ int ls[256];
  int i = blockIdx.x*256 + threadIdx.x;
  int v = (i < N_NODES) ? CNT[i] : 0;
  ls[threadIdx.x] = v;
  __syncthreads();
  for (int off=1; off<256; off<<=1){
    int t = (threadIdx.x >= off) ? ls[threadIdx.x-off] : 0;
    __syncthreads();
    ls[threadIdx.x] += t;
    __syncthreads();
  }
  int incl = ls[threadIdx.x];
  if (i < N_NODES) ROFF[i] = incl - v;
  if (threadIdx.x == 255) PART[blockIdx.x] = incl;
}
__global__ __launch_bounds__(512) void k_scan_b(int* __restrict__ PART){
  __shared__ int ls[512];
  int v = (threadIdx.x < SCAN_BLKS) ? PART[threadIdx.x] : 0;
  ls[threadIdx.x] = v;
  __syncthreads();
  for (int off=1; off<512; off<<=1){
    int t = (threadIdx.x >= off) ? ls[threadIdx.x-off] : 0;
    __syncthreads();
    ls[threadIdx.x] += t;
    __syncthreads();
  }
  if (threadIdx.x < SCAN_BLKS) PART[threadIdx.x] = ls[threadIdx.x] - v;
}
// ---- compacted scatter: iterate live-edge list ----
__global__ void k_scatterc(const int* __restrict__ L, const int* __restrict__ NLV, int which,
                           const int* __restrict__ par, const int* __restrict__ ROFF,
                           const int* __restrict__ PART, int* __restrict__ CUR,
                           int* __restrict__ EIDX){
  int j = blockIdx.x*256 + threadIdx.x;
  if (j >= NLV[which]) return;
  int e = L[j];
  int p = par[e];
  int pos = ROFF[p] + PART[p>>8] + atomicAdd(&CUR[p], 1);
  EIDX[pos] = e;
}

// ---- per-parent softmax + Householder aggregate; DK precomputed ----
__device__ __forceinline__ void agg_bucket(int p, int lane,
    const int* __restrict__ ROFF, const int* __restrict__ PART, const int* __restrict__ CNT,
    const int* __restrict__ EIDX, const float* __restrict__ BBUF, const float* __restrict__ DK,
    const int* __restrict__ chi, const int* __restrict__ relI,
    const unsigned short* __restrict__ Vh, const unsigned short* __restrict__ Xe,
    float acc[5]){
  int cnt = CNT[p];
  if (cnt <= 0) return;
  int base = ROFF[p] + PART[p>>8];
  if (cnt <= 64){
    float bl = (lane < cnt) ? BBUF[EIDX[base+lane]] : -1e30f;
    float m = bl;
    #pragma unroll
    for (int msk=32; msk>=1; msk>>=1) m = fmaxf(m, __shfl_xor(m, msk));
    float el = (lane < cnt) ? __expf(bl - m) : 0.f;
    float s = wred(el);
    float inv = 1.f / fmaxf(s, 1e-10f);
    for (int i=0;i<cnt;++i){
      int eid = EIDX[base+i];
      float a = __shfl(el, i) * inv;
      float s2 = 2.f*DK[eid]*a;
      int y = chi[eid], r = relI[eid];
      const unsigned short* vr = Vh + (size_t)r*D;
      const unsigned short* ey = Xe + (size_t)y*320;
      #pragma unroll
      for (int q=0;q<4;++q){
        int d = lane + 64*q;
        acc[q] += b2f(ey[d])*a - s2*b2f(vr[d]);
      }
      if (lane < 44){
        int d = lane + 256;
        acc[4] += b2f(ey[d])*a - s2*b2f(vr[d]);
      }
    }
  } else {
    float m = -1e30f;
    for (int i=0;i<cnt;++i) m = fmaxf(m, BBUF[EIDX[base+i]]);
    float s = 0.f;
    for (int i=0;i<cnt;++i) s += __expf(BBUF[EIDX[base+i]] - m);
    float inv = 1.f / fmaxf(s, 1e-10f);
    for (int i=0;i<cnt;++i){
      int eid = EIDX[base+i];
      float a = __expf(BBUF[eid]-m)*inv;
      float s2 = 2.f*DK[eid]*a;
      int y = chi[eid], r = relI[eid];
      const unsigned short* vr = Vh + (size_t)r*D;
      const unsigned short* ey = Xe + (size_t)y*320;
      #pragma unroll
      for (int q=0;q<4;++q){
        int d = lane + 64*q;
        acc[q] += b2f(ey[d])*a - s2*b2f(vr[d]);
      }
      if (lane < 44){
        int d = lane + 256;
        acc[4] += b2f(ey[d])*a - s2*b2f(vr[d]);
      }
    }
  }
}

// ---- level-2 (compacted): one wave per needed parent from NDL ----
__global__ __launch_bounds__(256) void k_agg2(const int* __restrict__ ROFF, const int* __restrict__ PART,
    const int* __restrict__ CNT, const int* __restrict__ EIDX,
    const float* __restrict__ BBUF, const float* __restrict__ DK,
    const int* __restrict__ chi, const int* __restrict__ relI,
    const unsigned short* __restrict__ Vh, const unsigned short* __restrict__ Xe,
    const int* __restrict__ NDL, const int* __restrict__ NLV,
    unsigned short* __restrict__ Xo){
  int nlv = NLV[2];
  int idx = (blockIdx.x*256 + threadIdx.x) >> 6;
  if (idx >= nlv) return;
  int lane = threadIdx.x & 63;
  int p = NDL[idx];
  float acc[5] = {0.f,0.f,0.f,0.f,0.f};
  agg_bucket(p, lane, ROFF, PART, CNT, EIDX, BBUF, DK, chi, relI, Vh, Xe, acc);
  const unsigned short* in = Xe + (size_t)p*320;
  unsigned short* op = Xo + (size_t)p*320;
  #pragma unroll
  for (int q=0;q<4;++q){
    int d = lane + 64*q;
    op[d] = f2b(leaky(b2f(in[d]) + acc[q]));
  }
  {
    int d = lane + 256;
    unsigned short o = 0;
    if (lane < 44) o = f2b(leaky(b2f(in[d]) + acc[4]));
    op[d] = o;
  }
}

// ---- level-1: one wave per OUTPUT (8192); writes d_out directly ----
__global__ __launch_bounds__(256) void k_aggout(const int* __restrict__ ro,
    const int* __restrict__ ROFF, const int* __restrict__ PART,
    const int* __restrict__ CNT, const int* __restrict__ EIDX,
    const float* __restrict__ BBUF, const float* __restrict__ DK,
    const int* __restrict__ chi, const int* __restrict__ relI,
    const unsigned short* __restrict__ Vh, const unsigned short* __restrict__ Xe,
    float* __restrict__ out){
  int lane = threadIdx.x & 63;
  int o = (blockIdx.x*256 + threadIdx.x) >> 6;
  if (o >= NB) return;
  int p = ro[o];
  float acc[5] = {0.f,0.f,0.f,0.f,0.f};
  agg_bucket(p, lane, ROFF, PART, CNT, EIDX, BBUF, DK, chi, relI, Vh, Xe, acc);
  const unsigned short* in = Xe + (size_t)p*320;
  float* op = out + (size_t)o*D;
  #pragma unroll
  for (int q=0;q<4;++q){
    int d = lane + 64*q;
    op[d] = leaky(b2f(in[d]) + acc[q]);
  }
  if (lane < 44){
    int d = lane + 256;
    op[d] = leaky(b2f(in[d]) + acc[4]);
  }
}

extern "C" void kernel_launch(void* const* d_in, const int* in_sizes, int n_in,
                              void* d_out, int out_size, void* d_ws, size_t ws_size,
                              hipStream_t stream){
  const float* node = (const float*)d_in[0];
  const float* relT = (const float*)d_in[1];
  const float* W    = (const float*)d_in[2];
  const float* watt = (const float*)d_in[3];
  const int* par2 = (const int*)d_in[4];
  const int* chi2 = (const int*)d_in[5];
  const int* roo2 = (const int*)d_in[6];
  const int* rel2i = (const int*)d_in[7];
  const int* relrp2 = (const int*)d_in[8];
  const int* par1 = (const int*)d_in[9];
  const int* chi1 = (const int*)d_in[10];
  const int* roo1 = (const int*)d_in[11];
  const int* rel1i = (const int*)d_in[12];
  const int* roout = (const int*)d_in[13];

  char* w = (char*)d_ws;
  size_t off = 0;
  auto alloc = [&](size_t bytes)->void*{ void* p = w + off; off += (bytes + 255) & ~(size_t)255; return p; };
  unsigned short* Gh = (unsigned short*)alloc((size_t)N_NODES*RD*2);
  float* P    = (float*)alloc((size_t)N_NODES*4*4);
  unsigned short* Vh = (unsigned short*)alloc((size_t)NREL*D*2);
  float* RINV = (float*)alloc(NREL*4);
  float* RVW1 = (float*)alloc(NREL*4);
  float* RVW2 = (float*)alloc(NREL*4);
  float* BBUF = (float*)alloc((size_t)E2*4);
  float* DKb  = (float*)alloc((size_t)E2*4);
  unsigned short* Xb  = (unsigned short*)alloc((size_t)NPAD*320*2);
  unsigned short* Xb2 = (unsigned short*)alloc((size_t)NPAD*320*2);
  unsigned short* Bt  = (unsigned short*)alloc((size_t)112*320*2);
  unsigned short* MbT = (unsigned short*)alloc((size_t)112*128*2);
  unsigned short* WtB = (unsigned short*)alloc((size_t)304*128*2);
  unsigned short* Rb  = (unsigned short*)alloc((size_t)1024*128*2);
  int* CNTa = (int*)alloc((size_t)N_NODES*4);
  int* CURa = (int*)alloc((size_t)N_NODES*4);
  int* CNTb = (int*)alloc((size_t)N_NODES*4);
  int* CURb = (int*)alloc((size_t)N_NODES*4);
  int* ROFF = (int*)alloc((size_t)N_NODES*4);
  int* PART = (int*)alloc(512*4);
  int* EIDX = (int*)alloc((size_t)E2*4);
  int* FRO  = (int*)alloc((size_t)N_NODES*4);
  int* ND2  = (int*)alloc((size_t)N_NODES*4);
  int* L2L  = (int*)alloc((size_t)E2*4);
  int* L1L  = (int*)alloc((size_t)E1*4);
  int* NDL  = (int*)alloc((size_t)N_NODES*4);
  int* NLV  = (int*)alloc(256);

  // backward-slice flags + compaction (index-only dependency)
  k_init<<<dim3(SCAN_BLKS), dim3(256), 0, stream>>>(FRO, ND2, CNTa, CURa, CNTb, CURb, NLV);
  k_flag<<<dim3((NB+255)/256), dim3(256), 0, stream>>>(roout, FRO);
  k_need<<<dim3((E1+255)/256), dim3(256), 0, stream>>>(par1, chi1, roo1, roout, FRO, ND2);
  k_compactAll<<<dim3((E2+255)/256), dim3(256), 0, stream>>>(par2, par1, FRO, ND2, L2L, L1L, NDL, NLV);

  // constants
  k_prep2b<<<dim3(56), dim3(256), 0, stream>>>(W, watt, MbT);
  k_prepAll<<<dim3(356), dim3(256), 0, stream>>>(W, watt, relT, Bt, WtB, Rb);
  k_relmm<<<dim3(16), dim3(256), 0, stream>>>(Rb, WtB, watt, Vh, RINV, RVW1, RVW2);

  // ---------- level 2 ----------
  k_cast<<<dim3(2048), dim3(256), 0, stream>>>(node, Xb);
  k_nodetab2<<<dim3((N_NODES+127)/128), dim3(256), 0, stream>>>(Xb, Bt, Gh, P);
  k_pass1_l2c<<<dim3(E2/64), dim3(256), 0, stream>>>(relT, rel2i, relrp2, par2, chi2, roo2,
                                                     Gh, P, MbT, RINV, RVW2, L2L, NLV, BBUF, DKb, CNTa);
  k_scan_a<<<dim3(SCAN_BLKS), dim3(256), 0, stream>>>(CNTa, ROFF, PART);
  k_scan_b<<<dim3(1), dim3(512), 0, stream>>>(PART);
  k_scatterc<<<dim3((E2+255)/256), dim3(256), 0, stream>>>(L2L, NLV, 0, par2, ROFF, PART, CURa, EIDX);
  k_agg2<<<dim3((N_NODES+3)/4), dim3(256), 0, stream>>>(ROFF, PART, CNTa, EIDX, BBUF, DKb,
                                                        chi2, rel2i, Vh, Xb, NDL, NLV, Xb2);

  // ---------- level 1 ----------
  k_nodetab2i<<<dim3((N_NODES+127)/128), dim3(256), 0, stream>>>(Xb2, Bt, NDL, NLV, Gh, P);
  k_pass1_l1c<<<dim3((E1+3)/4), dim3(256), 0, stream>>>(relT, rel1i, par1, chi1, roo1,
                                                        Gh, P, RINV, RVW1, RVW2, L1L, NLV, BBUF, DKb, CNTb);
  k_scan_a<<<dim3(SCAN_BLKS), dim3(256), 0, stream>>>(CNTb, ROFF, PART);
  k_scan_b<<<dim3(1), dim3(512), 0, stream>>>(PART);
  k_scatterc<<<dim3((E1+255)/256), dim3(256), 0, stream>>>(L1L, NLV, 1, par1, ROFF, PART, CURb, EIDX);
  k_aggout<<<dim3((NB+3)/4), dim3(256), 0, stream>>>(roout, ROFF, PART, CNTb, EIDX, BBUF, DKb,
                                                     chi1, rel1i, Vh, Xb2, (float*)d_out);
}

// Round 10
// 305.588 us; speedup vs baseline: 4.5530x; 1.0014x over previous
//
#include <hip/hip_runtime.h>
#include <hip/hip_bf16.h>
#include <cstdint>

#define N_NODES 100000
#define NPAD 100096
#define D 300
#define RD 100
#define NREL 1000
#define E2 200000
#define E1 100000
#define NB 8192
#define NEG 0.2f
#define SCAN_BLKS 391   // ceil(100000/256)

typedef __bf16 bf16x8 __attribute__((ext_vector_type(8)));
typedef float f32x4 __attribute__((ext_vector_type(4)));
typedef unsigned short us4 __attribute__((ext_vector_type(4)));
typedef unsigned short us8 __attribute__((ext_vector_type(8)));

__device__ __forceinline__ float leaky(float x){ return x >= 0.f ? x : NEG*x; }

__device__ __forceinline__ unsigned short f2b(float v){
  unsigned u = __float_as_uint(v);
  unsigned r = u + 0x7FFF + ((u>>16)&1u);
  return (unsigned short)(r>>16);
}
__device__ __forceinline__ float b2f(unsigned short b){
  return __uint_as_float(((unsigned)b) << 16);
}
__device__ __forceinline__ float wred(float v){
  #pragma unroll
  for (int m = 32; m >= 1; m >>= 1) v += __shfl_xor(v, m, 64);
  return v;
}

// ---- wave-aggregated list append: one atomic per wave (G12) ----
__device__ __forceinline__ int wave_append(int pred, int* counter){
  unsigned long long mask = __ballot(pred);
  int lane = threadIdx.x & 63;
  int total = __popcll(mask);
  int base = 0;
  if (total > 0){
    int leader = __ffsll(mask) - 1;
    if (lane == leader) base = atomicAdd(counter, total);
    base = __shfl(base, leader);
  }
  int prefix = __popcll(mask & ((1ull << lane) - 1ull));
  return base + prefix;
}

// ---- init: zero flags, per-level CNT/CUR, live counters ----
__global__ void k_init(int* __restrict__ FRO, int* __restrict__ ND2,
                       int* __restrict__ CNTa, int* __restrict__ CURa,
                       int* __restrict__ CNTb, int* __restrict__ CURb,
                       int* __restrict__ NLV){
  int i = blockIdx.x*256 + threadIdx.x;
  if (i < N_NODES){ FRO[i]=0; ND2[i]=0; CNTa[i]=0; CURa[i]=0; CNTb[i]=0; CURb[i]=0; }
  if (i < 4) NLV[i] = 0;
}
__global__ void k_flag(const int* __restrict__ ro, int* __restrict__ FRO){
  int o = blockIdx.x*256 + threadIdx.x;
  if (o < NB) FRO[ro[o]] = 1;
}
__global__ void k_need(const int* __restrict__ par1, const int* __restrict__ chi1,
                       const int* __restrict__ roo1, const int* __restrict__ ro,
                       const int* __restrict__ FRO, int* __restrict__ ND2){
  int i = blockIdx.x*256 + threadIdx.x;
  if (i < NB) ND2[ro[i]] = 1;
  if (i < E1){
    int p = par1[i];
    if (FRO[p]){ ND2[p] = 1; ND2[chi1[i]] = 1; ND2[roo1[i]] = 1; }
  }
}
// ---- compact live L2 edges, live L1 edges, needed nodes (wave-aggregated) ----
__global__ void k_compactAll(const int* __restrict__ par2, const int* __restrict__ par1,
                             const int* __restrict__ FRO, const int* __restrict__ ND2,
                             int* __restrict__ L2L, int* __restrict__ L1L, int* __restrict__ NDL,
                             int* __restrict__ NLV){
  int i = blockIdx.x*256 + threadIdx.x;
  int p2 = (i < E2) && ND2[par2[i]];
  int pos = wave_append(p2, &NLV[0]);
  if (p2) L2L[pos] = i;
  int p1 = (i < E1) && FRO[par1[i]];
  pos = wave_append(p1, &NLV[1]);
  if (p1) L1L[pos] = i;
  int pn = (i < N_NODES) && ND2[i];
  pos = wave_append(pn, &NLV[2]);
  if (pn) NDL[pos] = i;
}

// ---- MbT[112][128] bf16: rows j<100 -> M[j][i]; row 100 -> W^T w1 ----
__global__ void k_prep2b(const float* __restrict__ W, const float* __restrict__ watt,
                         unsigned short* __restrict__ MbT){
  int u = blockIdx.x*blockDim.x + threadIdx.x;
  if (u >= 112*128) return;
  int j = u >> 7, i = u & 127;
  float v = 0.f;
  if (i < RD){
    if (j < RD){ float a=0.f; for (int d=0;d<D;++d) a += W[d*RD+i]*W[d*RD+j]; v=a; }
    else if (j == RD){ float a=0.f; for (int d=0;d<D;++d) a += watt[d]*W[d*RD+i]; v=a; }
  }
  MbT[u] = f2b(v);
}

// ---- fused prep: Bt[112][320], WtB[304][128], Rb[1024][128] ----
__global__ void k_prepAll(const float* __restrict__ W, const float* __restrict__ watt,
                          const float* __restrict__ relT, unsigned short* __restrict__ Bt,
                          unsigned short* __restrict__ WtB, unsigned short* __restrict__ Rb){
  int b = blockIdx.x;
  if (b < 140){
    int u = b*256 + threadIdx.x;
    if (u < 112*320){
      int c = u / 320, k = u % 320;
      float v = 0.f;
      if (k < D){
        if (c < RD) v = W[k*RD + c];
        else if (c < RD+3) v = watt[(c-RD)*D + k];
      }
      Bt[u] = f2b(v);
    }
  } else if (b < 292){
    int u = (b-140)*256 + threadIdx.x;
    if (u < 304*128){
      int dd = u >> 7, k = u & 127;
      float v = (dd < D && k < RD) ? W[dd*RD + k] : 0.f;
      WtB[u] = f2b(v);
    }
  } else {
    int u = (b-292)*256 + threadIdx.x;
    if (u < 1024*16){
      int row = u >> 4, c8 = (u & 15)*8;
      us8 o;
      #pragma unroll
      for (int j=0;j<8;++j){
        int c = c8+j;
        o[j] = (row < NREL && c < RD) ? f2b(relT[row*RD + c]) : (unsigned short)0;
      }
      *(us8*)(Rb + (size_t)row*128 + c8) = o;
    }
  }
}

// ---- MFMA relation tables: U = Rb @ WtB^T -> Vh (bf16), RINV, RVW1, RVW2 ----
__global__ __launch_bounds__(256) void k_relmm(const unsigned short* __restrict__ Rb,
    const unsigned short* __restrict__ WtB, const float* __restrict__ watt,
    unsigned short* __restrict__ Vh, float* __restrict__ RINV,
    float* __restrict__ RVW1, float* __restrict__ RVW2){
  int lane = threadIdx.x & 63, wid = threadIdx.x >> 6;
  int r0 = blockIdx.x*64 + wid*16;
  int ep = lane & 15, g = lane >> 4;
  size_t a0 = (size_t)(r0 + ep)*128 + g*8;
  size_t b0 = (size_t)ep*128 + g*8;
  f32x4 acc[19];
  #pragma unroll
  for (int cf=0;cf<19;++cf) acc[cf]=(f32x4){0.f,0.f,0.f,0.f};
  #pragma unroll
  for (int ks=0; ks<4; ++ks){
    bf16x8 af = *(const bf16x8*)(Rb + a0 + ks*32);
    #pragma unroll
    for (int cf=0; cf<19; ++cf){
      bf16x8 bf = *(const bf16x8*)(WtB + b0 + (size_t)cf*16*128 + ks*32);
      acc[cf] = __builtin_amdgcn_mfma_f32_16x16x32_bf16(af, bf, acc[cf], 0, 0, 0);
    }
  }
  float w1v[19], w2v[19];
  #pragma unroll
  for (int cf=0; cf<19; ++cf){
    int col = cf*16+ep;
    bool ok = col < D;
    w1v[cf] = ok ? watt[col] : 0.f;
    w2v[cf] = ok ? watt[D+col] : 0.f;
  }
  #pragma unroll
  for (int reg=0; reg<4; ++reg){
    int row = r0 + g*4 + reg;
    float np = 0.f;
    #pragma unroll
    for (int cf=0; cf<19; ++cf){ float u = acc[cf][reg]; np += u*u; }
    np += __shfl_xor(np,1); np += __shfl_xor(np,2); np += __shfl_xor(np,4); np += __shfl_xor(np,8);
    float iv = 1.f / fmaxf(sqrtf(np), 1e-12f);
    float p1 = 0.f, p2 = 0.f;
    if (row < NREL){
      #pragma unroll
      for (int cf=0; cf<19; ++cf){
        int col = cf*16+ep;
        float v = acc[cf][reg]*iv;
        if (col < D){
          Vh[(size_t)row*D + col] = f2b(v);
          p1 += v*w1v[cf];
          p2 += v*w2v[cf];
        }
      }
    }
    p1 += __shfl_xor(p1,1); p1 += __shfl_xor(p1,2); p1 += __shfl_xor(p1,4); p1 += __shfl_xor(p1,8);
    p2 += __shfl_xor(p2,1); p2 += __shfl_xor(p2,2); p2 += __shfl_xor(p2,4); p2 += __shfl_xor(p2,8);
    if (ep == 0 && row < NREL){
      RINV[row] = iv; RVW1[row] = p1; RVW2[row] = p2;
    }
  }
}

// ---- cast node embeddings to padded bf16 table Xb[NPAD][320] ----
__global__ void k_cast(const float* __restrict__ src, unsigned short* __restrict__ dst){
  int total = NPAD*40;
  for (int u = blockIdx.x*blockDim.x + threadIdx.x; u < total; u += gridDim.x*blockDim.x){
    int row = u/40, c8 = (u%40)*8;
    us8 o;
    if (row < N_NODES && c8 <= 292){
      float4 x = *(const float4*)(src + (size_t)row*D + c8);
      float4 y = *(const float4*)(src + (size_t)row*D + c8 + 4);
      o[0]=f2b(x.x); o[1]=f2b(x.y); o[2]=f2b(x.z); o[3]=f2b(x.w);
      o[4]=f2b(y.x); o[5]=f2b(y.y); o[6]=f2b(y.z); o[7]=f2b(y.w);
    } else {
      #pragma unroll
      for (int j=0;j<8;++j){
        int c = c8+j;
        float v = (row < N_NODES && c < D) ? src[(size_t)row*D + c] : 0.f;
        o[j] = f2b(v);
      }
    }
    *(us8*)(dst + (size_t)row*320 + c8) = o;
  }
}

// ---- MFMA node tables (full, level 2): Gh[n] = bf16(W^T e_n), P[n] ----
__global__ __launch_bounds__(256) void k_nodetab2(const unsigned short* __restrict__ Eb,
    const unsigned short* __restrict__ Bt, unsigned short* __restrict__ Gh, float* __restrict__ P){
  int lane = threadIdx.x & 63, wid = threadIdx.x >> 6;
  int n0 = blockIdx.x*128;
  size_t a0 = (size_t)(n0 + wid*32 + (lane&15))*320 + ((lane>>4)*8);
  size_t b0 = (size_t)(lane&15)*320 + ((lane>>4)*8);
  f32x4 acc[2][7];
  #pragma unroll
  for (int s=0;s<2;++s)
    #pragma unroll
    for (int c=0;c<7;++c) acc[s][c] = (f32x4){0.f,0.f,0.f,0.f};
  for (int ks = 0; ks < 10; ++ks){
    bf16x8 a0f = *(const bf16x8*)(Eb + a0 + ks*32);
    bf16x8 a1f = *(const bf16x8*)(Eb + a0 + 16*320 + ks*32);
    #pragma unroll
    for (int cf=0; cf<7; ++cf){
      bf16x8 bf = *(const bf16x8*)(Bt + b0 + (size_t)cf*16*320 + ks*32);
      acc[0][cf] = __builtin_amdgcn_mfma_f32_16x16x32_bf16(a0f, bf, acc[0][cf], 0, 0, 0);
      acc[1][cf] = __builtin_amdgcn_mfma_f32_16x16x32_bf16(a1f, bf, acc[1][cf], 0, 0, 0);
    }
  }
  int rbase = n0 + wid*32 + ((lane>>4)<<2);
  int cbase = lane & 15;
  #pragma unroll
  for (int sub=0; sub<2; ++sub){
    #pragma unroll
    for (int cf=0; cf<7; ++cf){
      int col = cf*16 + cbase;
      #pragma unroll
      for (int r=0; r<4; ++r){
        int row = rbase + sub*16 + r;
        if (row < N_NODES){
          float v = acc[sub][cf][r];
          if (col < RD) Gh[(size_t)row*RD + col] = f2b(v);
          else if (col < RD+3) P[(size_t)row*4 + (col-RD)] = v;
        }
      }
    }
  }
}

// ---- MFMA node tables (indexed, level 1): rows from NDL, count-capped ----
__global__ __launch_bounds__(256) void k_nodetab2i(const unsigned short* __restrict__ Eb,
    const unsigned short* __restrict__ Bt, const int* __restrict__ NDL, const int* __restrict__ NLV,
    unsigned short* __restrict__ Gh, float* __restrict__ P){
  int nlv = NLV[2];
  int base = blockIdx.x*128;
  if (base >= nlv) return;
  int lane = threadIdx.x & 63, wid = threadIdx.x >> 6;
  int li0 = base + wid*32 + (lane&15);
  int li1 = li0 + 16;
  int row0 = (li0 < nlv) ? NDL[li0] : 0;
  int row1 = (li1 < nlv) ? NDL[li1] : 0;
  size_t a0 = (size_t)row0*320 + ((lane>>4)*8);
  size_t a1 = (size_t)row1*320 + ((lane>>4)*8);
  size_t b0 = (size_t)(lane&15)*320 + ((lane>>4)*8);
  f32x4 acc[2][7];
  #pragma unroll
  for (int s=0;s<2;++s)
    #pragma unroll
    for (int c=0;c<7;++c) acc[s][c] = (f32x4){0.f,0.f,0.f,0.f};
  for (int ks = 0; ks < 10; ++ks){
    bf16x8 a0f = *(const bf16x8*)(Eb + a0 + ks*32);
    bf16x8 a1f = *(const bf16x8*)(Eb + a1 + ks*32);
    #pragma unroll
    for (int cf=0; cf<7; ++cf){
      bf16x8 bf = *(const bf16x8*)(Bt + b0 + (size_t)cf*16*320 + ks*32);
      acc[0][cf] = __builtin_amdgcn_mfma_f32_16x16x32_bf16(a0f, bf, acc[0][cf], 0, 0, 0);
      acc[1][cf] = __builtin_amdgcn_mfma_f32_16x16x32_bf16(a1f, bf, acc[1][cf], 0, 0, 0);
    }
  }
  int lbase = base + wid*32 + ((lane>>4)<<2);
  int cbase = lane & 15;
  #pragma unroll
  for (int sub=0; sub<2; ++sub){
    #pragma unroll
    for (int r=0; r<4; ++r){
      int li = lbase + sub*16 + r;
      if (li >= nlv) continue;
      int row = NDL[li];
      #pragma unroll
      for (int cf=0; cf<7; ++cf){
        int col = cf*16 + cbase;
        float v = acc[sub][cf][r];
        if (col < RD) Gh[(size_t)row*RD + col] = f2b(v);
        else if (col < RD+3) P[(size_t)row*4 + (col-RD)] = v;
      }
    }
  }
}

// ---- level-2 pass 1 (MFMA, compacted): logits + DK + parent histogram ----
__global__ __launch_bounds__(256) void k_pass1_l2c(
    const float* __restrict__ relT, const int* __restrict__ rel2i, const int* __restrict__ relrp2,
    const int* __restrict__ par, const int* __restrict__ chi, const int* __restrict__ roo,
    const unsigned short* __restrict__ Gh, const float* __restrict__ P,
    const unsigned short* __restrict__ MbT,
    const float* __restrict__ RINV, const float* __restrict__ RVW2,
    const int* __restrict__ L2L, const int* __restrict__ NLV,
    float* __restrict__ BBUF, float* __restrict__ DK, int* __restrict__ CNT){
  __shared__ unsigned short Cl[4*16*136];
  int nlv = NLV[0];
  if (blockIdx.x*64 >= nlv) return;
  int lane = threadIdx.x & 63, wid = threadIdx.x >> 6;
  int ep = lane & 15, g = lane >> 4;
  unsigned short* cw = Cl + wid*16*136;
  int idx = blockIdx.x*64 + wid*16 + ep;
  int live = idx < nlv;
  int e = live ? L2L[idx] : 0;
  int rp = par[e];
  int ra = rel2i[e], rb = relrp2[e], rc = chi[e], rr = roo[e];
  const float* rA = relT + (size_t)ra*RD;
  const float* rB = relT + (size_t)rb*RD;
  const unsigned short* gR = Gh + (size_t)rr*RD;
  const unsigned short* gX = Gh + (size_t)rp*RD;
  const unsigned short* gY = Gh + (size_t)rc*RD;
  float dgi = 0.f, dgx = 0.f, dgy = 0.f;
  bf16x8 af[4];
  #pragma unroll
  for (int ks=0; ks<4; ++ks){
    us8 cpack;
    #pragma unroll
    for (int h=0; h<2; ++h){
      int k0 = g*8 + ks*32 + h*4;
      float4 a4 = make_float4(0.f,0.f,0.f,0.f), b4 = a4, grr = a4, grp = a4, gry = a4;
      if (live && k0 <= 96){
        a4  = *(const float4*)(rA + k0);
        b4  = *(const float4*)(rB + k0);
        us4 r4 = *(const us4*)(gR + k0);
        us4 x4 = *(const us4*)(gX + k0);
        us4 y4 = *(const us4*)(gY + k0);
        grr = make_float4(b2f(r4[0]),b2f(r4[1]),b2f(r4[2]),b2f(r4[3]));
        grp = make_float4(b2f(x4[0]),b2f(x4[1]),b2f(x4[2]),b2f(x4[3]));
        gry = make_float4(b2f(y4[0]),b2f(y4[1]),b2f(y4[2]),b2f(y4[3]));
      }
      float4 c4;
      c4.x = a4.x*b4.x; c4.y = a4.y*b4.y; c4.z = a4.z*b4.z; c4.w = a4.w*b4.w;
      dgi += c4.x*grr.x + c4.y*grr.y + c4.z*grr.z + c4.w*grr.w;
      dgx += a4.x*grp.x + a4.y*grp.y + a4.z*grp.z + a4.w*grp.w;
      dgy += a4.x*gry.x + a4.y*gry.y + a4.z*gry.z + a4.w*gry.w;
      cpack[h*4+0]=f2b(c4.x); cpack[h*4+1]=f2b(c4.y); cpack[h*4+2]=f2b(c4.z); cpack[h*4+3]=f2b(c4.w);
    }
    *(us8*)((char*)cw + ep*272 + g*16 + ks*64) = cpack;
    af[ks] = *(bf16x8*)&cpack;
  }
  f32x4 acc[7];
  #pragma unroll
  for (int cf=0; cf<7; ++cf) acc[cf] = (f32x4){0.f,0.f,0.f,0.f};
  #pragma unroll
  for (int cf=0; cf<7; ++cf){
    #pragma unroll
    for (int ks=0; ks<4; ++ks){
      bf16x8 bfr = *(const bf16x8*)(MbT + (size_t)(cf*16+ep)*128 + g*8 + ks*32);
      acc[cf] = __builtin_amdgcn_mfma_f32_16x16x32_bf16(af[ks], bfr, acc[cf], 0, 0, 0);
    }
  }
  dgi += __shfl_xor(dgi, 16); dgi += __shfl_xor(dgi, 32);
  dgx += __shfl_xor(dgx, 16); dgx += __shfl_xor(dgx, 32);
  dgy += __shfl_xor(dgy, 16); dgy += __shfl_xor(dgy, 32);
  __syncthreads();
  #pragma unroll
  for (int r=0; r<4; ++r){
    int row = g*4 + r;
    int src = (lane & 48) | row;
    int livr = __shfl(live, src);
    if (!livr) continue;
    float pr = 0.f;
    #pragma unroll
    for (int cf=0; cf<7; ++cf)
      pr += b2f(cw[row*136 + cf*16 + ep]) * acc[cf][r];
    pr += __shfl_xor(pr, 1); pr += __shfl_xor(pr, 2);
    pr += __shfl_xor(pr, 4); pr += __shfl_xor(pr, 8);
    float dw1r = __shfl(acc[6][r], (lane & 48) | 4);   // t[row][100]
    float dgir = __shfl(dgi, src);
    float dgxr = __shfl(dgx, src);
    float dgyr = __shfl(dgy, src);
    int rar = __shfl(ra, src), rpr = __shfl(rp, src);
    int rcr = __shfl(rc, src), rrr = __shfl(rr, src);
    int er  = __shfl(e, src);
    float invp = 1.f / fmaxf(sqrtf(pr), 1e-12f);
    float rinv = RINV[rar];
    float t1 = (dgir*invp)*(dw1r*invp);
    float t2 = (dgxr*rinv)*RVW2[rar];
    float bb = P[(size_t)rrr*4+0] - 2.f*t1 + P[(size_t)rpr*4+1] - 2.f*t2 + P[(size_t)rcr*4+2];
    bb = leaky(bb);
    if (ep == 0){
      BBUF[er] = bb;
      DK[er] = dgyr * rinv;
      atomicAdd(&CNT[rpr], 1);
    }
  }
}

// ---- level-1 pass 1 (compacted): one wave per live edge ----
__global__ __launch_bounds__(256) void k_pass1_l1c(
    const float* __restrict__ relT, const int* __restrict__ rel1i,
    const int* __restrict__ par, const int* __restrict__ chi, const int* __restrict__ roo,
    const unsigned short* __restrict__ Gh, const float* __restrict__ P,
    const float* __restrict__ RINV, const float* __restrict__ RVW1, const float* __restrict__ RVW2,
    const int* __restrict__ L1L, const int* __restrict__ NLV,
    float* __restrict__ BBUF, float* __restrict__ DK, int* __restrict__ CNT){
  int nlv = NLV[1];
  int j = (blockIdx.x*256 + threadIdx.x) >> 6;
  if (j >= nlv) return;
  int lane = threadIdx.x & 63;
  int e = L1L[j];
  int pp = par[e];
  int r = rel1i[e], cc = chi[e], ii = roo[e];
  const float* rrow = relT + r*RD;
  const unsigned short* gI = Gh + (size_t)ii*RD;
  const unsigned short* gX = Gh + (size_t)pp*RD;
  const unsigned short* gY = Gh + (size_t)cc*RD;
  float ai = rrow[lane]*b2f(gI[lane]);
  float ax = rrow[lane]*b2f(gX[lane]);
  float ay = rrow[lane]*b2f(gY[lane]);
  if (lane < 36){
    ai += rrow[lane+64]*b2f(gI[lane+64]);
    ax += rrow[lane+64]*b2f(gX[lane+64]);
    ay += rrow[lane+64]*b2f(gY[lane+64]);
  }
  float dgi = wred(ai), dgx = wred(ax), dgy = wred(ay);
  if (lane == 0){
    float invn = RINV[r];
    float b = P[(size_t)ii*4+0] - 2.f*(dgi*invn)*RVW1[r]
            + P[(size_t)pp*4+1] - 2.f*(dgx*invn)*RVW2[r]
            + P[(size_t)cc*4+2];
    b = leaky(b);
    BBUF[e] = b;
    DK[e] = dgy * invn;
    atomicAdd(&CNT[pp], 1);
  }
}

// ---- CSR build: exclusive scan over CNT ----
__global__ __launch_bounds__(256) void k_scan_a(const int* __restrict__ CNT,
    int* __restrict__ ROFF, int* __restrict__ PART){
  __shared__ int ls[256];
  int i = blockIdx.x*256 + threadIdx.x;
  int v = (i < N_NODES) ? CNT[i] : 0;
  ls[threadIdx.x] = v;
  __syncthreads();
  for (int off=1; off<256; off<<=1){
    int t = (threadIdx.x >= off) ? ls[threadIdx.x-off] : 0;
    __syncthreads();
    ls[threadIdx.x] += t;
    __syncthreads();
  }
  int incl = ls[threadIdx.x];
  if (i < N_NODES) ROFF[i] = incl - v;
  if (threadIdx.x == 255) PART[blockIdx.x] = incl;
}
__global__ __launch_bounds__(512) void k_scan_b(int* __restrict__ PART){
  __shared__ int ls[512];
  int v = (threadIdx.x < SCAN_BLKS) ? PART[threadIdx.x] : 0;
  ls[threadIdx.x] = v;
  __syncthreads();
  for (int off=1; off<512; off<<=1){
    int t = (threadIdx.x >= off) ? ls[threadIdx.x-off] : 0;
    __syncthreads();
    ls[threadIdx.x] += t;
    __syncthreads();
  }
  if (threadIdx.x < SCAN_BLKS) PART[threadIdx.x] = ls[threadIdx.x] - v;
}
// ---- compacted scatter: iterate live-edge list ----
__global__ void k_scatterc(const int* __restrict__ L, const int* __restrict__ NLV, int which,
                           const int* __restrict__ par, const int* __restrict__ ROFF,
                           const int* __restrict__ PART, int* __restrict__ CUR,
                           int* __restrict__ EIDX){
  int j = blockIdx.x*256 + threadIdx.x;
  if (j >= NLV[which]) return;
  int e = L[j];
  int p = par[e];
  int pos = ROFF[p] + PART[p>>8] + atomicAdd(&CUR[p], 1);
  EIDX[pos] = e;
}

// ---- per-parent softmax + Householder aggregate; DK precomputed ----
__device__ __forceinline__ void agg_bucket(int p, int lane,
    const int* __restrict__ ROFF, const int* __restrict__ PART, const int* __restrict__ CNT,
    const int* __restrict__ EIDX, const float* __restrict__ BBUF, const float* __restrict__ DK,
    const int* __restrict__ chi, const int* __restrict__ relI,
    const unsigned short* __restrict__ Vh, const unsigned short* __restrict__ Xe,
    float acc[5]){
  int cnt = CNT[p];
  if (cnt <= 0) return;
  int base = ROFF[p] + PART[p>>8];
  if (cnt <= 64){
    float bl = (lane < cnt) ? BBUF[EIDX[base+lane]] : -1e30f;
    float m = bl;
    #pragma unroll
    for (int msk=32; msk>=1; msk>>=1) m = fmaxf(m, __shfl_xor(m, msk));
    float el = (lane < cnt) ? __expf(bl - m) : 0.f;
    float s = wred(el);
    float inv = 1.f / fmaxf(s, 1e-10f);
    for (int i=0;i<cnt;++i){
      int eid = EIDX[base+i];
      float a = __shfl(el, i) * inv;
      float s2 = 2.f*DK[eid]*a;
      int y = chi[eid], r = relI[eid];
      const unsigned short* vr = Vh + (size_t)r*D;
      const unsigned short* ey = Xe + (size_t)y*320;
      #pragma unroll
      for (int q=0;q<4;++q){
        int d = lane + 64*q;
        acc[q] += b2f(ey[d])*a - s2*b2f(vr[d]);
      }
      if (lane < 44){
        int d = lane + 256;
        acc[4] += b2f(ey[d])*a - s2*b2f(vr[d]);
      }
    }
  } else {
    float m = -1e30f;
    for (int i=0;i<cnt;++i) m = fmaxf(m, BBUF[EIDX[base+i]]);
    float s = 0.f;
    for (int i=0;i<cnt;++i) s += __expf(BBUF[EIDX[base+i]] - m);
    float inv = 1.f / fmaxf(s, 1e-10f);
    for (int i=0;i<cnt;++i){
      int eid = EIDX[base+i];
      float a = __expf(BBUF[eid]-m)*inv;
      float s2 = 2.f*DK[eid]*a;
      int y = chi[eid], r = relI[eid];
      const unsigned short* vr = Vh + (size_t)r*D;
      const unsigned short* ey = Xe + (size_t)y*320;
      #pragma unroll
      for (int q=0;q<4;++q){
        int d = lane + 64*q;
        acc[q] += b2f(ey[d])*a - s2*b2f(vr[d]);
      }
      if (lane < 44){
        int d = lane + 256;
        acc[4] += b2f(ey[d])*a - s2*b2f(vr[d]);
      }
    }
  }
}

// ---- level-2 (compacted): one wave per needed parent from NDL ----
__global__ __launch_bounds__(256) void k_agg2(const int* __restrict__ ROFF, const int* __restrict__ PART,
    const int* __restrict__ CNT, const int* __restrict__ EIDX,
    const float* __restrict__ BBUF, const float* __restrict__ DK,
    const int* __restrict__ chi, const int* __restrict__ relI,
    const unsigned short* __restrict__ Vh, const unsigned short* __restrict__ Xe,
    const int* __restrict__ NDL, const int* __restrict__ NLV,
    unsigned short* __restrict__ Xo){
  int nlv = NLV[2];
  int idx = (blockIdx.x*256 + threadIdx.x) >> 6;
  if (idx >= nlv) return;
  int lane = threadIdx.x & 63;
  int p = NDL[idx];
  float acc[5] = {0.f,0.f,0.f,0.f,0.f};
  agg_bucket(p, lane, ROFF, PART, CNT, EIDX, BBUF, DK, chi, relI, Vh, Xe, acc);
  const unsigned short* in = Xe + (size_t)p*320;
  unsigned short* op = Xo + (size_t)p*320;
  #pragma unroll
  for (int q=0;q<4;++q){
    int d = lane + 64*q;
    op[d] = f2b(leaky(b2f(in[d]) + acc[q]));
  }
  {
    int d = lane + 256;
    unsigned short o = 0;
    if (lane < 44) o = f2b(leaky(b2f(in[d]) + acc[4]));
    op[d] = o;
  }
}

// ---- level-1: one wave per OUTPUT (8192); writes d_out directly ----
__global__ __launch_bounds__(256) void k_aggout(const int* __restrict__ ro,
    const int* __restrict__ ROFF, const int* __restrict__ PART,
    const int* __restrict__ CNT, const int* __restrict__ EIDX,
    const float* __restrict__ BBUF, const float* __restrict__ DK,
    const int* __restrict__ chi, const int* __restrict__ relI,
    const unsigned short* __restrict__ Vh, const unsigned short* __restrict__ Xe,
    float* __restrict__ out){
  int lane = threadIdx.x & 63;
  int o = (blockIdx.x*256 + threadIdx.x) >> 6;
  if (o >= NB) return;
  int p = ro[o];
  float acc[5] = {0.f,0.f,0.f,0.f,0.f};
  agg_bucket(p, lane, ROFF, PART, CNT, EIDX, BBUF, DK, chi, relI, Vh, Xe, acc);
  const unsigned short* in = Xe + (size_t)p*320;
  float* op = out + (size_t)o*D;
  #pragma unroll
  for (int q=0;q<4;++q){
    int d = lane + 64*q;
    op[d] = leaky(b2f(in[d]) + acc[q]);
  }
  if (lane < 44){
    int d = lane + 256;
    op[d] = leaky(b2f(in[d]) + acc[4]);
  }
}

extern "C" void kernel_launch(void* const* d_in, const int* in_sizes, int n_in,
                              void* d_out, int out_size, void* d_ws, size_t ws_size,
                              hipStream_t stream){
  const float* node = (const float*)d_in[0];
  const float* relT = (const float*)d_in[1];
  const float* W    = (const float*)d_in[2];
  const float* watt = (const float*)d_in[3];
  const int* par2 = (const int*)d_in[4];
  const int* chi2 = (const int*)d_in[5];
  const int* roo2 = (const int*)d_in[6];
  const int* rel2i = (const int*)d_in[7];
  const int* relrp2 = (const int*)d_in[8];
  const int* par1 = (const int*)d_in[9];
  const int* chi1 = (const int*)d_in[10];
  const int* roo1 = (const int*)d_in[11];
  const int* rel1i = (const int*)d_in[12];
  const int* roout = (const int*)d_in[13];

  char* w = (char*)d_ws;
  size_t off = 0;
  auto alloc = [&](size_t bytes)->void*{ void* p = w + off; off += (bytes + 255) & ~(size_t)255; return p; };
  unsigned short* Gh = (unsigned short*)alloc((size_t)N_NODES*RD*2);
  float* P    = (float*)alloc((size_t)N_NODES*4*4);
  unsigned short* Vh = (unsigned short*)alloc((size_t)NREL*D*2);
  float* RINV = (float*)alloc(NREL*4);
  float* RVW1 = (float*)alloc(NREL*4);
  float* RVW2 = (float*)alloc(NREL*4);
  float* BBUF = (float*)alloc((size_t)E2*4);
  float* DKb  = (float*)alloc((size_t)E2*4);
  unsigned short* Xb  = (unsigned short*)alloc((size_t)NPAD*320*2);
  unsigned short* Xb2 = (unsigned short*)alloc((size_t)NPAD*320*2);
  unsigned short* Bt  = (unsigned short*)alloc((size_t)112*320*2);
  unsigned short* MbT = (unsigned short*)alloc((size_t)112*128*2);
  unsigned short* WtB = (unsigned short*)alloc((size_t)304*128*2);
  unsigned short* Rb  = (unsigned short*)alloc((size_t)1024*128*2);
  int* CNTa = (int*)alloc((size_t)N_NODES*4);
  int* CURa = (int*)alloc((size_t)N_NODES*4);
  int* CNTb = (int*)alloc((size_t)N_NODES*4);
  int* CURb = (int*)alloc((size_t)N_NODES*4);
  int* ROFF = (int*)alloc((size_t)N_NODES*4);
  int* PART = (int*)alloc(512*4);
  int* EIDX = (int*)alloc((size_t)E2*4);
  int* FRO  = (int*)alloc((size_t)N_NODES*4);
  int* ND2  = (int*)alloc((size_t)N_NODES*4);
  int* L2L  = (int*)alloc((size_t)E2*4);
  int* L1L  = (int*)alloc((size_t)E1*4);
  int* NDL  = (int*)alloc((size_t)N_NODES*4);
  int* NLV  = (int*)alloc(256);

  // backward-slice flags + compaction (index-only dependency)
  k_init<<<dim3(SCAN_BLKS), dim3(256), 0, stream>>>(FRO, ND2, CNTa, CURa, CNTb, CURb, NLV);
  k_flag<<<dim3((NB+255)/256), dim3(256), 0, stream>>>(roout, FRO);
  k_need<<<dim3((E1+255)/256), dim3(256), 0, stream>>>(par1, chi1, roo1, roout, FRO, ND2);
  k_compactAll<<<dim3((E2+255)/256), dim3(256), 0, stream>>>(par2, par1, FRO, ND2, L2L, L1L, NDL, NLV);

  // constants
  k_prep2b<<<dim3(56), dim3(256), 0, stream>>>(W, watt, MbT);
  k_prepAll<<<dim3(356), dim3(256), 0, stream>>>(W, watt, relT, Bt, WtB, Rb);
  k_relmm<<<dim3(16), dim3(256), 0, stream>>>(Rb, WtB, watt, Vh, RINV, RVW1, RVW2);

  // ---------- level 2 ----------
  k_cast<<<dim3(2048), dim3(256), 0, stream>>>(node, Xb);
  k_nodetab2<<<dim3((N_NODES+127)/128), dim3(256), 0, stream>>>(Xb, Bt, Gh, P);
  k_pass1_l2c<<<dim3(E2/64), dim3(256), 0, stream>>>(relT, rel2i, relrp2, par2, chi2, roo2,
                                                     Gh, P, MbT, RINV, RVW2, L2L, NLV, BBUF, DKb, CNTa);
  k_scan_a<<<dim3(SCAN_BLKS), dim3(256), 0, stream>>>(CNTa, ROFF, PART);
  k_scan_b<<<dim3(1), dim3(512), 0, stream>>>(PART);
  k_scatterc<<<dim3((E2+255)/256), dim3(256), 0, stream>>>(L2L, NLV, 0, par2, ROFF, PART, CURa, EIDX);
  k_agg2<<<dim3((N_NODES+3)/4), dim3(256), 0, stream>>>(ROFF, PART, CNTa, EIDX, BBUF, DKb,
                                                        chi2, rel2i, Vh, Xb, NDL, NLV, Xb2);

  // ---------- level 1 ----------
  k_nodetab2i<<<dim3((N_NODES+127)/128), dim3(256), 0, stream>>>(Xb2, Bt, NDL, NLV, Gh, P);
  k_pass1_l1c<<<dim3((E1+3)/4), dim3(256), 0, stream>>>(relT, rel1i, par1, chi1, roo1,
                                                        Gh, P, RINV, RVW1, RVW2, L1L, NLV, BBUF, DKb, CNTb);
  k_scan_a<<<dim3(SCAN_BLKS), dim3(256), 0, stream>>>(CNTb, ROFF, PART);
  k_scan_b<<<dim3(1), dim3(512), 0, stream>>>(PART);
  k_scatterc<<<dim3((E1+255)/256), dim3(256), 0, stream>>>(L1L, NLV, 1, par1, ROFF, PART, CURb, EIDX);
  k_aggout<<<dim3((NB+3)/4), dim3(256), 0, stream>>>(roout, ROFF, PART, CNTb, EIDX, BBUF, DKb,
                                                     chi1, rel1i, Vh, Xb2, (float*)d_out);
}

// Round 11
// 244.152 us; speedup vs baseline: 5.6986x; 1.2516x over previous
//
#include <hip/hip_runtime.h>
#include <hip/hip_bf16.h>
#include <cstdint>

#define N_NODES 100000
#define NPAD 100096
#define D 300
#define RD 100
#define NREL 1000
#define E2 200000
#define E1 100000
#define NB 8192
#define NEG 0.2f
#define SCAN_BLKS 391   // ceil(100000/256)
#define NBLKC 782       // ceil(200000/256)
#define NWAVES (NBLKC*4)

typedef __bf16 bf16x8 __attribute__((ext_vector_type(8)));
typedef float f32x4 __attribute__((ext_vector_type(4)));
typedef unsigned short us4 __attribute__((ext_vector_type(4)));
typedef unsigned short us8 __attribute__((ext_vector_type(8)));
typedef unsigned long long ull;

__device__ __forceinline__ float leaky(float x){ return x >= 0.f ? x : NEG*x; }

__device__ __forceinline__ unsigned short f2b(float v){
  unsigned u = __float_as_uint(v);
  unsigned r = u + 0x7FFF + ((u>>16)&1u);
  return (unsigned short)(r>>16);
}
__device__ __forceinline__ float b2f(unsigned short b){
  return __uint_as_float(((unsigned)b) << 16);
}
__device__ __forceinline__ float wred(float v){
  #pragma unroll
  for (int m = 32; m >= 1; m >>= 1) v += __shfl_xor(v, m, 64);
  return v;
}

// ---- init: zero flags, per-level CNT/CUR ----
__global__ void k_init(int* __restrict__ FRO, int* __restrict__ ND2,
                       int* __restrict__ CNTa, int* __restrict__ CURa,
                       int* __restrict__ CNTb, int* __restrict__ CURb){
  int i = blockIdx.x*256 + threadIdx.x;
  if (i < N_NODES){ FRO[i]=0; ND2[i]=0; CNTa[i]=0; CURa[i]=0; CNTb[i]=0; CURb[i]=0; }
}
__global__ void k_flag(const int* __restrict__ ro, int* __restrict__ FRO){
  int o = blockIdx.x*256 + threadIdx.x;
  if (o < NB) FRO[ro[o]] = 1;
}
__global__ void k_need(const int* __restrict__ par1, const int* __restrict__ chi1,
                       const int* __restrict__ roo1, const int* __restrict__ ro,
                       const int* __restrict__ FRO, int* __restrict__ ND2){
  int i = blockIdx.x*256 + threadIdx.x;
  if (i < NB) ND2[ro[i]] = 1;
  if (i < E1){
    int p = par1[i];
    if (FRO[p]){ ND2[p] = 1; ND2[chi1[i]] = 1; ND2[roo1[i]] = 1; }
  }
}

// ---- compaction phase 1: predicates -> wave masks + per-block counts (no atomics) ----
__global__ void k_cnt3(const int* __restrict__ par2, const int* __restrict__ par1,
                       const int* __restrict__ FRO, const int* __restrict__ ND2,
                       ull* __restrict__ MSK, int* __restrict__ BC){
  int i = blockIdx.x*256 + threadIdx.x;
  int lane = threadIdx.x & 63, wid = threadIdx.x >> 6;
  __shared__ int ws[3][4];
  int p2 = (i < E2) && ND2[par2[i]];
  int p1 = (i < E1) && FRO[par1[i]];
  int pn = (i < N_NODES) && ND2[i];
  ull m2 = __ballot(p2), m1 = __ballot(p1), mn = __ballot(pn);
  if (lane == 0){
    int wg = blockIdx.x*4 + wid;
    MSK[0*NWAVES + wg] = m2; ws[0][wid] = __popcll(m2);
    MSK[1*NWAVES + wg] = m1; ws[1][wid] = __popcll(m1);
    MSK[2*NWAVES + wg] = mn; ws[2][wid] = __popcll(mn);
  }
  __syncthreads();
  if (threadIdx.x < 3)
    BC[threadIdx.x*NBLKC + blockIdx.x] =
      ws[threadIdx.x][0]+ws[threadIdx.x][1]+ws[threadIdx.x][2]+ws[threadIdx.x][3];
}

// ---- compaction phase 2: scan 3x782 block counts -> block offsets + totals ----
__global__ __launch_bounds__(1024) void k_scanblk(const int* __restrict__ BC,
                                                  int* __restrict__ BOFF, int* __restrict__ NLV){
  __shared__ int ls[1024];
  for (int l=0; l<3; ++l){
    int v = (threadIdx.x < NBLKC) ? BC[l*NBLKC + threadIdx.x] : 0;
    ls[threadIdx.x] = v;
    __syncthreads();
    for (int off=1; off<1024; off<<=1){
      int t = (threadIdx.x >= off) ? ls[threadIdx.x-off] : 0;
      __syncthreads();
      ls[threadIdx.x] += t;
      __syncthreads();
    }
    if (threadIdx.x < NBLKC) BOFF[l*NBLKC + threadIdx.x] = ls[threadIdx.x] - v;
    if (threadIdx.x == 1023) NLV[l] = ls[1023];
    __syncthreads();
  }
}

// ---- compaction phase 3: write lists from stored masks (deterministic, no atomics) ----
__global__ void k_fill(const ull* __restrict__ MSK, const int* __restrict__ BOFF,
                       int* __restrict__ L2L, int* __restrict__ L1L, int* __restrict__ NDL){
  int i = blockIdx.x*256 + threadIdx.x;
  int lane = threadIdx.x & 63, wid = threadIdx.x >> 6;
  int wg = blockIdx.x*4 + wid;
  __shared__ int ws[3][4];
  ull m2 = MSK[0*NWAVES+wg], m1 = MSK[1*NWAVES+wg], mn = MSK[2*NWAVES+wg];
  if (lane == 0){ ws[0][wid]=__popcll(m2); ws[1][wid]=__popcll(m1); ws[2][wid]=__popcll(mn); }
  __syncthreads();
  int w2=0, w1=0, wn=0;
  #pragma unroll
  for (int k=0;k<4;++k){
    if (k < wid){ w2+=ws[0][k]; w1+=ws[1][k]; wn+=ws[2][k]; }
  }
  ull below = (1ull<<lane) - 1ull;
  if ((m2>>lane)&1ull) L2L[BOFF[0*NBLKC+blockIdx.x] + w2 + __popcll(m2 & below)] = i;
  if ((m1>>lane)&1ull) L1L[BOFF[1*NBLKC+blockIdx.x] + w1 + __popcll(m1 & below)] = i;
  if ((mn>>lane)&1ull) NDL[BOFF[2*NBLKC+blockIdx.x] + wn + __popcll(mn & below)] = i;
}

// ---- MbT[112][128] bf16: rows j<100 -> M[j][i]; row 100 -> W^T w1 ----
__global__ void k_prep2b(const float* __restrict__ W, const float* __restrict__ watt,
                         unsigned short* __restrict__ MbT){
  int u = blockIdx.x*blockDim.x + threadIdx.x;
  if (u >= 112*128) return;
  int j = u >> 7, i = u & 127;
  float v = 0.f;
  if (i < RD){
    if (j < RD){ float a=0.f; for (int d=0;d<D;++d) a += W[d*RD+i]*W[d*RD+j]; v=a; }
    else if (j == RD){ float a=0.f; for (int d=0;d<D;++d) a += watt[d]*W[d*RD+i]; v=a; }
  }
  MbT[u] = f2b(v);
}

// ---- fused prep: Bt[112][320], WtB[304][128], Rb[1024][128] ----
__global__ void k_prepAll(const float* __restrict__ W, const float* __restrict__ watt,
                          const float* __restrict__ relT, unsigned short* __restrict__ Bt,
                          unsigned short* __restrict__ WtB, unsigned short* __restrict__ Rb){
  int b = blockIdx.x;
  if (b < 140){
    int u = b*256 + threadIdx.x;
    if (u < 112*320){
      int c = u / 320, k = u % 320;
      float v = 0.f;
      if (k < D){
        if (c < RD) v = W[k*RD + c];
        else if (c < RD+3) v = watt[(c-RD)*D + k];
      }
      Bt[u] = f2b(v);
    }
  } else if (b < 292){
    int u = (b-140)*256 + threadIdx.x;
    if (u < 304*128){
      int dd = u >> 7, k = u & 127;
      float v = (dd < D && k < RD) ? W[dd*RD + k] : 0.f;
      WtB[u] = f2b(v);
    }
  } else {
    int u = (b-292)*256 + threadIdx.x;
    if (u < 1024*16){
      int row = u >> 4, c8 = (u & 15)*8;
      us8 o;
      #pragma unroll
      for (int j=0;j<8;++j){
        int c = c8+j;
        o[j] = (row < NREL && c < RD) ? f2b(relT[row*RD + c]) : (unsigned short)0;
      }
      *(us8*)(Rb + (size_t)row*128 + c8) = o;
    }
  }
}

// ---- MFMA relation tables: U = Rb @ WtB^T -> Vh (bf16), RINV, RVW1, RVW2 ----
__global__ __launch_bounds__(256) void k_relmm(const unsigned short* __restrict__ Rb,
    const unsigned short* __restrict__ WtB, const float* __restrict__ watt,
    unsigned short* __restrict__ Vh, float* __restrict__ RINV,
    float* __restrict__ RVW1, float* __restrict__ RVW2){
  int lane = threadIdx.x & 63, wid = threadIdx.x >> 6;
  int r0 = blockIdx.x*64 + wid*16;
  int ep = lane & 15, g = lane >> 4;
  size_t a0 = (size_t)(r0 + ep)*128 + g*8;
  size_t b0 = (size_t)ep*128 + g*8;
  f32x4 acc[19];
  #pragma unroll
  for (int cf=0;cf<19;++cf) acc[cf]=(f32x4){0.f,0.f,0.f,0.f};
  #pragma unroll
  for (int ks=0; ks<4; ++ks){
    bf16x8 af = *(const bf16x8*)(Rb + a0 + ks*32);
    #pragma unroll
    for (int cf=0; cf<19; ++cf){
      bf16x8 bf = *(const bf16x8*)(WtB + b0 + (size_t)cf*16*128 + ks*32);
      acc[cf] = __builtin_amdgcn_mfma_f32_16x16x32_bf16(af, bf, acc[cf], 0, 0, 0);
    }
  }
  float w1v[19], w2v[19];
  #pragma unroll
  for (int cf=0; cf<19; ++cf){
    int col = cf*16+ep;
    bool ok = col < D;
    w1v[cf] = ok ? watt[col] : 0.f;
    w2v[cf] = ok ? watt[D+col] : 0.f;
  }
  #pragma unroll
  for (int reg=0; reg<4; ++reg){
    int row = r0 + g*4 + reg;
    float np = 0.f;
    #pragma unroll
    for (int cf=0; cf<19; ++cf){ float u = acc[cf][reg]; np += u*u; }
    np += __shfl_xor(np,1); np += __shfl_xor(np,2); np += __shfl_xor(np,4); np += __shfl_xor(np,8);
    float iv = 1.f / fmaxf(sqrtf(np), 1e-12f);
    float p1 = 0.f, p2 = 0.f;
    if (row < NREL){
      #pragma unroll
      for (int cf=0; cf<19; ++cf){
        int col = cf*16+ep;
        float v = acc[cf][reg]*iv;
        if (col < D){
          Vh[(size_t)row*D + col] = f2b(v);
          p1 += v*w1v[cf];
          p2 += v*w2v[cf];
        }
      }
    }
    p1 += __shfl_xor(p1,1); p1 += __shfl_xor(p1,2); p1 += __shfl_xor(p1,4); p1 += __shfl_xor(p1,8);
    p2 += __shfl_xor(p2,1); p2 += __shfl_xor(p2,2); p2 += __shfl_xor(p2,4); p2 += __shfl_xor(p2,8);
    if (ep == 0 && row < NREL){
      RINV[row] = iv; RVW1[row] = p1; RVW2[row] = p2;
    }
  }
}

// ---- cast node embeddings to padded bf16 table Xb[NPAD][320] ----
__global__ void k_cast(const float* __restrict__ src, unsigned short* __restrict__ dst){
  int total = NPAD*40;
  for (int u = blockIdx.x*blockDim.x + threadIdx.x; u < total; u += gridDim.x*blockDim.x){
    int row = u/40, c8 = (u%40)*8;
    us8 o;
    if (row < N_NODES && c8 <= 292){
      float4 x = *(const float4*)(src + (size_t)row*D + c8);
      float4 y = *(const float4*)(src + (size_t)row*D + c8 + 4);
      o[0]=f2b(x.x); o[1]=f2b(x.y); o[2]=f2b(x.z); o[3]=f2b(x.w);
      o[4]=f2b(y.x); o[5]=f2b(y.y); o[6]=f2b(y.z); o[7]=f2b(y.w);
    } else {
      #pragma unroll
      for (int j=0;j<8;++j){
        int c = c8+j;
        float v = (row < N_NODES && c < D) ? src[(size_t)row*D + c] : 0.f;
        o[j] = f2b(v);
      }
    }
    *(us8*)(dst + (size_t)row*320 + c8) = o;
  }
}

// ---- MFMA node tables (full, level 2): Gh[n] = bf16(W^T e_n), P[n] ----
__global__ __launch_bounds__(256) void k_nodetab2(const unsigned short* __restrict__ Eb,
    const unsigned short* __restrict__ Bt, unsigned short* __restrict__ Gh, float* __restrict__ P){
  int lane = threadIdx.x & 63, wid = threadIdx.x >> 6;
  int n0 = blockIdx.x*128;
  size_t a0 = (size_t)(n0 + wid*32 + (lane&15))*320 + ((lane>>4)*8);
  size_t b0 = (size_t)(lane&15)*320 + ((lane>>4)*8);
  f32x4 acc[2][7];
  #pragma unroll
  for (int s=0;s<2;++s)
    #pragma unroll
    for (int c=0;c<7;++c) acc[s][c] = (f32x4){0.f,0.f,0.f,0.f};
  for (int ks = 0; ks < 10; ++ks){
    bf16x8 a0f = *(const bf16x8*)(Eb + a0 + ks*32);
    bf16x8 a1f = *(const bf16x8*)(Eb + a0 + 16*320 + ks*32);
    #pragma unroll
    for (int cf=0; cf<7; ++cf){
      bf16x8 bf = *(const bf16x8*)(Bt + b0 + (size_t)cf*16*320 + ks*32);
      acc[0][cf] = __builtin_amdgcn_mfma_f32_16x16x32_bf16(a0f, bf, acc[0][cf], 0, 0, 0);
      acc[1][cf] = __builtin_amdgcn_mfma_f32_16x16x32_bf16(a1f, bf, acc[1][cf], 0, 0, 0);
    }
  }
  int rbase = n0 + wid*32 + ((lane>>4)<<2);
  int cbase = lane & 15;
  #pragma unroll
  for (int sub=0; sub<2; ++sub){
    #pragma unroll
    for (int cf=0; cf<7; ++cf){
      int col = cf*16 + cbase;
      #pragma unroll
      for (int r=0; r<4; ++r){
        int row = rbase + sub*16 + r;
        if (row < N_NODES){
          float v = acc[sub][cf][r];
          if (col < RD) Gh[(size_t)row*RD + col] = f2b(v);
          else if (col < RD+3) P[(size_t)row*4 + (col-RD)] = v;
        }
      }
    }
  }
}

// ---- MFMA node tables (indexed, level 1): rows from NDL, count-capped ----
__global__ __launch_bounds__(256) void k_nodetab2i(const unsigned short* __restrict__ Eb,
    const unsigned short* __restrict__ Bt, const int* __restrict__ NDL, const int* __restrict__ NLV,
    unsigned short* __restrict__ Gh, float* __restrict__ P){
  int nlv = NLV[2];
  int base = blockIdx.x*128;
  if (base >= nlv) return;
  int lane = threadIdx.x & 63, wid = threadIdx.x >> 6;
  int li0 = base + wid*32 + (lane&15);
  int li1 = li0 + 16;
  int row0 = (li0 < nlv) ? NDL[li0] : 0;
  int row1 = (li1 < nlv) ? NDL[li1] : 0;
  size_t a0 = (size_t)row0*320 + ((lane>>4)*8);
  size_t a1 = (size_t)row1*320 + ((lane>>4)*8);
  size_t b0 = (size_t)(lane&15)*320 + ((lane>>4)*8);
  f32x4 acc[2][7];
  #pragma unroll
  for (int s=0;s<2;++s)
    #pragma unroll
    for (int c=0;c<7;++c) acc[s][c] = (f32x4){0.f,0.f,0.f,0.f};
  for (int ks = 0; ks < 10; ++ks){
    bf16x8 a0f = *(const bf16x8*)(Eb + a0 + ks*32);
    bf16x8 a1f = *(const bf16x8*)(Eb + a1 + ks*32);
    #pragma unroll
    for (int cf=0; cf<7; ++cf){
      bf16x8 bf = *(const bf16x8*)(Bt + b0 + (size_t)cf*16*320 + ks*32);
      acc[0][cf] = __builtin_amdgcn_mfma_f32_16x16x32_bf16(a0f, bf, acc[0][cf], 0, 0, 0);
      acc[1][cf] = __builtin_amdgcn_mfma_f32_16x16x32_bf16(a1f, bf, acc[1][cf], 0, 0, 0);
    }
  }
  int lbase = base + wid*32 + ((lane>>4)<<2);
  int cbase = lane & 15;
  #pragma unroll
  for (int sub=0; sub<2; ++sub){
    #pragma unroll
    for (int r=0; r<4; ++r){
      int li = lbase + sub*16 + r;
      if (li >= nlv) continue;
      int row = NDL[li];
      #pragma unroll
      for (int cf=0; cf<7; ++cf){
        int col = cf*16 + cbase;
        float v = acc[sub][cf][r];
        if (col < RD) Gh[(size_t)row*RD + col] = f2b(v);
        else if (col < RD+3) P[(size_t)row*4 + (col-RD)] = v;
      }
    }
  }
}

// ---- level-2 pass 1 (MFMA, compacted): logits + DK + parent histogram ----
__global__ __launch_bounds__(256) void k_pass1_l2c(
    const float* __restrict__ relT, const int* __restrict__ rel2i, const int* __restrict__ relrp2,
    const int* __restrict__ par, const int* __restrict__ chi, const int* __restrict__ roo,
    const unsigned short* __restrict__ Gh, const float* __restrict__ P,
    const unsigned short* __restrict__ MbT,
    const float* __restrict__ RINV, const float* __restrict__ RVW2,
    const int* __restrict__ L2L, const int* __restrict__ NLV,
    float* __restrict__ BBUF, float* __restrict__ DK, int* __restrict__ CNT){
  __shared__ unsigned short Cl[4*16*136];
  int nlv = NLV[0];
  if (blockIdx.x*64 >= nlv) return;
  int lane = threadIdx.x & 63, wid = threadIdx.x >> 6;
  int ep = lane & 15, g = lane >> 4;
  unsigned short* cw = Cl + wid*16*136;
  int idx = blockIdx.x*64 + wid*16 + ep;
  int live = idx < nlv;
  int e = live ? L2L[idx] : 0;
  int rp = par[e];
  int ra = rel2i[e], rb = relrp2[e], rc = chi[e], rr = roo[e];
  const float* rA = relT + (size_t)ra*RD;
  const float* rB = relT + (size_t)rb*RD;
  const unsigned short* gR = Gh + (size_t)rr*RD;
  const unsigned short* gX = Gh + (size_t)rp*RD;
  const unsigned short* gY = Gh + (size_t)rc*RD;
  float dgi = 0.f, dgx = 0.f, dgy = 0.f;
  bf16x8 af[4];
  #pragma unroll
  for (int ks=0; ks<4; ++ks){
    us8 cpack;
    #pragma unroll
    for (int h=0; h<2; ++h){
      int k0 = g*8 + ks*32 + h*4;
      float4 a4 = make_float4(0.f,0.f,0.f,0.f), b4 = a4, grr = a4, grp = a4, gry = a4;
      if (live && k0 <= 96){
        a4  = *(const float4*)(rA + k0);
        b4  = *(const float4*)(rB + k0);
        us4 r4 = *(const us4*)(gR + k0);
        us4 x4 = *(const us4*)(gX + k0);
        us4 y4 = *(const us4*)(gY + k0);
        grr = make_float4(b2f(r4[0]),b2f(r4[1]),b2f(r4[2]),b2f(r4[3]));
        grp = make_float4(b2f(x4[0]),b2f(x4[1]),b2f(x4[2]),b2f(x4[3]));
        gry = make_float4(b2f(y4[0]),b2f(y4[1]),b2f(y4[2]),b2f(y4[3]));
      }
      float4 c4;
      c4.x = a4.x*b4.x; c4.y = a4.y*b4.y; c4.z = a4.z*b4.z; c4.w = a4.w*b4.w;
      dgi += c4.x*grr.x + c4.y*grr.y + c4.z*grr.z + c4.w*grr.w;
      dgx += a4.x*grp.x + a4.y*grp.y + a4.z*grp.z + a4.w*grp.w;
      dgy += a4.x*gry.x + a4.y*gry.y + a4.z*gry.z + a4.w*gry.w;
      cpack[h*4+0]=f2b(c4.x); cpack[h*4+1]=f2b(c4.y); cpack[h*4+2]=f2b(c4.z); cpack[h*4+3]=f2b(c4.w);
    }
    *(us8*)((char*)cw + ep*272 + g*16 + ks*64) = cpack;
    af[ks] = *(bf16x8*)&cpack;
  }
  f32x4 acc[7];
  #pragma unroll
  for (int cf=0; cf<7; ++cf) acc[cf] = (f32x4){0.f,0.f,0.f,0.f};
  #pragma unroll
  for (int cf=0; cf<7; ++cf){
    #pragma unroll
    for (int ks=0; ks<4; ++ks){
      bf16x8 bfr = *(const bf16x8*)(MbT + (size_t)(cf*16+ep)*128 + g*8 + ks*32);
      acc[cf] = __builtin_amdgcn_mfma_f32_16x16x32_bf16(af[ks], bfr, acc[cf], 0, 0, 0);
    }
  }
  dgi += __shfl_xor(dgi, 16); dgi += __shfl_xor(dgi, 32);
  dgx += __shfl_xor(dgx, 16); dgx += __shfl_xor(dgx, 32);
  dgy += __shfl_xor(dgy, 16); dgy += __shfl_xor(dgy, 32);
  __syncthreads();
  #pragma unroll
  for (int r=0; r<4; ++r){
    int row = g*4 + r;
    int src = (lane & 48) | row;
    int livr = __shfl(live, src);
    if (!livr) continue;
    float pr = 0.f;
    #pragma unroll
    for (int cf=0; cf<7; ++cf)
      pr += b2f(cw[row*136 + cf*16 + ep]) * acc[cf][r];
    pr += __shfl_xor(pr, 1); pr += __shfl_xor(pr, 2);
    pr += __shfl_xor(pr, 4); pr += __shfl_xor(pr, 8);
    float dw1r = __shfl(acc[6][r], (lane & 48) | 4);   // t[row][100]
    float dgir = __shfl(dgi, src);
    float dgxr = __shfl(dgx, src);
    float dgyr = __shfl(dgy, src);
    int rar = __shfl(ra, src), rpr = __shfl(rp, src);
    int rcr = __shfl(rc, src), rrr = __shfl(rr, src);
    int er  = __shfl(e, src);
    float invp = 1.f / fmaxf(sqrtf(pr), 1e-12f);
    float rinv = RINV[rar];
    float t1 = (dgir*invp)*(dw1r*invp);
    float t2 = (dgxr*rinv)*RVW2[rar];
    float bb = P[(size_t)rrr*4+0] - 2.f*t1 + P[(size_t)rpr*4+1] - 2.f*t2 + P[(size_t)rcr*4+2];
    bb = leaky(bb);
    if (ep == 0){
      BBUF[er] = bb;
      DK[er] = dgyr * rinv;
      atomicAdd(&CNT[rpr], 1);
    }
  }
}

// ---- level-1 pass 1 (compacted): one wave per live edge ----
__global__ __launch_bounds__(256) void k_pass1_l1c(
    const float* __restrict__ relT, const int* __restrict__ rel1i,
    const int* __restrict__ par, const int* __restrict__ chi, const int* __restrict__ roo,
    const unsigned short* __restrict__ Gh, const float* __restrict__ P,
    const float* __restrict__ RINV, const float* __restrict__ RVW1, const float* __restrict__ RVW2,
    const int* __restrict__ L1L, const int* __restrict__ NLV,
    float* __restrict__ BBUF, float* __restrict__ DK, int* __restrict__ CNT){
  int nlv = NLV[1];
  int j = (blockIdx.x*256 + threadIdx.x) >> 6;
  if (j >= nlv) return;
  int lane = threadIdx.x & 63;
  int e = L1L[j];
  int pp = par[e];
  int r = rel1i[e], cc = chi[e], ii = roo[e];
  const float* rrow = relT + r*RD;
  const unsigned short* gI = Gh + (size_t)ii*RD;
  const unsigned short* gX = Gh + (size_t)pp*RD;
  const unsigned short* gY = Gh + (size_t)cc*RD;
  float ai = rrow[lane]*b2f(gI[lane]);
  float ax = rrow[lane]*b2f(gX[lane]);
  float ay = rrow[lane]*b2f(gY[lane]);
  if (lane < 36){
    ai += rrow[lane+64]*b2f(gI[lane+64]);
    ax += rrow[lane+64]*b2f(gX[lane+64]);
    ay += rrow[lane+64]*b2f(gY[lane+64]);
  }
  float dgi = wred(ai), dgx = wred(ax), dgy = wred(ay);
  if (lane == 0){
    float invn = RINV[r];
    float b = P[(size_t)ii*4+0] - 2.f*(dgi*invn)*RVW1[r]
            + P[(size_t)pp*4+1] - 2.f*(dgx*invn)*RVW2[r]
            + P[(size_t)cc*4+2];
    b = leaky(b);
    BBUF[e] = b;
    DK[e] = dgy * invn;
    atomicAdd(&CNT[pp], 1);
  }
}

// ---- CSR build: exclusive scan over CNT ----
__global__ __launch_bounds__(256) void k_scan_a(const int* __restrict__ CNT,
    int* __restrict__ ROFF, int* __restrict__ PART){
  __shared__ int ls[256];
  int i = blockIdx.x*256 + threadIdx.x;
  int v = (i < N_NODES) ? CNT[i] : 0;
  ls[threadIdx.x] = v;
  __syncthreads();
  for (int off=1; off<256; off<<=1){
    int t = (threadIdx.x >= off) ? ls[threadIdx.x-off] : 0;
    __syncthreads();
    ls[threadIdx.x] += t;
    __syncthreads();
  }
  int incl = ls[threadIdx.x];
  if (i < N_NODES) ROFF[i] = incl - v;
  if (threadIdx.x == 255) PART[blockIdx.x] = incl;
}
__global__ __launch_bounds__(512) void k_scan_b(int* __restrict__ PART){
  __shared__ int ls[512];
  int v = (threadIdx.x < SCAN_BLKS) ? PART[threadIdx.x] : 0;
  ls[threadIdx.x] = v;
  __syncthreads();
  for (int off=1; off<512; off<<=1){
    int t = (threadIdx.x >= off) ? ls[threadIdx.x-off] : 0;
    __syncthreads();
    ls[threadIdx.x] += t;
    __syncthreads();
  }
  if (threadIdx.x < SCAN_BLKS) PART[threadIdx.x] = ls[threadIdx.x] - v;
}
// ---- compacted scatter: iterate live-edge list ----
__global__ void k_scatterc(const int* __restrict__ L, const int* __restrict__ NLV, int which,
                           const int* __restrict__ par, const int* __restrict__ ROFF,
                           const int* __restrict__ PART, int* __restrict__ CUR,
                           int* __restrict__ EIDX){
  int j = blockIdx.x*256 + threadIdx.x;
  if (j >= NLV[which]) return;
  int e = L[j];
  int p = par[e];
  int pos = ROFF[p] + PART[p>>8] + atomicAdd(&CUR[p], 1);
  EIDX[pos] = e;
}

// ---- per-parent softmax + Householder aggregate; DK precomputed ----
__device__ __forceinline__ void agg_bucket(int p, int lane,
    const int* __restrict__ ROFF, const int* __restrict__ PART, const int* __restrict__ CNT,
    const int* __restrict__ EIDX, const float* __restrict__ BBUF, const float* __restrict__ DK,
    const int* __restrict__ chi, const int* __restrict__ relI,
    const unsigned short* __restrict__ Vh, const unsigned short* __restrict__ Xe,
    float acc[5]){
  int cnt = CNT[p];
  if (cnt <= 0) return;
  int base = ROFF[p] + PART[p>>8];
  if (cnt <= 64){
    float bl = (lane < cnt) ? BBUF[EIDX[base+lane]] : -1e30f;
    float m = bl;
    #pragma unroll
    for (int msk=32; msk>=1; msk>>=1) m = fmaxf(m, __shfl_xor(m, msk));
    float el = (lane < cnt) ? __expf(bl - m) : 0.f;
    float s = wred(el);
    float inv = 1.f / fmaxf(s, 1e-10f);
    for (int i=0;i<cnt;++i){
      int eid = EIDX[base+i];
      float a = __shfl(el, i) * inv;
      float s2 = 2.f*DK[eid]*a;
      int y = chi[eid], r = relI[eid];
      const unsigned short* vr = Vh + (size_t)r*D;
      const unsigned short* ey = Xe + (size_t)y*320;
      #pragma unroll
      for (int q=0;q<4;++q){
        int d = lane + 64*q;
        acc[q] += b2f(ey[d])*a - s2*b2f(vr[d]);
      }
      if (lane < 44){
        int d = lane + 256;
        acc[4] += b2f(ey[d])*a - s2*b2f(vr[d]);
      }
    }
  } else {
    float m = -1e30f;
    for (int i=0;i<cnt;++i) m = fmaxf(m, BBUF[EIDX[base+i]]);
    float s = 0.f;
    for (int i=0;i<cnt;++i) s += __expf(BBUF[EIDX[base+i]] - m);
    float inv = 1.f / fmaxf(s, 1e-10f);
    for (int i=0;i<cnt;++i){
      int eid = EIDX[base+i];
      float a = __expf(BBUF[eid]-m)*inv;
      float s2 = 2.f*DK[eid]*a;
      int y = chi[eid], r = relI[eid];
      const unsigned short* vr = Vh + (size_t)r*D;
      const unsigned short* ey = Xe + (size_t)y*320;
      #pragma unroll
      for (int q=0;q<4;++q){
        int d = lane + 64*q;
        acc[q] += b2f(ey[d])*a - s2*b2f(vr[d]);
      }
      if (lane < 44){
        int d = lane + 256;
        acc[4] += b2f(ey[d])*a - s2*b2f(vr[d]);
      }
    }
  }
}

// ---- level-2 (compacted): one wave per needed parent from NDL ----
__global__ __launch_bounds__(256) void k_agg2(const int* __restrict__ ROFF, const int* __restrict__ PART,
    const int* __restrict__ CNT, const int* __restrict__ EIDX,
    const float* __restrict__ BBUF, const float* __restrict__ DK,
    const int* __restrict__ chi, const int* __restrict__ relI,
    const unsigned short* __restrict__ Vh, const unsigned short* __restrict__ Xe,
    const int* __restrict__ NDL, const int* __restrict__ NLV,
    unsigned short* __restrict__ Xo){
  int nlv = NLV[2];
  int idx = (blockIdx.x*256 + threadIdx.x) >> 6;
  if (idx >= nlv) return;
  int lane = threadIdx.x & 63;
  int p = NDL[idx];
  float acc[5] = {0.f,0.f,0.f,0.f,0.f};
  agg_bucket(p, lane, ROFF, PART, CNT, EIDX, BBUF, DK, chi, relI, Vh, Xe, acc);
  const unsigned short* in = Xe + (size_t)p*320;
  unsigned short* op = Xo + (size_t)p*320;
  #pragma unroll
  for (int q=0;q<4;++q){
    int d = lane + 64*q;
    op[d] = f2b(leaky(b2f(in[d]) + acc[q]));
  }
  {
    int d = lane + 256;
    unsigned short o = 0;
    if (lane < 44) o = f2b(leaky(b2f(in[d]) + acc[4]));
    op[d] = o;
  }
}

// ---- level-1: one wave per OUTPUT (8192); writes d_out directly ----
__global__ __launch_bounds__(256) void k_aggout(const int* __restrict__ ro,
    const int* __restrict__ ROFF, const int* __restrict__ PART,
    const int* __restrict__ CNT, const int* __restrict__ EIDX,
    const float* __restrict__ BBUF, const float* __restrict__ DK,
    const int* __restrict__ chi, const int* __restrict__ relI,
    const unsigned short* __restrict__ Vh, const unsigned short* __restrict__ Xe,
    float* __restrict__ out){
  int lane = threadIdx.x & 63;
  int o = (blockIdx.x*256 + threadIdx.x) >> 6;
  if (o >= NB) return;
  int p = ro[o];
  float acc[5] = {0.f,0.f,0.f,0.f,0.f};
  agg_bucket(p, lane, ROFF, PART, CNT, EIDX, BBUF, DK, chi, relI, Vh, Xe, acc);
  const unsigned short* in = Xe + (size_t)p*320;
  float* op = out + (size_t)o*D;
  #pragma unroll
  for (int q=0;q<4;++q){
    int d = lane + 64*q;
    op[d] = leaky(b2f(in[d]) + acc[q]);
  }
  if (lane < 44){
    int d = lane + 256;
    op[d] = leaky(b2f(in[d]) + acc[4]);
  }
}

extern "C" void kernel_launch(void* const* d_in, const int* in_sizes, int n_in,
                              void* d_out, int out_size, void* d_ws, size_t ws_size,
                              hipStream_t stream){
  const float* node = (const float*)d_in[0];
  const float* relT = (const float*)d_in[1];
  const float* W    = (const float*)d_in[2];
  const float* watt = (const float*)d_in[3];
  const int* par2 = (const int*)d_in[4];
  const int* chi2 = (const int*)d_in[5];
  const int* roo2 = (const int*)d_in[6];
  const int* rel2i = (const int*)d_in[7];
  const int* relrp2 = (const int*)d_in[8];
  const int* par1 = (const int*)d_in[9];
  const int* chi1 = (const int*)d_in[10];
  const int* roo1 = (const int*)d_in[11];
  const int* rel1i = (const int*)d_in[12];
  const int* roout = (const int*)d_in[13];

  char* w = (char*)d_ws;
  size_t off = 0;
  auto alloc = [&](size_t bytes)->void*{ void* p = w + off; off += (bytes + 255) & ~(size_t)255; return p; };
  unsigned short* Gh = (unsigned short*)alloc((size_t)N_NODES*RD*2);
  float* P    = (float*)alloc((size_t)N_NODES*4*4);
  unsigned short* Vh = (unsigned short*)alloc((size_t)NREL*D*2);
  float* RINV = (float*)alloc(NREL*4);
  float* RVW1 = (float*)alloc(NREL*4);
  float* RVW2 = (float*)alloc(NREL*4);
  float* BBUF = (float*)alloc((size_t)E2*4);
  float* DKb  = (float*)alloc((size_t)E2*4);
  unsigned short* Xb  = (unsigned short*)alloc((size_t)NPAD*320*2);
  unsigned short* Xb2 = (unsigned short*)alloc((size_t)NPAD*320*2);
  unsigned short* Bt  = (unsigned short*)alloc((size_t)112*320*2);
  unsigned short* MbT = (unsigned short*)alloc((size_t)112*128*2);
  unsigned short* WtB = (unsigned short*)alloc((size_t)304*128*2);
  unsigned short* Rb  = (unsigned short*)alloc((size_t)1024*128*2);
  int* CNTa = (int*)alloc((size_t)N_NODES*4);
  int* CURa = (int*)alloc((size_t)N_NODES*4);
  int* CNTb = (int*)alloc((size_t)N_NODES*4);
  int* CURb = (int*)alloc((size_t)N_NODES*4);
  int* ROFF = (int*)alloc((size_t)N_NODES*4);
  int* PART = (int*)alloc(512*4);
  int* EIDX = (int*)alloc((size_t)E2*4);
  int* FRO  = (int*)alloc((size_t)N_NODES*4);
  int* ND2  = (int*)alloc((size_t)N_NODES*4);
  int* L2L  = (int*)alloc((size_t)E2*4);
  int* L1L  = (int*)alloc((size_t)E1*4);
  int* NDL  = (int*)alloc((size_t)N_NODES*4);
  int* NLV  = (int*)alloc(256);
  ull* MSK  = (ull*)alloc((size_t)3*NWAVES*8);
  int* BC   = (int*)alloc((size_t)3*NBLKC*4);
  int* BOFF = (int*)alloc((size_t)3*NBLKC*4);

  // backward-slice flags + scan-based compaction (index-only dependency, no global atomics)
  k_init<<<dim3(SCAN_BLKS), dim3(256), 0, stream>>>(FRO, ND2, CNTa, CURa, CNTb, CURb);
  k_flag<<<dim3((NB+255)/256), dim3(256), 0, stream>>>(roout, FRO);
  k_need<<<dim3((E1+255)/256), dim3(256), 0, stream>>>(par1, chi1, roo1, roout, FRO, ND2);
  k_cnt3<<<dim3(NBLKC), dim3(256), 0, stream>>>(par2, par1, FRO, ND2, MSK, BC);
  k_scanblk<<<dim3(1), dim3(1024), 0, stream>>>(BC, BOFF, NLV);
  k_fill<<<dim3(NBLKC), dim3(256), 0, stream>>>(MSK, BOFF, L2L, L1L, NDL);

  // constants
  k_prep2b<<<dim3(56), dim3(256), 0, stream>>>(W, watt, MbT);
  k_prepAll<<<dim3(356), dim3(256), 0, stream>>>(W, watt, relT, Bt, WtB, Rb);
  k_relmm<<<dim3(16), dim3(256), 0, stream>>>(Rb, WtB, watt, Vh, RINV, RVW1, RVW2);

  // ---------- level 2 ----------
  k_cast<<<dim3(2048), dim3(256), 0, stream>>>(node, Xb);
  k_nodetab2<<<dim3((N_NODES+127)/128), dim3(256), 0, stream>>>(Xb, Bt, Gh, P);
  k_pass1_l2c<<<dim3(E2/64), dim3(256), 0, stream>>>(relT, rel2i, relrp2, par2, chi2, roo2,
                                                     Gh, P, MbT, RINV, RVW2, L2L, NLV, BBUF, DKb, CNTa);
  k_scan_a<<<dim3(SCAN_BLKS), dim3(256), 0, stream>>>(CNTa, ROFF, PART);
  k_scan_b<<<dim3(1), dim3(512), 0, stream>>>(PART);
  k_scatterc<<<dim3((E2+255)/256), dim3(256), 0, stream>>>(L2L, NLV, 0, par2, ROFF, PART, CURa, EIDX);
  k_agg2<<<dim3((N_NODES+3)/4), dim3(256), 0, stream>>>(ROFF, PART, CNTa, EIDX, BBUF, DKb,
                                                        chi2, rel2i, Vh, Xb, NDL, NLV, Xb2);

  // ---------- level 1 ----------
  k_nodetab2i<<<dim3((N_NODES+127)/128), dim3(256), 0, stream>>>(Xb2, Bt, NDL, NLV, Gh, P);
  k_pass1_l1c<<<dim3((E1+3)/4), dim3(256), 0, stream>>>(relT, rel1i, par1, chi1, roo1,
                                                        Gh, P, RINV, RVW1, RVW2, L1L, NLV, BBUF, DKb, CNTb);
  k_scan_a<<<dim3(SCAN_BLKS), dim3(256), 0, stream>>>(CNTb, ROFF, PART);
  k_scan_b<<<dim3(1), dim3(512), 0, stream>>>(PART);
  k_scatterc<<<dim3((E1+255)/256), dim3(256), 0, stream>>>(L1L, NLV, 1, par1, ROFF, PART, CURb, EIDX);
  k_aggout<<<dim3((NB+3)/4), dim3(256), 0, stream>>>(roout, ROFF, PART, CNTb, EIDX, BBUF, DKb,
                                                     chi1, rel1i, Vh, Xb2, (float*)d_out);
}

// Round 12
// 224.060 us; speedup vs baseline: 6.2096x; 1.0897x over previous
//
#include <hip/hip_runtime.h>
#include <hip/hip_bf16.h>
#include <cstdint>

#define N_NODES 100000
#define NPAD 100096
#define D 300
#define RD 100
#define NREL 1000
#define E2 200000
#define E1 100000
#define NB 8192
#define NEG 0.2f
#define SCAN_BLKS 391   // ceil(100000/256)
#define NBLKC 782       // ceil(200000/256)
#define NWAVES (NBLKC*4)

typedef __bf16 bf16x8 __attribute__((ext_vector_type(8)));
typedef float f32x4 __attribute__((ext_vector_type(4)));
typedef unsigned short us4 __attribute__((ext_vector_type(4)));
typedef unsigned short us8 __attribute__((ext_vector_type(8)));
typedef unsigned long long ull;

__device__ __forceinline__ float leaky(float x){ return x >= 0.f ? x : NEG*x; }

__device__ __forceinline__ unsigned short f2b(float v){
  unsigned u = __float_as_uint(v);
  unsigned r = u + 0x7FFF + ((u>>16)&1u);
  return (unsigned short)(r>>16);
}
__device__ __forceinline__ float b2f(unsigned short b){
  return __uint_as_float(((unsigned)b) << 16);
}
__device__ __forceinline__ float wred(float v){
  #pragma unroll
  for (int m = 32; m >= 1; m >>= 1) v += __shfl_xor(v, m, 64);
  return v;
}

// load 8 cols of a node row as bf16 (rows/cols clamped to zero)
__device__ __forceinline__ us8 ldcvt(const float* __restrict__ p, int row, int cb){
  us8 o;
  if (row < N_NODES && cb <= 292){
    float4 x = *(const float4*)(p + (size_t)row*D + cb);
    float4 y = *(const float4*)(p + (size_t)row*D + cb + 4);
    o[0]=f2b(x.x); o[1]=f2b(x.y); o[2]=f2b(x.z); o[3]=f2b(x.w);
    o[4]=f2b(y.x); o[5]=f2b(y.y); o[6]=f2b(y.z); o[7]=f2b(y.w);
  } else if (row < N_NODES && cb == 296){
    float4 x = *(const float4*)(p + (size_t)row*D + 296);
    o[0]=f2b(x.x); o[1]=f2b(x.y); o[2]=f2b(x.z); o[3]=f2b(x.w);
    o[4]=0; o[5]=0; o[6]=0; o[7]=0;
  } else {
    #pragma unroll
    for (int j=0;j<8;++j) o[j]=0;
  }
  return o;
}

// ---- init: zero flags, per-level CNT/CUR ----
__global__ void k_init(int* __restrict__ FRO, int* __restrict__ ND2,
                       int* __restrict__ CNTa, int* __restrict__ CURa,
                       int* __restrict__ CNTb, int* __restrict__ CURb){
  int i = blockIdx.x*256 + threadIdx.x;
  if (i < N_NODES){ FRO[i]=0; ND2[i]=0; CNTa[i]=0; CURa[i]=0; CNTb[i]=0; CURb[i]=0; }
}
__global__ void k_flag(const int* __restrict__ ro, int* __restrict__ FRO){
  int o = blockIdx.x*256 + threadIdx.x;
  if (o < NB) FRO[ro[o]] = 1;
}
__global__ void k_need(const int* __restrict__ par1, const int* __restrict__ chi1,
                       const int* __restrict__ roo1, const int* __restrict__ ro,
                       const int* __restrict__ FRO, int* __restrict__ ND2){
  int i = blockIdx.x*256 + threadIdx.x;
  if (i < NB) ND2[ro[i]] = 1;
  if (i < E1){
    int p = par1[i];
    if (FRO[p]){ ND2[p] = 1; ND2[chi1[i]] = 1; ND2[roo1[i]] = 1; }
  }
}

// ---- compaction phase 1: predicates -> wave masks + per-block counts (no atomics) ----
__global__ void k_cnt3(const int* __restrict__ par2, const int* __restrict__ par1,
                       const int* __restrict__ FRO, const int* __restrict__ ND2,
                       ull* __restrict__ MSK, int* __restrict__ BC){
  int i = blockIdx.x*256 + threadIdx.x;
  int lane = threadIdx.x & 63, wid = threadIdx.x >> 6;
  __shared__ int ws[3][4];
  int p2 = (i < E2) && ND2[par2[i]];
  int p1 = (i < E1) && FRO[par1[i]];
  int pn = (i < N_NODES) && ND2[i];
  ull m2 = __ballot(p2), m1 = __ballot(p1), mn = __ballot(pn);
  if (lane == 0){
    int wg = blockIdx.x*4 + wid;
    MSK[0*NWAVES + wg] = m2; ws[0][wid] = __popcll(m2);
    MSK[1*NWAVES + wg] = m1; ws[1][wid] = __popcll(m1);
    MSK[2*NWAVES + wg] = mn; ws[2][wid] = __popcll(mn);
  }
  __syncthreads();
  if (threadIdx.x < 3)
    BC[threadIdx.x*NBLKC + blockIdx.x] =
      ws[threadIdx.x][0]+ws[threadIdx.x][1]+ws[threadIdx.x][2]+ws[threadIdx.x][3];
}

// ---- compaction phase 2: scan block counts (one block per list) ----
__global__ __launch_bounds__(1024) void k_scanblk(const int* __restrict__ BC,
                                                  int* __restrict__ BOFF, int* __restrict__ NLV){
  int l = blockIdx.x;
  __shared__ int ls[1024];
  int v = (threadIdx.x < NBLKC) ? BC[l*NBLKC + threadIdx.x] : 0;
  ls[threadIdx.x] = v;
  __syncthreads();
  for (int off=1; off<1024; off<<=1){
    int t = (threadIdx.x >= off) ? ls[threadIdx.x-off] : 0;
    __syncthreads();
    ls[threadIdx.x] += t;
    __syncthreads();
  }
  if (threadIdx.x < NBLKC) BOFF[l*NBLKC + threadIdx.x] = ls[threadIdx.x] - v;
  if (threadIdx.x == 1023) NLV[l] = ls[1023];
}

// ---- compaction phase 3: write lists from stored masks (deterministic, no atomics) ----
__global__ void k_fill(const ull* __restrict__ MSK, const int* __restrict__ BOFF,
                       int* __restrict__ L2L, int* __restrict__ L1L, int* __restrict__ NDL){
  int i = blockIdx.x*256 + threadIdx.x;
  int lane = threadIdx.x & 63, wid = threadIdx.x >> 6;
  int wg = blockIdx.x*4 + wid;
  __shared__ int ws[3][4];
  ull m2 = MSK[0*NWAVES+wg], m1 = MSK[1*NWAVES+wg], mn = MSK[2*NWAVES+wg];
  if (lane == 0){ ws[0][wid]=__popcll(m2); ws[1][wid]=__popcll(m1); ws[2][wid]=__popcll(mn); }
  __syncthreads();
  int w2=0, w1=0, wn=0;
  #pragma unroll
  for (int k=0;k<4;++k){
    if (k < wid){ w2+=ws[0][k]; w1+=ws[1][k]; wn+=ws[2][k]; }
  }
  ull below = (1ull<<lane) - 1ull;
  if ((m2>>lane)&1ull) L2L[BOFF[0*NBLKC+blockIdx.x] + w2 + __popcll(m2 & below)] = i;
  if ((m1>>lane)&1ull) L1L[BOFF[1*NBLKC+blockIdx.x] + w1 + __popcll(m1 & below)] = i;
  if ((mn>>lane)&1ull) NDL[BOFF[2*NBLKC+blockIdx.x] + wn + __popcll(mn & below)] = i;
}

// ---- fused prep: Bt[112][320], WtB[304][128], Rb[1024][128], MbT[112][128] ----
__global__ void k_prepAll(const float* __restrict__ W, const float* __restrict__ watt,
                          const float* __restrict__ relT, unsigned short* __restrict__ Bt,
                          unsigned short* __restrict__ WtB, unsigned short* __restrict__ Rb,
                          unsigned short* __restrict__ MbT){
  int b = blockIdx.x;
  if (b < 140){
    int u = b*256 + threadIdx.x;
    if (u < 112*320){
      int c = u / 320, k = u % 320;
      float v = 0.f;
      if (k < D){
        if (c < RD) v = W[k*RD + c];
        else if (c < RD+3) v = watt[(c-RD)*D + k];
      }
      Bt[u] = f2b(v);
    }
  } else if (b < 292){
    int u = (b-140)*256 + threadIdx.x;
    if (u < 304*128){
      int dd = u >> 7, k = u & 127;
      float v = (dd < D && k < RD) ? W[dd*RD + k] : 0.f;
      WtB[u] = f2b(v);
    }
  } else if (b < 356){
    int u = (b-292)*256 + threadIdx.x;
    if (u < 1024*16){
      int row = u >> 4, c8 = (u & 15)*8;
      us8 o;
      #pragma unroll
      for (int j=0;j<8;++j){
        int c = c8+j;
        o[j] = (row < NREL && c < RD) ? f2b(relT[row*RD + c]) : (unsigned short)0;
      }
      *(us8*)(Rb + (size_t)row*128 + c8) = o;
    }
  } else {
    int u = (b-356)*256 + threadIdx.x;
    if (u < 112*128){
      int j = u >> 7, i = u & 127;
      float v = 0.f;
      if (i < RD){
        if (j < RD){ float a=0.f; for (int d=0;d<D;++d) a += W[d*RD+i]*W[d*RD+j]; v=a; }
        else if (j == RD){ float a=0.f; for (int d=0;d<D;++d) a += watt[d]*W[d*RD+i]; v=a; }
      }
      MbT[u] = f2b(v);
    }
  }
}

// ---- MFMA relation tables: U = Rb @ WtB^T -> Vh (bf16), RINV, RVW1, RVW2 ----
__global__ __launch_bounds__(256) void k_relmm(const unsigned short* __restrict__ Rb,
    const unsigned short* __restrict__ WtB, const float* __restrict__ watt,
    unsigned short* __restrict__ Vh, float* __restrict__ RINV,
    float* __restrict__ RVW1, float* __restrict__ RVW2){
  int lane = threadIdx.x & 63, wid = threadIdx.x >> 6;
  int r0 = blockIdx.x*64 + wid*16;
  int ep = lane & 15, g = lane >> 4;
  size_t a0 = (size_t)(r0 + ep)*128 + g*8;
  size_t b0 = (size_t)ep*128 + g*8;
  f32x4 acc[19];
  #pragma unroll
  for (int cf=0;cf<19;++cf) acc[cf]=(f32x4){0.f,0.f,0.f,0.f};
  #pragma unroll
  for (int ks=0; ks<4; ++ks){
    bf16x8 af = *(const bf16x8*)(Rb + a0 + ks*32);
    #pragma unroll
    for (int cf=0; cf<19; ++cf){
      bf16x8 bf = *(const bf16x8*)(WtB + b0 + (size_t)cf*16*128 + ks*32);
      acc[cf] = __builtin_amdgcn_mfma_f32_16x16x32_bf16(af, bf, acc[cf], 0, 0, 0);
    }
  }
  float w1v[19], w2v[19];
  #pragma unroll
  for (int cf=0; cf<19; ++cf){
    int col = cf*16+ep;
    bool ok = col < D;
    w1v[cf] = ok ? watt[col] : 0.f;
    w2v[cf] = ok ? watt[D+col] : 0.f;
  }
  #pragma unroll
  for (int reg=0; reg<4; ++reg){
    int row = r0 + g*4 + reg;
    float np = 0.f;
    #pragma unroll
    for (int cf=0; cf<19; ++cf){ float u = acc[cf][reg]; np += u*u; }
    np += __shfl_xor(np,1); np += __shfl_xor(np,2); np += __shfl_xor(np,4); np += __shfl_xor(np,8);
    float iv = 1.f / fmaxf(sqrtf(np), 1e-12f);
    float p1 = 0.f, p2 = 0.f;
    if (row < NREL){
      #pragma unroll
      for (int cf=0; cf<19; ++cf){
        int col = cf*16+ep;
        float v = acc[cf][reg]*iv;
        if (col < D){
          Vh[(size_t)row*D + col] = f2b(v);
          p1 += v*w1v[cf];
          p2 += v*w2v[cf];
        }
      }
    }
    p1 += __shfl_xor(p1,1); p1 += __shfl_xor(p1,2); p1 += __shfl_xor(p1,4); p1 += __shfl_xor(p1,8);
    p2 += __shfl_xor(p2,1); p2 += __shfl_xor(p2,2); p2 += __shfl_xor(p2,4); p2 += __shfl_xor(p2,8);
    if (ep == 0 && row < NREL){
      RINV[row] = iv; RVW1[row] = p1; RVW2[row] = p2;
    }
  }
}

// ---- FUSED MFMA node tables (level 2): reads node f32, emits Xb bf16 + Gh + P ----
__global__ __launch_bounds__(256) void k_nodetab2f(const float* __restrict__ node,
    const unsigned short* __restrict__ Bt, unsigned short* __restrict__ Gh, float* __restrict__ P,
    unsigned short* __restrict__ Xb){
  int lane = threadIdx.x & 63, wid = threadIdx.x >> 6;
  int n0 = blockIdx.x*128;
  int row0 = n0 + wid*32 + (lane&15);
  int row1 = row0 + 16;
  int cb0 = (lane>>4)*8;
  size_t b0 = (size_t)(lane&15)*320 + cb0;
  f32x4 acc[2][7];
  #pragma unroll
  for (int s=0;s<2;++s)
    #pragma unroll
    for (int c=0;c<7;++c) acc[s][c] = (f32x4){0.f,0.f,0.f,0.f};
  for (int ks = 0; ks < 10; ++ks){
    int cb = cb0 + ks*32;
    us8 a0p = ldcvt(node, row0, cb);
    us8 a1p = ldcvt(node, row1, cb);
    if (row0 < N_NODES) *(us8*)(Xb + (size_t)row0*320 + cb) = a0p;
    if (row1 < N_NODES) *(us8*)(Xb + (size_t)row1*320 + cb) = a1p;
    bf16x8 a0f = *(bf16x8*)&a0p;
    bf16x8 a1f = *(bf16x8*)&a1p;
    #pragma unroll
    for (int cf=0; cf<7; ++cf){
      bf16x8 bf = *(const bf16x8*)(Bt + b0 + (size_t)cf*16*320 + ks*32);
      acc[0][cf] = __builtin_amdgcn_mfma_f32_16x16x32_bf16(a0f, bf, acc[0][cf], 0, 0, 0);
      acc[1][cf] = __builtin_amdgcn_mfma_f32_16x16x32_bf16(a1f, bf, acc[1][cf], 0, 0, 0);
    }
  }
  int rbase = n0 + wid*32 + ((lane>>4)<<2);
  int cbase = lane & 15;
  #pragma unroll
  for (int sub=0; sub<2; ++sub){
    #pragma unroll
    for (int cf=0; cf<7; ++cf){
      int col = cf*16 + cbase;
      #pragma unroll
      for (int r=0; r<4; ++r){
        int row = rbase + sub*16 + r;
        if (row < N_NODES){
          float v = acc[sub][cf][r];
          if (col < RD) Gh[(size_t)row*RD + col] = f2b(v);
          else if (col < RD+3) P[(size_t)row*4 + (col-RD)] = v;
        }
      }
    }
  }
}

// ---- MFMA node tables (indexed, level 1): rows from NDL, count-capped ----
__global__ __launch_bounds__(256) void k_nodetab2i(const unsigned short* __restrict__ Eb,
    const unsigned short* __restrict__ Bt, const int* __restrict__ NDL, const int* __restrict__ NLV,
    unsigned short* __restrict__ Gh, float* __restrict__ P){
  int nlv = NLV[2];
  int base = blockIdx.x*128;
  if (base >= nlv) return;
  int lane = threadIdx.x & 63, wid = threadIdx.x >> 6;
  int li0 = base + wid*32 + (lane&15);
  int li1 = li0 + 16;
  int row0 = (li0 < nlv) ? NDL[li0] : 0;
  int row1 = (li1 < nlv) ? NDL[li1] : 0;
  size_t a0 = (size_t)row0*320 + ((lane>>4)*8);
  size_t a1 = (size_t)row1*320 + ((lane>>4)*8);
  size_t b0 = (size_t)(lane&15)*320 + ((lane>>4)*8);
  f32x4 acc[2][7];
  #pragma unroll
  for (int s=0;s<2;++s)
    #pragma unroll
    for (int c=0;c<7;++c) acc[s][c] = (f32x4){0.f,0.f,0.f,0.f};
  for (int ks = 0; ks < 10; ++ks){
    bf16x8 a0f = *(const bf16x8*)(Eb + a0 + ks*32);
    bf16x8 a1f = *(const bf16x8*)(Eb + a1 + ks*32);
    #pragma unroll
    for (int cf=0; cf<7; ++cf){
      bf16x8 bf = *(const bf16x8*)(Bt + b0 + (size_t)cf*16*320 + ks*32);
      acc[0][cf] = __builtin_amdgcn_mfma_f32_16x16x32_bf16(a0f, bf, acc[0][cf], 0, 0, 0);
      acc[1][cf] = __builtin_amdgcn_mfma_f32_16x16x32_bf16(a1f, bf, acc[1][cf], 0, 0, 0);
    }
  }
  int lbase = base + wid*32 + ((lane>>4)<<2);
  int cbase = lane & 15;
  #pragma unroll
  for (int sub=0; sub<2; ++sub){
    #pragma unroll
    for (int r=0; r<4; ++r){
      int li = lbase + sub*16 + r;
      if (li >= nlv) continue;
      int row = NDL[li];
      #pragma unroll
      for (int cf=0; cf<7; ++cf){
        int col = cf*16 + cbase;
        float v = acc[sub][cf][r];
        if (col < RD) Gh[(size_t)row*RD + col] = f2b(v);
        else if (col < RD+3) P[(size_t)row*4 + (col-RD)] = v;
      }
    }
  }
}

// ---- level-2 pass 1 (MFMA, compacted): logits + DK + parent histogram ----
__global__ __launch_bounds__(256) void k_pass1_l2c(
    const float* __restrict__ relT, const int* __restrict__ rel2i, const int* __restrict__ relrp2,
    const int* __restrict__ par, const int* __restrict__ chi, const int* __restrict__ roo,
    const unsigned short* __restrict__ Gh, const float* __restrict__ P,
    const unsigned short* __restrict__ MbT,
    const float* __restrict__ RINV, const float* __restrict__ RVW2,
    const int* __restrict__ L2L, const int* __restrict__ NLV,
    float* __restrict__ BBUF, float* __restrict__ DK, int* __restrict__ CNT){
  __shared__ unsigned short Cl[4*16*136];
  int nlv = NLV[0];
  if (blockIdx.x*64 >= nlv) return;
  int lane = threadIdx.x & 63, wid = threadIdx.x >> 6;
  int ep = lane & 15, g = lane >> 4;
  unsigned short* cw = Cl + wid*16*136;
  int idx = blockIdx.x*64 + wid*16 + ep;
  int live = idx < nlv;
  int e = live ? L2L[idx] : 0;
  int rp = par[e];
  int ra = rel2i[e], rb = relrp2[e], rc = chi[e], rr = roo[e];
  const float* rA = relT + (size_t)ra*RD;
  const float* rB = relT + (size_t)rb*RD;
  const unsigned short* gR = Gh + (size_t)rr*RD;
  const unsigned short* gX = Gh + (size_t)rp*RD;
  const unsigned short* gY = Gh + (size_t)rc*RD;
  float dgi = 0.f, dgx = 0.f, dgy = 0.f;
  bf16x8 af[4];
  #pragma unroll
  for (int ks=0; ks<4; ++ks){
    us8 cpack;
    #pragma unroll
    for (int h=0; h<2; ++h){
      int k0 = g*8 + ks*32 + h*4;
      float4 a4 = make_float4(0.f,0.f,0.f,0.f), b4 = a4, grr = a4, grp = a4, gry = a4;
      if (live && k0 <= 96){
        a4  = *(const float4*)(rA + k0);
        b4  = *(const float4*)(rB + k0);
        us4 r4 = *(const us4*)(gR + k0);
        us4 x4 = *(const us4*)(gX + k0);
        us4 y4 = *(const us4*)(gY + k0);
        grr = make_float4(b2f(r4[0]),b2f(r4[1]),b2f(r4[2]),b2f(r4[3]));
        grp = make_float4(b2f(x4[0]),b2f(x4[1]),b2f(x4[2]),b2f(x4[3]));
        gry = make_float4(b2f(y4[0]),b2f(y4[1]),b2f(y4[2]),b2f(y4[3]));
      }
      float4 c4;
      c4.x = a4.x*b4.x; c4.y = a4.y*b4.y; c4.z = a4.z*b4.z; c4.w = a4.w*b4.w;
      dgi += c4.x*grr.x + c4.y*grr.y + c4.z*grr.z + c4.w*grr.w;
      dgx += a4.x*grp.x + a4.y*grp.y + a4.z*grp.z + a4.w*grp.w;
      dgy += a4.x*gry.x + a4.y*gry.y + a4.z*gry.z + a4.w*gry.w;
      cpack[h*4+0]=f2b(c4.x); cpack[h*4+1]=f2b(c4.y); cpack[h*4+2]=f2b(c4.z); cpack[h*4+3]=f2b(c4.w);
    }
    *(us8*)((char*)cw + ep*272 + g*16 + ks*64) = cpack;
    af[ks] = *(bf16x8*)&cpack;
  }
  f32x4 acc[7];
  #pragma unroll
  for (int cf=0; cf<7; ++cf) acc[cf] = (f32x4){0.f,0.f,0.f,0.f};
  #pragma unroll
  for (int cf=0; cf<7; ++cf){
    #pragma unroll
    for (int ks=0; ks<4; ++ks){
      bf16x8 bfr = *(const bf16x8*)(MbT + (size_t)(cf*16+ep)*128 + g*8 + ks*32);
      acc[cf] = __builtin_amdgcn_mfma_f32_16x16x32_bf16(af[ks], bfr, acc[cf], 0, 0, 0);
    }
  }
  dgi += __shfl_xor(dgi, 16); dgi += __shfl_xor(dgi, 32);
  dgx += __shfl_xor(dgx, 16); dgx += __shfl_xor(dgx, 32);
  dgy += __shfl_xor(dgy, 16); dgy += __shfl_xor(dgy, 32);
  __syncthreads();
  #pragma unroll
  for (int r=0; r<4; ++r){
    int row = g*4 + r;
    int src = (lane & 48) | row;
    int livr = __shfl(live, src);
    if (!livr) continue;
    float pr = 0.f;
    #pragma unroll
    for (int cf=0; cf<7; ++cf)
      pr += b2f(cw[row*136 + cf*16 + ep]) * acc[cf][r];
    pr += __shfl_xor(pr, 1); pr += __shfl_xor(pr, 2);
    pr += __shfl_xor(pr, 4); pr += __shfl_xor(pr, 8);
    float dw1r = __shfl(acc[6][r], (lane & 48) | 4);   // t[row][100]
    float dgir = __shfl(dgi, src);
    float dgxr = __shfl(dgx, src);
    float dgyr = __shfl(dgy, src);
    int rar = __shfl(ra, src), rpr = __shfl(rp, src);
    int rcr = __shfl(rc, src), rrr = __shfl(rr, src);
    int er  = __shfl(e, src);
    float invp = 1.f / fmaxf(sqrtf(pr), 1e-12f);
    float rinv = RINV[rar];
    float t1 = (dgir*invp)*(dw1r*invp);
    float t2 = (dgxr*rinv)*RVW2[rar];
    float bb = P[(size_t)rrr*4+0] - 2.f*t1 + P[(size_t)rpr*4+1] - 2.f*t2 + P[(size_t)rcr*4+2];
    bb = leaky(bb);
    if (ep == 0){
      BBUF[er] = bb;
      DK[er] = dgyr * rinv;
      atomicAdd(&CNT[rpr], 1);
    }
  }
}

// ---- level-1 pass 1 (compacted): one wave per live edge ----
__global__ __launch_bounds__(256) void k_pass1_l1c(
    const float* __restrict__ relT, const int* __restrict__ rel1i,
    const int* __restrict__ par, const int* __restrict__ chi, const int* __restrict__ roo,
    const unsigned short* __restrict__ Gh, const float* __restrict__ P,
    const float* __restrict__ RINV, const float* __restrict__ RVW1, const float* __restrict__ RVW2,
    const int* __restrict__ L1L, const int* __restrict__ NLV,
    float* __restrict__ BBUF, float* __restrict__ DK, int* __restrict__ CNT){
  int nlv = NLV[1];
  int j = (blockIdx.x*256 + threadIdx.x) >> 6;
  if (j >= nlv) return;
  int lane = threadIdx.x & 63;
  int e = L1L[j];
  int pp = par[e];
  int r = rel1i[e], cc = chi[e], ii = roo[e];
  const float* rrow = relT + r*RD;
  const unsigned short* gI = Gh + (size_t)ii*RD;
  const unsigned short* gX = Gh + (size_t)pp*RD;
  const unsigned short* gY = Gh + (size_t)cc*RD;
  float ai = rrow[lane]*b2f(gI[lane]);
  float ax = rrow[lane]*b2f(gX[lane]);
  float ay = rrow[lane]*b2f(gY[lane]);
  if (lane < 36){
    ai += rrow[lane+64]*b2f(gI[lane+64]);
    ax += rrow[lane+64]*b2f(gX[lane+64]);
    ay += rrow[lane+64]*b2f(gY[lane+64]);
  }
  float dgi = wred(ai), dgx = wred(ax), dgy = wred(ay);
  if (lane == 0){
    float invn = RINV[r];
    float b = P[(size_t)ii*4+0] - 2.f*(dgi*invn)*RVW1[r]
            + P[(size_t)pp*4+1] - 2.f*(dgx*invn)*RVW2[r]
            + P[(size_t)cc*4+2];
    b = leaky(b);
    BBUF[e] = b;
    DK[e] = dgy * invn;
    atomicAdd(&CNT[pp], 1);
  }
}

// ---- CSR build: exclusive scan over CNT ----
__global__ __launch_bounds__(256) void k_scan_a(const int* __restrict__ CNT,
    int* __restrict__ ROFF, int* __restrict__ PART){
  __shared__ int ls[256];
  int i = blockIdx.x*256 + threadIdx.x;
  int v = (i < N_NODES) ? CNT[i] : 0;
  ls[threadIdx.x] = v;
  __syncthreads();
  for (int off=1; off<256; off<<=1){
    int t = (threadIdx.x >= off) ? ls[threadIdx.x-off] : 0;
    __syncthreads();
    ls[threadIdx.x] += t;
    __syncthreads();
  }
  int incl = ls[threadIdx.x];
  if (i < N_NODES) ROFF[i] = incl - v;
  if (threadIdx.x == 255) PART[blockIdx.x] = incl;
}
__global__ __launch_bounds__(512) void k_scan_b(int* __restrict__ PART){
  __shared__ int ls[512];
  int v = (threadIdx.x < SCAN_BLKS) ? PART[threadIdx.x] : 0;
  ls[threadIdx.x] = v;
  __syncthreads();
  for (int off=1; off<512; off<<=1){
    int t = (threadIdx.x >= off) ? ls[threadIdx.x-off] : 0;
    __syncthreads();
    ls[threadIdx.x] += t;
    __syncthreads();
  }
  if (threadIdx.x < SCAN_BLKS) PART[threadIdx.x] = ls[threadIdx.x] - v;
}
// ---- compacted scatter: iterate live-edge list ----
__global__ void k_scatterc(const int* __restrict__ L, const int* __restrict__ NLV, int which,
                           const int* __restrict__ par, const int* __restrict__ ROFF,
                           const int* __restrict__ PART, int* __restrict__ CUR,
                           int* __restrict__ EIDX){
  int j = blockIdx.x*256 + threadIdx.x;
  if (j >= NLV[which]) return;
  int e = L[j];
  int p = par[e];
  int pos = ROFF[p] + PART[p>>8] + atomicAdd(&CUR[p], 1);
  EIDX[pos] = e;
}

// ---- per-parent softmax + Householder aggregate; DK precomputed ----
__device__ __forceinline__ void agg_bucket(int p, int lane,
    const int* __restrict__ ROFF, const int* __restrict__ PART, const int* __restrict__ CNT,
    const int* __restrict__ EIDX, const float* __restrict__ BBUF, const float* __restrict__ DK,
    const int* __restrict__ chi, const int* __restrict__ relI,
    const unsigned short* __restrict__ Vh, const unsigned short* __restrict__ Xe,
    float acc[5]){
  int cnt = CNT[p];
  if (cnt <= 0) return;
  int base = ROFF[p] + PART[p>>8];
  if (cnt <= 64){
    float bl = (lane < cnt) ? BBUF[EIDX[base+lane]] : -1e30f;
    float m = bl;
    #pragma unroll
    for (int msk=32; msk>=1; msk>>=1) m = fmaxf(m, __shfl_xor(m, msk));
    float el = (lane < cnt) ? __expf(bl - m) : 0.f;
    float s = wred(el);
    float inv = 1.f / fmaxf(s, 1e-10f);
    for (int i=0;i<cnt;++i){
      int eid = EIDX[base+i];
      float a = __shfl(el, i) * inv;
      float s2 = 2.f*DK[eid]*a;
      int y = chi[eid], r = relI[eid];
      const unsigned short* vr = Vh + (size_t)r*D;
      const unsigned short* ey = Xe + (size_t)y*320;
      #pragma unroll
      for (int q=0;q<4;++q){
        int d = lane + 64*q;
        acc[q] += b2f(ey[d])*a - s2*b2f(vr[d]);
      }
      if (lane < 44){
        int d = lane + 256;
        acc[4] += b2f(ey[d])*a - s2*b2f(vr[d]);
      }
    }
  } else {
    float m = -1e30f;
    for (int i=0;i<cnt;++i) m = fmaxf(m, BBUF[EIDX[base+i]]);
    float s = 0.f;
    for (int i=0;i<cnt;++i) s += __expf(BBUF[EIDX[base+i]] - m);
    float inv = 1.f / fmaxf(s, 1e-10f);
    for (int i=0;i<cnt;++i){
      int eid = EIDX[base+i];
      float a = __expf(BBUF[eid]-m)*inv;
      float s2 = 2.f*DK[eid]*a;
      int y = chi[eid], r = relI[eid];
      const unsigned short* vr = Vh + (size_t)r*D;
      const unsigned short* ey = Xe + (size_t)y*320;
      #pragma unroll
      for (int q=0;q<4;++q){
        int d = lane + 64*q;
        acc[q] += b2f(ey[d])*a - s2*b2f(vr[d]);
      }
      if (lane < 44){
        int d = lane + 256;
        acc[4] += b2f(ey[d])*a - s2*b2f(vr[d]);
      }
    }
  }
}

// ---- level-2 (compacted): one wave per needed parent from NDL ----
__global__ __launch_bounds__(256) void k_agg2(const int* __restrict__ ROFF, const int* __restrict__ PART,
    const int* __restrict__ CNT, const int* __restrict__ EIDX,
    const float* __restrict__ BBUF, const float* __restrict__ DK,
    const int* __restrict__ chi, const int* __restrict__ relI,
    const unsigned short* __restrict__ Vh, const unsigned short* __restrict__ Xe,
    const int* __restrict__ NDL, const int* __restrict__ NLV,
    unsigned short* __restrict__ Xo){
  int nlv = NLV[2];
  int idx = (blockIdx.x*256 + threadIdx.x) >> 6;
  if (idx >= nlv) return;
  int lane = threadIdx.x & 63;
  int p = NDL[idx];
  float acc[5] = {0.f,0.f,0.f,0.f,0.f};
  agg_bucket(p, lane, ROFF, PART, CNT, EIDX, BBUF, DK, chi, relI, Vh, Xe, acc);
  const unsigned short* in = Xe + (size_t)p*320;
  unsigned short* op = Xo + (size_t)p*320;
  #pragma unroll
  for (int q=0;q<4;++q){
    int d = lane + 64*q;
    op[d] = f2b(leaky(b2f(in[d]) + acc[q]));
  }
  {
    int d = lane + 256;
    unsigned short o = 0;
    if (lane < 44) o = f2b(leaky(b2f(in[d]) + acc[4]));
    op[d] = o;
  }
}

// ---- level-1: one wave per OUTPUT (8192); writes d_out directly ----
__global__ __launch_bounds__(256) void k_aggout(const int* __restrict__ ro,
    const int* __restrict__ ROFF, const int* __restrict__ PART,
    const int* __restrict__ CNT, const int* __restrict__ EIDX,
    const float* __restrict__ BBUF, const float* __restrict__ DK,
    const int* __restrict__ chi, const int* __restrict__ relI,
    const unsigned short* __restrict__ Vh, const unsigned short* __restrict__ Xe,
    float* __restrict__ out){
  int lane = threadIdx.x & 63;
  int o = (blockIdx.x*256 + threadIdx.x) >> 6;
  if (o >= NB) return;
  int p = ro[o];
  float acc[5] = {0.f,0.f,0.f,0.f,0.f};
  agg_bucket(p, lane, ROFF, PART, CNT, EIDX, BBUF, DK, chi, relI, Vh, Xe, acc);
  const unsigned short* in = Xe + (size_t)p*320;
  float* op = out + (size_t)o*D;
  #pragma unroll
  for (int q=0;q<4;++q){
    int d = lane + 64*q;
    op[d] = leaky(b2f(in[d]) + acc[q]);
  }
  if (lane < 44){
    int d = lane + 256;
    op[d] = leaky(b2f(in[d]) + acc[4]);
  }
}

extern "C" void kernel_launch(void* const* d_in, const int* in_sizes, int n_in,
                              void* d_out, int out_size, void* d_ws, size_t ws_size,
                              hipStream_t stream){
  const float* node = (const float*)d_in[0];
  const float* relT = (const float*)d_in[1];
  const float* W    = (const float*)d_in[2];
  const float* watt = (const float*)d_in[3];
  const int* par2 = (const int*)d_in[4];
  const int* chi2 = (const int*)d_in[5];
  const int* roo2 = (const int*)d_in[6];
  const int* rel2i = (const int*)d_in[7];
  const int* relrp2 = (const int*)d_in[8];
  const int* par1 = (const int*)d_in[9];
  const int* chi1 = (const int*)d_in[10];
  const int* roo1 = (const int*)d_in[11];
  const int* rel1i = (const int*)d_in[12];
  const int* roout = (const int*)d_in[13];

  char* w = (char*)d_ws;
  size_t off = 0;
  auto alloc = [&](size_t bytes)->void*{ void* p = w + off; off += (bytes + 255) & ~(size_t)255; return p; };
  unsigned short* Gh = (unsigned short*)alloc((size_t)N_NODES*RD*2);
  float* P    = (float*)alloc((size_t)N_NODES*4*4);
  unsigned short* Vh = (unsigned short*)alloc((size_t)NREL*D*2);
  float* RINV = (float*)alloc(NREL*4);
  float* RVW1 = (float*)alloc(NREL*4);
  float* RVW2 = (float*)alloc(NREL*4);
  float* BBUF = (float*)alloc((size_t)E2*4);
  float* DKb  = (float*)alloc((size_t)E2*4);
  unsigned short* Xb  = (unsigned short*)alloc((size_t)NPAD*320*2);
  unsigned short* Xb2 = (unsigned short*)alloc((size_t)NPAD*320*2);
  unsigned short* Bt  = (unsigned short*)alloc((size_t)112*320*2);
  unsigned short* MbT = (unsigned short*)alloc((size_t)112*128*2);
  unsigned short* WtB = (unsigned short*)alloc((size_t)304*128*2);
  unsigned short* Rb  = (unsigned short*)alloc((size_t)1024*128*2);
  int* CNTa = (int*)alloc((size_t)N_NODES*4);
  int* CURa = (int*)alloc((size_t)N_NODES*4);
  int* CNTb = (int*)alloc((size_t)N_NODES*4);
  int* CURb = (int*)alloc((size_t)N_NODES*4);
  int* ROFF = (int*)alloc((size_t)N_NODES*4);
  int* PART = (int*)alloc(512*4);
  int* EIDX = (int*)alloc((size_t)E2*4);
  int* FRO  = (int*)alloc((size_t)N_NODES*4);
  int* ND2  = (int*)alloc((size_t)N_NODES*4);
  int* L2L  = (int*)alloc((size_t)E2*4);
  int* L1L  = (int*)alloc((size_t)E1*4);
  int* NDL  = (int*)alloc((size_t)N_NODES*4);
  int* NLV  = (int*)alloc(256);
  ull* MSK  = (ull*)alloc((size_t)3*NWAVES*8);
  int* BC   = (int*)alloc((size_t)3*NBLKC*4);
  int* BOFF = (int*)alloc((size_t)3*NBLKC*4);

  // backward-slice flags + scan-based compaction (index-only dependency, no global atomics)
  k_init<<<dim3(SCAN_BLKS), dim3(256), 0, stream>>>(FRO, ND2, CNTa, CURa, CNTb, CURb);
  k_flag<<<dim3((NB+255)/256), dim3(256), 0, stream>>>(roout, FRO);
  k_need<<<dim3((E1+255)/256), dim3(256), 0, stream>>>(par1, chi1, roo1, roout, FRO, ND2);
  k_cnt3<<<dim3(NBLKC), dim3(256), 0, stream>>>(par2, par1, FRO, ND2, MSK, BC);
  k_scanblk<<<dim3(3), dim3(1024), 0, stream>>>(BC, BOFF, NLV);
  k_fill<<<dim3(NBLKC), dim3(256), 0, stream>>>(MSK, BOFF, L2L, L1L, NDL);

  // constants
  k_prepAll<<<dim3(412), dim3(256), 0, stream>>>(W, watt, relT, Bt, WtB, Rb, MbT);
  k_relmm<<<dim3(16), dim3(256), 0, stream>>>(Rb, WtB, watt, Vh, RINV, RVW1, RVW2);

  // ---------- level 2 ----------
  k_nodetab2f<<<dim3((N_NODES+127)/128), dim3(256), 0, stream>>>(node, Bt, Gh, P, Xb);
  k_pass1_l2c<<<dim3(E2/64), dim3(256), 0, stream>>>(relT, rel2i, relrp2, par2, chi2, roo2,
                                                     Gh, P, MbT, RINV, RVW2, L2L, NLV, BBUF, DKb, CNTa);
  k_scan_a<<<dim3(SCAN_BLKS), dim3(256), 0, stream>>>(CNTa, ROFF, PART);
  k_scan_b<<<dim3(1), dim3(512), 0, stream>>>(PART);
  k_scatterc<<<dim3((E2+255)/256), dim3(256), 0, stream>>>(L2L, NLV, 0, par2, ROFF, PART, CURa, EIDX);
  k_agg2<<<dim3((N_NODES+3)/4), dim3(256), 0, stream>>>(ROFF, PART, CNTa, EIDX, BBUF, DKb,
                                                        chi2, rel2i, Vh, Xb, NDL, NLV, Xb2);

  // ---------- level 1 ----------
  k_nodetab2i<<<dim3((N_NODES+127)/128), dim3(256), 0, stream>>>(Xb2, Bt, NDL, NLV, Gh, P);
  k_pass1_l1c<<<dim3((E1+3)/4), dim3(256), 0, stream>>>(relT, rel1i, par1, chi1, roo1,
                                                        Gh, P, RINV, RVW1, RVW2, L1L, NLV, BBUF, DKb, CNTb);
  k_scan_a<<<dim3(SCAN_BLKS), dim3(256), 0, stream>>>(CNTb, ROFF, PART);
  k_scan_b<<<dim3(1), dim3(512), 0, stream>>>(PART);
  k_scatterc<<<dim3((E1+255)/256), dim3(256), 0, stream>>>(L1L, NLV, 1, par1, ROFF, PART, CURb, EIDX);
  k_aggout<<<dim3((NB+3)/4), dim3(256), 0, stream>>>(roout, ROFF, PART, CNTb, EIDX, BBUF, DKb,
                                                     chi1, rel1i, Vh, Xb2, (float*)d_out);
}